// Round 3
// baseline (1029.630 us; speedup 1.0000x reference)
//
#include <hip/hip_runtime.h>
#include <hip/hip_bf16.h>

#define NTOK   2048      // B*L
#define DMODEL 1024
#define NEXP   8
#define DFF    4096
#define MAXROWS 5120
#define MAXTILES 40

typedef __attribute__((ext_vector_type(8))) short short8;
typedef __attribute__((ext_vector_type(4))) float float4v;

__device__ __forceinline__ unsigned short f2bf(float f) {
  union { float f; unsigned u; } v; v.f = f;
  unsigned r = v.u + 0x7fffu + ((v.u >> 16) & 1u);
  return (unsigned short)(r >> 16);
}
__device__ __forceinline__ float bf2f(unsigned short h) {
  union { unsigned u; float f; } v; v.u = ((unsigned)h) << 16; return v.f;
}
__device__ __forceinline__ void gl_lds16(const void* g, void* l) {
  __builtin_amdgcn_global_load_lds((const __attribute__((address_space(1))) void*)g,
                                   (__attribute__((address_space(3))) void*)l, 16, 0, 0);
}

// bijective XCD swizzle: consecutive HW bids round-robin over 8 XCDs; give each
// XCD a contiguous chunk of logical tile space (requires nwg % 8 == 0).
__device__ __forceinline__ int xcd_swz(int bid, int nwg) {
  if (nwg & 7) return bid;
  const int chunk = nwg >> 3;
  return (bid & 7) * chunk + (bid >> 3);
}

// ---------------- GEMM: C[M,N] = A[M,K](bf16) x B[N,K]^T(bf16), fp32 acc ---
// EPI: 0 C=acc ; 3 Cbf=bf16(gelu(acc))
// split-K: z covers k in [z*kslice, (z+1)*kslice), partial C slab at z*zstride
template<int EPI, int EMAP>
__launch_bounds__(256, 5)
__global__ void gemm_bt(const unsigned short* __restrict__ A,
                        const unsigned short* __restrict__ B0,
                        float* __restrict__ C,
                        unsigned short* __restrict__ Cbf,
                        const int N, const int K,
                        const int kslice, const long zstride,
                        const int* __restrict__ tmap, const long estride) {
  // ---- XCD-swizzled logical tile id ----
  const int gx = gridDim.x, gy = gridDim.y;
  const int nwg = gx * gy * gridDim.z;
  const int lid = xcd_swz(blockIdx.x + gx * (blockIdx.y + gy * blockIdx.z), nwg);
  const int bx = lid % gx;
  const int t1 = lid / gx;
  const int mtile = t1 % gy;
  const int bz = t1 / gy;

  const unsigned short* B = B0;
  if (EMAP) {
    int e = tmap[mtile];
    if (e < 0) return;
    B += (size_t)e * (size_t)estride;
  }
  const int n0 = bx * 128;
  const int m0 = mtile * 128;
  if (EPI == 0) C += (size_t)bz * (size_t)zstride;
  __shared__ unsigned short sA[128 * 64];
  __shared__ unsigned short sB[128 * 64];
  const int tid  = threadIdx.x;
  const int w    = tid >> 6;
  const int lane = tid & 63;
  const int quad = lane >> 4;
  const int r16  = lane & 15;
  const int wr   = w >> 1;
  const int wc   = w & 1;
  const int rl   = lane >> 3;
  const int csl  = lane & 7;
  const int cg   = csl ^ rl;
  float4v acc[4][4];
#pragma unroll
  for (int i = 0; i < 4; ++i)
#pragma unroll
    for (int j = 0; j < 4; ++j) acc[i][j] = float4v{0.f, 0.f, 0.f, 0.f};

  const unsigned short* Ab = A + (size_t)m0 * K + cg * 8;
  const unsigned short* Bb = B + (size_t)n0 * K + cg * 8;

  const int kbeg = bz * kslice;
  const int kend = kbeg + kslice;
  for (int k0 = kbeg; k0 < kend; k0 += 64) {
    __syncthreads();
#pragma unroll
    for (int i = 0; i < 4; ++i) {
      const int j = w * 4 + i;
      gl_lds16(Ab + (size_t)(j * 8 + rl) * K + k0, (char*)sA + j * 1024);
      gl_lds16(Bb + (size_t)(j * 8 + rl) * K + k0, (char*)sB + j * 1024);
    }
    __syncthreads();
#pragma unroll
    for (int kc = 0; kc < 8; kc += 4) {
      short8 af[4], bq[4];
#pragma unroll
      for (int mt = 0; mt < 4; ++mt) {
        int r = wr * 64 + mt * 16 + r16;
        af[mt] = *(const short8*)(sA + ((r * 8 + ((kc + quad) ^ (r & 7))) * 8));
      }
#pragma unroll
      for (int nt = 0; nt < 4; ++nt) {
        int r = wc * 64 + nt * 16 + r16;
        bq[nt] = *(const short8*)(sB + ((r * 8 + ((kc + quad) ^ (r & 7))) * 8));
      }
#pragma unroll
      for (int mt = 0; mt < 4; ++mt)
#pragma unroll
        for (int nt = 0; nt < 4; ++nt)
          acc[mt][nt] = __builtin_amdgcn_mfma_f32_16x16x32_bf16(af[mt], bq[nt], acc[mt][nt], 0, 0, 0);
    }
  }
#pragma unroll
  for (int mt = 0; mt < 4; ++mt) {
#pragma unroll
    for (int nt = 0; nt < 4; ++nt) {
#pragma unroll
      for (int rg = 0; rg < 4; ++rg) {
        const int m = m0 + wr * 64 + mt * 16 + quad * 4 + rg;
        const int n = n0 + wc * 64 + nt * 16 + r16;
        const size_t idx = (size_t)m * N + n;
        const float v = acc[mt][nt][rg];
        if (EPI == 0) C[idx] = v;
        else {
          // tanh-form gelu: x*sigmoid(1.5958(x+0.044715x^3)); |err| ~1e-4,
          // far below hid's bf16 quantization. Replaces ~25-op erff (was
          // VALUBusy=30%, epilogue ~= MFMA-loop cost).
          const float u = v + 0.044715f * v * v * v;
          const float ge = v / (1.0f + __expf(-1.5957691216f * u));
          Cbf[idx] = f2bf(ge);
        }
      }
    }
  }
}

// ------- split-bf16 GEMM: C = (Ah+Al)x(Bh+Bl)^T, 3 terms, split-K slabs -----
__launch_bounds__(256, 2)
__global__ void gemm_split(const unsigned short* __restrict__ Ah,
                           const unsigned short* __restrict__ Al,
                           const unsigned short* __restrict__ Bh,
                           const unsigned short* __restrict__ Bl,
                           float* __restrict__ C,
                           const int N, const int K,
                           const int kslice, const long zstride) {
  const int gx = gridDim.x, gy = gridDim.y;
  const int nwg = gx * gy * gridDim.z;
  const int lid = xcd_swz(blockIdx.x + gx * (blockIdx.y + gy * blockIdx.z), nwg);
  const int bx = lid % gx;
  const int t1 = lid / gx;
  const int by = t1 % gy;
  const int bz = t1 / gy;

  const int n0 = bx * 128;
  const int m0 = by * 128;
  C += (size_t)bz * (size_t)zstride;
  __shared__ unsigned short sAh[128 * 64];
  __shared__ unsigned short sAl[128 * 64];
  __shared__ unsigned short sBh[128 * 64];
  __shared__ unsigned short sBl[128 * 64];
  const int tid  = threadIdx.x;
  const int w    = tid >> 6;
  const int lane = tid & 63;
  const int quad = lane >> 4;
  const int r16  = lane & 15;
  const int wr   = w >> 1;
  const int wc   = w & 1;
  const int rl   = lane >> 3;
  const int csl  = lane & 7;
  const int cg   = csl ^ rl;
  float4v acc[4][4];
#pragma unroll
  for (int i = 0; i < 4; ++i)
#pragma unroll
    for (int j = 0; j < 4; ++j) acc[i][j] = float4v{0.f, 0.f, 0.f, 0.f};

  const size_t aoff = (size_t)m0 * K + cg * 8;
  const size_t boff = (size_t)n0 * K + cg * 8;

  const int kbeg = bz * kslice;
  const int kend = kbeg + kslice;
  for (int k0 = kbeg; k0 < kend; k0 += 64) {
    __syncthreads();
#pragma unroll
    for (int i = 0; i < 4; ++i) {
      const int j = w * 4 + i;
      const size_t ro = (size_t)(j * 8 + rl) * K + k0;
      gl_lds16(Ah + aoff + ro, (char*)sAh + j * 1024);
      gl_lds16(Al + aoff + ro, (char*)sAl + j * 1024);
      gl_lds16(Bh + boff + ro, (char*)sBh + j * 1024);
      gl_lds16(Bl + boff + ro, (char*)sBl + j * 1024);
    }
    __syncthreads();
#pragma unroll
    for (int kc = 0; kc < 8; kc += 4) {
      short8 afh[4], afl[4], bqh[4], bql[4];
#pragma unroll
      for (int mt = 0; mt < 4; ++mt) {
        int r = wr * 64 + mt * 16 + r16;
        int o = (r * 8 + ((kc + quad) ^ (r & 7))) * 8;
        afh[mt] = *(const short8*)(sAh + o);
        afl[mt] = *(const short8*)(sAl + o);
      }
#pragma unroll
      for (int nt = 0; nt < 4; ++nt) {
        int r = wc * 64 + nt * 16 + r16;
        int o = (r * 8 + ((kc + quad) ^ (r & 7))) * 8;
        bqh[nt] = *(const short8*)(sBh + o);
        bql[nt] = *(const short8*)(sBl + o);
      }
#pragma unroll
      for (int mt = 0; mt < 4; ++mt)
#pragma unroll
        for (int nt = 0; nt < 4; ++nt) {
          acc[mt][nt] = __builtin_amdgcn_mfma_f32_16x16x32_bf16(afh[mt], bqh[nt], acc[mt][nt], 0, 0, 0);
          acc[mt][nt] = __builtin_amdgcn_mfma_f32_16x16x32_bf16(afh[mt], bql[nt], acc[mt][nt], 0, 0, 0);
          acc[mt][nt] = __builtin_amdgcn_mfma_f32_16x16x32_bf16(afl[mt], bqh[nt], acc[mt][nt], 0, 0, 0);
        }
    }
  }
#pragma unroll
  for (int mt = 0; mt < 4; ++mt) {
#pragma unroll
    for (int nt = 0; nt < 4; ++nt) {
#pragma unroll
      for (int rg = 0; rg < 4; ++rg) {
        const int m = m0 + wr * 64 + mt * 16 + quad * 4 + rg;
        const int n = n0 + wc * 64 + nt * 16 + r16;
        C[(size_t)m * N + n] = acc[mt][nt][rg];
      }
    }
  }
}

// ------ fp32 [K,N] -> bf16 [N,K] (hi, optional lo), 64x64, vectorized -------
template<int WLO>
__global__ void transpose_w(const float* __restrict__ in, unsigned short* __restrict__ oh,
                            unsigned short* __restrict__ ol, const int K, const int N,
                            const long istride, const long ostride) {
  const int bz = blockIdx.z;
  in += (size_t)bz * istride;
  oh += (size_t)bz * ostride;
  if (WLO) ol += (size_t)bz * ostride;
  __shared__ float t[64][65];
  const int n0 = blockIdx.x * 64;
  const int k0 = blockIdx.y * 64;
  const int tid = threadIdx.x;
  const int rr = tid >> 4;        // 0..15
  const int c4 = (tid & 15) * 4;  // 0..60
#pragma unroll
  for (int p = 0; p < 4; ++p) {
    const int row = p * 16 + rr;
    const float4 v = *(const float4*)(in + (size_t)(k0 + row) * N + n0 + c4);
    t[row][c4] = v.x; t[row][c4 + 1] = v.y; t[row][c4 + 2] = v.z; t[row][c4 + 3] = v.w;
  }
  __syncthreads();
#pragma unroll
  for (int p = 0; p < 4; ++p) {
    const int n = p * 16 + rr;
    float vs[4];
#pragma unroll
    for (int i = 0; i < 4; ++i) vs[i] = t[c4 + i][n];
    ushort4 h;
    h.x = f2bf(vs[0]); h.y = f2bf(vs[1]); h.z = f2bf(vs[2]); h.w = f2bf(vs[3]);
    const size_t o = (size_t)(n0 + n) * K + k0 + c4;
    *(ushort4*)(oh + o) = h;
    if (WLO) {
      ushort4 lo4;
      lo4.x = f2bf(vs[0] - bf2f(h.x));
      lo4.y = f2bf(vs[1] - bf2f(h.y));
      lo4.z = f2bf(vs[2] - bf2f(h.z));
      lo4.w = f2bf(vs[3] - bf2f(h.w));
      *(ushort4*)(ol + o) = lo4;
    }
  }
}

// ---------------- LayerNorm over D=1024 -------------------------------------
__global__ void ln_kernel(const float* __restrict__ x, const float* __restrict__ g,
                          const float* __restrict__ b, unsigned short* __restrict__ hi,
                          unsigned short* __restrict__ lo, float* __restrict__ f32o) {
  const int row = blockIdx.x;
  const int tid = threadIdx.x;
  const int w = tid >> 6, lane = tid & 63;
  const float4 v = *(const float4*)(x + (size_t)row * DMODEL + tid * 4);
  float s = v.x + v.y + v.z + v.w;
  float q = v.x * v.x + v.y * v.y + v.z * v.z + v.w * v.w;
#pragma unroll
  for (int o = 32; o; o >>= 1) { s += __shfl_xor(s, o); q += __shfl_xor(q, o); }
  __shared__ float red[8];
  if (lane == 0) { red[w] = s; red[4 + w] = q; }
  __syncthreads();
  s = red[0] + red[1] + red[2] + red[3];
  q = red[4] + red[5] + red[6] + red[7];
  const float mean = s * (1.0f / DMODEL);
  const float var = q * (1.0f / DMODEL) - mean * mean;
  const float rs = rsqrtf(var + 1e-5f);
  const float4 gg = *(const float4*)(g + tid * 4);
  const float4 bb = *(const float4*)(b + tid * 4);
  float y[4];
  y[0] = (v.x - mean) * rs * gg.x + bb.x;
  y[1] = (v.y - mean) * rs * gg.y + bb.y;
  y[2] = (v.z - mean) * rs * gg.z + bb.z;
  y[3] = (v.w - mean) * rs * gg.w + bb.w;
  const size_t base = (size_t)row * DMODEL + tid * 4;
#pragma unroll
  for (int i = 0; i < 4; ++i) {
    unsigned short h = f2bf(y[i]);
    hi[base + i] = h;
    if (lo) lo[base + i] = f2bf(y[i] - bf2f(h));
    if (f32o) f32o[base + i] = y[i];
  }
}

// -------- RoPE -> split-bf16 Q [bh][L][64], K [bkvh][L][64] -----------------
// qkv arrives as 2 split-K slabs; fold the sum here (sole consumer of q/k part)
__global__ void rope_split(const float* __restrict__ qkv, const float* __restrict__ qkv2,
                           unsigned short* __restrict__ q_hi, unsigned short* __restrict__ q_lo,
                           unsigned short* __restrict__ k_hi, unsigned short* __restrict__ k_lo) {
  const int rowtok = blockIdx.x;
  const int b = rowtok >> 10;
  const int l = rowtok & 1023;
  const int tid = threadIdx.x;
  __shared__ float cb[32], sb[32];
  if (tid < 32) {
    float inv = powf(10000.0f, -(float)tid * (1.0f / 32.0f));
    float ang = (float)l * inv;
    cb[tid] = cosf(ang);
    sb[tid] = sinf(ang);
  }
  __syncthreads();
  const float* src  = qkv  + (size_t)rowtok * 1536;
  const float* src2 = qkv2 + (size_t)rowtok * 1536;
#pragma unroll
  for (int it = 0; it < 5; ++it) {
    const int e = tid + it * 256;
    const int hh = e >> 6;
    const int d = e & 63;
    const int dm = d & 31;
    float val = src[e] + src2[e];
    float partner = (d < 32) ? -(src[e + 32] + src2[e + 32]) : (src[e - 32] + src2[e - 32]);
    float ov = val * cb[dm] + partner * sb[dm];
    unsigned short hv = f2bf(ov);
    unsigned short lv = f2bf(ov - bf2f(hv));
    if (hh < 16) {
      size_t idx = ((size_t)(b * 16 + hh) * 1024 + l) * 64 + d;
      q_hi[idx] = hv; q_lo[idx] = lv;
    } else {
      size_t idx = ((size_t)(b * 4 + (hh - 16)) * 1024 + l) * 64 + d;
      k_hi[idx] = hv; k_lo[idx] = lv;
    }
  }
}

// -------- V transpose: qkv v-part [L][64] -> bf16 hi/lo [bkvh][64][L] -------
__global__ void vt_split(const float* __restrict__ qkv, const float* __restrict__ qkv2,
                         unsigned short* __restrict__ vt_hi, unsigned short* __restrict__ vt_lo) {
  const int bkvh = blockIdx.z;
  const int b = bkvh >> 2;
  const int kvh = bkvh & 3;
  const size_t sbase = (size_t)b * 1024 * 1536 + 1280 + kvh * 64;
  const float* src  = qkv  + sbase;
  const float* src2 = qkv2 + sbase;
  __shared__ float t[32][33];
  const int l0 = blockIdx.y * 32;
  const int d0 = blockIdx.x * 32;
  const int tx = threadIdx.x;
  const int ty = threadIdx.y;
#pragma unroll
  for (int i = 0; i < 4; ++i) {
    const size_t o = (size_t)(l0 + ty + i * 8) * 1536 + d0 + tx;
    t[ty + i * 8][tx] = src[o] + src2[o];
  }
  __syncthreads();
#pragma unroll
  for (int i = 0; i < 4; ++i) {
    float v = t[tx][ty + i * 8];
    size_t o = (size_t)bkvh * 65536 + (size_t)(d0 + ty + i * 8) * 1024 + l0 + tx;
    unsigned short h = f2bf(v);
    vt_hi[o] = h;
    vt_lo[o] = f2bf(v - bf2f(h));
  }
}

// ---------------- flash attention, split-bf16 MFMA, fp32 softmax ------------
__launch_bounds__(256, 2)
__global__ void attn_mfma(const unsigned short* __restrict__ q_hi, const unsigned short* __restrict__ q_lo,
                          const unsigned short* __restrict__ k_hi, const unsigned short* __restrict__ k_lo,
                          const unsigned short* __restrict__ vt_hi, const unsigned short* __restrict__ vt_lo,
                          unsigned short* __restrict__ ohi, unsigned short* __restrict__ olo) {
  const int blk = blockIdx.x;
  const int bh = blk & 31;               // (b,h)
  const int qt = 15 - (blk >> 5);        // long tiles dispatch first
  const int b = bh >> 4;
  const int h = bh & 15;
  const int kvbh = b * 4 + (h >> 2);
  const int q0 = qt * 64;
  const int tid = threadIdx.x;
  const int w = tid >> 6;
  const int lane = tid & 63;
  const int quad = lane >> 4;
  const int r16 = lane & 15;
  const int rl = lane >> 3;
  const int csl = lane & 7;
  const int cg = csl ^ rl;

  __shared__ unsigned short sK[2][64 * 64];
  __shared__ unsigned short sV[2][64 * 64];
  __shared__ unsigned short sP[2][64 * 64];

  short8 qfh[2], qfl[2];
  {
    const size_t qrow = ((size_t)bh * 1024 + q0 + w * 16 + r16) * 64 + quad * 8;
    qfh[0] = *(const short8*)(q_hi + qrow);
    qfh[1] = *(const short8*)(q_hi + qrow + 32);
    qfl[0] = *(const short8*)(q_lo + qrow);
    qfl[1] = *(const short8*)(q_lo + qrow + 32);
  }
  float4v O[4];
#pragma unroll
  for (int nt = 0; nt < 4; ++nt) O[nt] = float4v{0.f, 0.f, 0.f, 0.f};
  float m[4], l[4];
#pragma unroll
  for (int rg = 0; rg < 4; ++rg) { m[rg] = -__builtin_inff(); l[rg] = 0.f; }

  const unsigned short* khb = k_hi + (size_t)kvbh * 65536 + cg * 8;
  const unsigned short* klb = k_lo + (size_t)kvbh * 65536 + cg * 8;
  const unsigned short* vhb = vt_hi + (size_t)kvbh * 65536 + cg * 8;
  const unsigned short* vlb = vt_lo + (size_t)kvbh * 65536 + cg * 8;

  for (int c = 0; c <= qt; ++c) {
    __syncthreads();
#pragma unroll
    for (int j = 0; j < 2; ++j) {
      const int i = w * 2 + j;
      const int row = i * 8 + rl;
      gl_lds16(khb + (size_t)(c * 64 + row) * 64, (char*)sK[0] + i * 1024);
      gl_lds16(klb + (size_t)(c * 64 + row) * 64, (char*)sK[1] + i * 1024);
      gl_lds16(vhb + (size_t)row * 1024 + c * 64, (char*)sV[0] + i * 1024);
      gl_lds16(vlb + (size_t)row * 1024 + c * 64, (char*)sV[1] + i * 1024);
    }
    __syncthreads();

    float4v S[4];
#pragma unroll
    for (int nt = 0; nt < 4; ++nt) S[nt] = float4v{0.f, 0.f, 0.f, 0.f};
#pragma unroll
    for (int ks = 0; ks < 2; ++ks) {
#pragma unroll
      for (int nt = 0; nt < 4; ++nt) {
        const int r = nt * 16 + r16;
        const int o = (r * 8 + ((ks * 4 + quad) ^ (r & 7))) * 8;
        const short8 kh = *(const short8*)(sK[0] + o);
        const short8 kl = *(const short8*)(sK[1] + o);
        S[nt] = __builtin_amdgcn_mfma_f32_16x16x32_bf16(qfh[ks], kh, S[nt], 0, 0, 0);
        S[nt] = __builtin_amdgcn_mfma_f32_16x16x32_bf16(qfh[ks], kl, S[nt], 0, 0, 0);
        S[nt] = __builtin_amdgcn_mfma_f32_16x16x32_bf16(qfl[ks], kh, S[nt], 0, 0, 0);
      }
    }
    const float NEGINF = -__builtin_inff();
#pragma unroll
    for (int nt = 0; nt < 4; ++nt)
#pragma unroll
      for (int rg = 0; rg < 4; ++rg) S[nt][rg] *= 0.125f;
    if (c == qt) {
#pragma unroll
      for (int nt = 0; nt < 4; ++nt) {
        const int col = nt * 16 + r16;
#pragma unroll
        for (int rg = 0; rg < 4; ++rg) {
          const int row = w * 16 + quad * 4 + rg;
          if (col > row) S[nt][rg] = NEGINF;
        }
      }
    }
    float alpha[4], lsum[4];
#pragma unroll
    for (int rg = 0; rg < 4; ++rg) {
      float mx = fmaxf(fmaxf(S[0][rg], S[1][rg]), fmaxf(S[2][rg], S[3][rg]));
      mx = fmaxf(mx, __shfl_xor(mx, 1));
      mx = fmaxf(mx, __shfl_xor(mx, 2));
      mx = fmaxf(mx, __shfl_xor(mx, 4));
      mx = fmaxf(mx, __shfl_xor(mx, 8));
      const float mn = fmaxf(m[rg], mx);
      alpha[rg] = __expf(m[rg] - mn);
      m[rg] = mn;
      lsum[rg] = 0.f;
    }
#pragma unroll
    for (int nt = 0; nt < 4; ++nt)
#pragma unroll
      for (int rg = 0; rg < 4; ++rg) {
        const float e = __expf(S[nt][rg] - m[rg]);
        S[nt][rg] = e;
        lsum[rg] += e;
      }
#pragma unroll
    for (int rg = 0; rg < 4; ++rg) {
      float ls = lsum[rg];
      ls += __shfl_xor(ls, 1);
      ls += __shfl_xor(ls, 2);
      ls += __shfl_xor(ls, 4);
      ls += __shfl_xor(ls, 8);
      l[rg] = l[rg] * alpha[rg] + ls;
    }
#pragma unroll
    for (int nt = 0; nt < 4; ++nt) {
      const int key = nt * 16 + r16;
      const int chunk = key >> 3;
#pragma unroll
      for (int rg = 0; rg < 4; ++rg) {
        const int r = w * 16 + quad * 4 + rg;
        const int addr = r * 64 + ((chunk ^ (r & 7)) * 8) + (key & 7);
        const float e = S[nt][rg];
        const unsigned short hv = f2bf(e);
        sP[0][addr] = hv;
        sP[1][addr] = f2bf(e - bf2f(hv));
      }
    }
#pragma unroll
    for (int nt = 0; nt < 4; ++nt)
#pragma unroll
      for (int rg = 0; rg < 4; ++rg) O[nt][rg] *= alpha[rg];
#pragma unroll
    for (int ks = 0; ks < 2; ++ks) {
      const int rA = w * 16 + r16;
      const int oA = (rA * 8 + ((ks * 4 + quad) ^ (rA & 7))) * 8;
      const short8 ph = *(const short8*)(sP[0] + oA);
      const short8 pl = *(const short8*)(sP[1] + oA);
#pragma unroll
      for (int nt = 0; nt < 4; ++nt) {
        const int rv = nt * 16 + r16;
        const int ov = (rv * 8 + ((ks * 4 + quad) ^ (rv & 7))) * 8;
        const short8 vh = *(const short8*)(sV[0] + ov);
        const short8 vl = *(const short8*)(sV[1] + ov);
        O[nt] = __builtin_amdgcn_mfma_f32_16x16x32_bf16(ph, vh, O[nt], 0, 0, 0);
        O[nt] = __builtin_amdgcn_mfma_f32_16x16x32_bf16(ph, vl, O[nt], 0, 0, 0);
        O[nt] = __builtin_amdgcn_mfma_f32_16x16x32_bf16(pl, vh, O[nt], 0, 0, 0);
      }
    }
  }
#pragma unroll
  for (int nt = 0; nt < 4; ++nt) {
    const int col = h * 64 + nt * 16 + r16;
#pragma unroll
    for (int rg = 0; rg < 4; ++rg) {
      const int row = q0 + w * 16 + quad * 4 + rg;
      const float ovv = O[nt][rg] / l[rg];
      const size_t idx = ((size_t)b * 1024 + row) * DMODEL + col;
      const unsigned short hv = f2bf(ovv);
      ohi[idx] = hv;
      olo[idx] = f2bf(ovv - bf2f(hv));
    }
  }
}

// ----- x1 = x + sum of 4 wo-GEMM split-K partial slabs ----------------------
__global__ void merge_x1(const float* __restrict__ x, const float* __restrict__ parts,
                         float* __restrict__ x1) {
  const size_t i = ((size_t)blockIdx.x * 256 + threadIdx.x) * 4;
  float4 r = *(const float4*)(x + i);
#pragma unroll
  for (int z = 0; z < 4; ++z) {
    const float4 p = *(const float4*)(parts + (size_t)z * NTOK * DMODEL + i);
    r.x += p.x; r.y += p.y; r.z += p.z; r.w += p.w;
  }
  *(float4*)(x1 + i) = r;
}

// ---------------- router: fp32 logits, top-2, gates, counts -----------------
#define RED6SUM(X) { X += __shfl_xor(X,32); X += __shfl_xor(X,16); X += __shfl_xor(X,8); X += __shfl_xor(X,4); X += __shfl_xor(X,2); X += __shfl_xor(X,1); }

__global__ void router_kernel(const float* __restrict__ h2f, const float* __restrict__ wg,
                              int* __restrict__ tok_e, float* __restrict__ tok_g,
                              int* __restrict__ counts) {
  const int t = blockIdx.x;
  const int lane = threadIdx.x;
  float acc[8] = {0,0,0,0,0,0,0,0};
  const float* hr = h2f + (size_t)t * DMODEL;
  for (int d = lane; d < DMODEL; d += 64) {
    const float hv = hr[d];
    const float4 w0 = *(const float4*)(wg + d * 8);
    const float4 w1_ = *(const float4*)(wg + d * 8 + 4);
    acc[0] += hv * w0.x; acc[1] += hv * w0.y; acc[2] += hv * w0.z; acc[3] += hv * w0.w;
    acc[4] += hv * w1_.x; acc[5] += hv * w1_.y; acc[6] += hv * w1_.z; acc[7] += hv * w1_.w;
  }
#pragma unroll
  for (int e = 0; e < 8; ++e) { RED6SUM(acc[e]); }
  if (lane == 0) {
    int i0 = 0; float v0 = acc[0];
#pragma unroll
    for (int e = 1; e < 8; ++e) if (acc[e] > v0) { v0 = acc[e]; i0 = e; }
    int i1 = -1; float v1 = -__builtin_inff();
#pragma unroll
    for (int e = 0; e < 8; ++e) if (e != i0 && acc[e] > v1) { v1 = acc[e]; i1 = e; }
    const float ex = __expf(v1 - v0);
    const float den = 1.0f + ex;
    tok_e[t * 2] = i0; tok_e[t * 2 + 1] = i1;
    tok_g[t * 2] = 1.0f / den; tok_g[t * 2 + 1] = ex / den;
    atomicAdd(counts + i0, 1);
    atomicAdd(counts + i1, 1);
  }
}

__global__ void finalize_kernel(const int* __restrict__ counts, int* __restrict__ off_pad,
                                int* __restrict__ tile_map, float* __restrict__ lb_out) {
  if (threadIdx.x == 0 && blockIdx.x == 0) {
    int tile = 0, rowoff = 0;
    for (int e = 0; e < NEXP; ++e) {
      off_pad[e] = rowoff;
      const int c = counts[e];
      const int nt = (c + 127) >> 7;
      for (int i = 0; i < nt; ++i) tile_map[tile++] = e;
      rowoff += nt * 128;
    }
    for (; tile < MAXTILES; ++tile) tile_map[tile] = -1;
    float sacc = 0.f;
    for (int e = 0; e < NEXP; ++e) {
      const float cn = (float)counts[e] * (1.0f / 4096.0f);
      const float d = cn - 0.125f;
      sacc += d * d;
    }
    lb_out[0] = sacc * (1.0f / 8.0f);
  }
}

__global__ void scatter_kernel(const int* __restrict__ tok_e, const int* __restrict__ off_pad,
                               int* __restrict__ fill, int* __restrict__ tok_pos,
                               const unsigned short* __restrict__ h2bf, unsigned short* __restrict__ Xg) {
  const int slot = blockIdx.x;
  const int t = slot >> 1;
  __shared__ int sp;
  if (threadIdx.x == 0) {
    const int e = tok_e[slot];
    const int r = atomicAdd(fill + e, 1);
    const int ppos = off_pad[e] + r;
    tok_pos[slot] = ppos;
    sp = ppos;
  }
  __syncthreads();
  const int pos = sp;
  *(uint2*)(Xg + (size_t)pos * DMODEL + threadIdx.x * 4) =
      *(const uint2*)(h2bf + (size_t)t * DMODEL + threadIdx.x * 4);
}

// ----- combine: out = x1 + g0*sum_z eout_z[p0] + g1*sum_z eout_z[p1] --------
__global__ void combine_kernel(const float* __restrict__ x1, const float* __restrict__ eout,
                               const int* __restrict__ tok_pos, const float* __restrict__ tok_g,
                               float* __restrict__ out) {
  const int t = blockIdx.x;
  const int tid = threadIdx.x;
  const int p0 = tok_pos[t * 2], p1 = tok_pos[t * 2 + 1];
  const float g0 = tok_g[t * 2], g1 = tok_g[t * 2 + 1];
  const size_t o = (size_t)t * DMODEL + tid * 4;
  const float4 a = *(const float4*)(x1 + o);
  float s0x = 0.f, s0y = 0.f, s0z = 0.f, s0w = 0.f;
  float s1x = 0.f, s1y = 0.f, s1z = 0.f, s1w = 0.f;
#pragma unroll
  for (int z = 0; z < 4; ++z) {
    const size_t zb = (size_t)z * MAXROWS * DMODEL;
    const float4 e0 = *(const float4*)(eout + zb + (size_t)p0 * DMODEL + tid * 4);
    const float4 e1 = *(const float4*)(eout + zb + (size_t)p1 * DMODEL + tid * 4);
    s0x += e0.x; s0y += e0.y; s0z += e0.z; s0w += e0.w;
    s1x += e1.x; s1y += e1.y; s1z += e1.z; s1w += e1.w;
  }
  float4 r;
  r.x = a.x + g0 * s0x + g1 * s1x;
  r.y = a.y + g0 * s0y + g1 * s1y;
  r.z = a.z + g0 * s0z + g1 * s1z;
  r.w = a.w + g0 * s0w + g1 * s1w;
  *(float4*)(out + o) = r;
}

__global__ void init_kernel(int* counts, int* fill) {
  const int t = threadIdx.x;
  if (t < 8) { counts[t] = 0; fill[t] = 0; }
}

extern "C" void kernel_launch(void* const* d_in, const int* in_sizes, int n_in,
                              void* d_out, int out_size, void* d_ws, size_t ws_size,
                              hipStream_t stream) {
  (void)in_sizes; (void)n_in; (void)out_size; (void)ws_size;
  const float* x    = (const float*)d_in[0];
  const float* wq   = (const float*)d_in[1];
  const float* wk   = (const float*)d_in[2];
  const float* wv   = (const float*)d_in[3];
  const float* wo   = (const float*)d_in[4];
  const float* wg   = (const float*)d_in[5];
  const float* w1   = (const float*)d_in[6];
  const float* w2   = (const float*)d_in[7];
  const float* ln1g = (const float*)d_in[8];
  const float* ln1b = (const float*)d_in[9];
  const float* ln2g = (const float*)d_in[10];
  const float* ln2b = (const float*)d_in[11];
  float* out = (float*)d_out;

  char* p = (char*)d_ws;
  auto take = [&](size_t n) { void* r = (void*)p; p += (n + 255) & ~(size_t)255; return r; };
  unsigned short* h1_hi   = (unsigned short*)take((size_t)NTOK * DMODEL * 2);
  unsigned short* h1_lo   = (unsigned short*)take((size_t)NTOK * DMODEL * 2);
  unsigned short* wqkv_hi = (unsigned short*)take((size_t)1536 * 1024 * 2);
  unsigned short* wqkv_lo = (unsigned short*)take((size_t)1536 * 1024 * 2);
  unsigned short* woT_hi  = (unsigned short*)take((size_t)1024 * 1024 * 2);
  unsigned short* woT_lo  = (unsigned short*)take((size_t)1024 * 1024 * 2);
  unsigned short* w1t     = (unsigned short*)take((size_t)NEXP * DFF * DMODEL * 2);
  unsigned short* w2t     = (unsigned short*)take((size_t)NEXP * DMODEL * DFF * 2);
  float* qkv   = (float*)take((size_t)2 * NTOK * 1536 * 4);          // 2 split-K slabs
  unsigned short* q_hi  = (unsigned short*)take((size_t)2 * 16 * 1024 * 64 * 2);
  unsigned short* q_lo  = (unsigned short*)take((size_t)2 * 16 * 1024 * 64 * 2);
  unsigned short* k_hi  = (unsigned short*)take((size_t)2 * 4 * 1024 * 64 * 2);
  unsigned short* k_lo  = (unsigned short*)take((size_t)2 * 4 * 1024 * 64 * 2);
  unsigned short* vt_hi = (unsigned short*)take((size_t)2 * 4 * 1024 * 64 * 2);
  unsigned short* vt_lo = (unsigned short*)take((size_t)2 * 4 * 1024 * 64 * 2);
  unsigned short* attn_hi = (unsigned short*)take((size_t)NTOK * DMODEL * 2);
  unsigned short* attn_lo = (unsigned short*)take((size_t)NTOK * DMODEL * 2);
  float* x1p   = (float*)take((size_t)4 * NTOK * DMODEL * 4);        // 4 split-K slabs
  float* x1    = (float*)take((size_t)NTOK * DMODEL * 4);
  float* h2f   = (float*)take((size_t)NTOK * DMODEL * 4);
  unsigned short* h2bf = (unsigned short*)take((size_t)NTOK * DMODEL * 2);
  unsigned short* Xg   = (unsigned short*)take((size_t)MAXROWS * DMODEL * 2);
  unsigned short* hid  = (unsigned short*)take((size_t)MAXROWS * DFF * 2);
  float* eout  = (float*)take((size_t)4 * MAXROWS * DMODEL * 4);     // 4 split-K slabs
  int*   tok_e   = (int*)take(4096 * 4);
  float* tok_g   = (float*)take(4096 * 4);
  int*   tok_pos = (int*)take(4096 * 4);
  int*   counts  = (int*)take(64);
  int*   fill    = (int*)take(64);
  int*   off_pad = (int*)take(64);
  int*   tile_map = (int*)take(256);

  init_kernel<<<1, 64, 0, stream>>>(counts, fill);
  ln_kernel<<<NTOK, 256, 0, stream>>>(x, ln1g, ln1b, h1_hi, h1_lo, nullptr);
  transpose_w<1><<<dim3(16, 16, 1), 256, 0, stream>>>(wq, wqkv_hi, wqkv_lo, 1024, 1024, 0, 0);
  transpose_w<1><<<dim3(4, 16, 1), 256, 0, stream>>>(wk, wqkv_hi + (size_t)1024 * 1024, wqkv_lo + (size_t)1024 * 1024, 1024, 256, 0, 0);
  transpose_w<1><<<dim3(4, 16, 1), 256, 0, stream>>>(wv, wqkv_hi + (size_t)1280 * 1024, wqkv_lo + (size_t)1280 * 1024, 1024, 256, 0, 0);
  transpose_w<1><<<dim3(16, 16, 1), 256, 0, stream>>>(wo, woT_hi, woT_lo, 1024, 1024, 0, 0);
  transpose_w<0><<<dim3(64, 16, 8), 256, 0, stream>>>(w1, w1t, nullptr, 1024, 4096, (long)1024 * 4096, (long)4096 * 1024);
  transpose_w<0><<<dim3(16, 64, 8), 256, 0, stream>>>(w2, w2t, nullptr, 4096, 1024, (long)4096 * 1024, (long)1024 * 4096);
  // qkv = h1 @ [wq|wk|wv], split-K x2 (384 blocks), XCD-swizzled
  gemm_split<<<dim3(12, 16, 2), 256, 0, stream>>>(h1_hi, h1_lo, wqkv_hi, wqkv_lo, qkv, 1536, 1024, 512, (long)NTOK * 1536);
  rope_split<<<NTOK, 256, 0, stream>>>(qkv, qkv + (size_t)NTOK * 1536, q_hi, q_lo, k_hi, k_lo);
  vt_split<<<dim3(2, 32, 8), dim3(32, 8), 0, stream>>>(qkv, qkv + (size_t)NTOK * 1536, vt_hi, vt_lo);
  attn_mfma<<<512, 256, 0, stream>>>(q_hi, q_lo, k_hi, k_lo, vt_hi, vt_lo, attn_hi, attn_lo);
  // wo projection: split-K x4 (512 blocks); residual folded in merge_x1
  gemm_split<<<dim3(8, 16, 4), 256, 0, stream>>>(attn_hi, attn_lo, woT_hi, woT_lo, x1p, 1024, 1024, 256, (long)NTOK * DMODEL);
  merge_x1<<<2048, 256, 0, stream>>>(x, x1p, x1);
  ln_kernel<<<NTOK, 256, 0, stream>>>(x1, ln2g, ln2b, h2bf, nullptr, h2f);
  router_kernel<<<NTOK, 64, 0, stream>>>(h2f, wg, tok_e, tok_g, counts);
  finalize_kernel<<<1, 64, 0, stream>>>(counts, off_pad, tile_map, out + (size_t)NTOK * DMODEL);
  scatter_kernel<<<4096, 256, 0, stream>>>(tok_e, off_pad, fill, tok_pos, h2bf, Xg);
  // w1 GEMM: gelu epilogue now tanh-form (cheap), XCD-swizzled
  gemm_bt<3,1><<<dim3(32, MAXTILES), 256, 0, stream>>>(Xg, w1t, nullptr, hid, DFF, DMODEL, DMODEL, 0, tile_map, (long)DFF * DMODEL);
  // expert down-proj: split-K x4 (1280 blocks), XCD-swizzled
  gemm_bt<0,1><<<dim3(8, MAXTILES, 4), 256, 0, stream>>>(hid, w2t, eout, nullptr, DMODEL, DFF, 1024, (long)MAXROWS * DMODEL, tile_map, (long)DMODEL * DFF);
  combine_kernel<<<NTOK, 256, 0, stream>>>(x1, eout, tok_pos, tok_g, out);
}

// Round 5
// 706.378 us; speedup vs baseline: 1.4576x; 1.4576x over previous
//
#include <hip/hip_runtime.h>
#include <hip/hip_bf16.h>

#define NTOK   2048      // B*L
#define DMODEL 1024
#define NEXP   8
#define DFF    4096
#define MAXROWS 5120
#define MAXTILES 40

typedef __attribute__((ext_vector_type(8))) short short8;
typedef __attribute__((ext_vector_type(4))) float float4v;

__device__ __forceinline__ unsigned short f2bf(float f) {
  union { float f; unsigned u; } v; v.f = f;
  unsigned r = v.u + 0x7fffu + ((v.u >> 16) & 1u);
  return (unsigned short)(r >> 16);
}
__device__ __forceinline__ float bf2f(unsigned short h) {
  union { unsigned u; float f; } v; v.u = ((unsigned)h) << 16; return v.f;
}
__device__ __forceinline__ void gl_lds16(const void* g, void* l) {
  __builtin_amdgcn_global_load_lds((const __attribute__((address_space(1))) void*)g,
                                   (__attribute__((address_space(3))) void*)l, 16, 0, 0);
}

// bijective XCD swizzle: consecutive HW bids round-robin over 8 XCDs; give each
// XCD a contiguous chunk of logical tile space (requires nwg % 8 == 0).
__device__ __forceinline__ int xcd_swz(int bid, int nwg) {
  if (nwg & 7) return bid;
  const int chunk = nwg >> 3;
  return (bid & 7) * chunk + (bid >> 3);
}

// ---------------- GEMM: C[M,N] = A[M,K](bf16) x B[N,K]^T(bf16), fp32 acc ---
// EPI: 0 C=acc ; 3 Cbf=bf16(gelu(acc))
// split-K: z covers k in [z*kslice, (z+1)*kslice), partial C slab at z*zstride
// launch_bounds(256,4): 4 waves/EU -> 128-reg budget; kernel needs ~60 VGPR +
// 64 AGPR acc. (256,5) caps at ~102 regs and SPILLS the accumulator to
// scratch: R3 measured WRITE_SIZE 38->303 MB, 78->253us. Do not raise.
template<int EPI, int EMAP>
__launch_bounds__(256, 4)
__global__ void gemm_bt(const unsigned short* __restrict__ A,
                        const unsigned short* __restrict__ B0,
                        float* __restrict__ C,
                        unsigned short* __restrict__ Cbf,
                        const int N, const int K,
                        const int kslice, const long zstride,
                        const int* __restrict__ tmap, const long estride) {
  // ---- XCD-swizzled logical tile id ----
  const int gx = gridDim.x, gy = gridDim.y;
  const int nwg = gx * gy * gridDim.z;
  const int lid = xcd_swz(blockIdx.x + gx * (blockIdx.y + gy * blockIdx.z), nwg);
  const int bx = lid % gx;
  const int t1 = lid / gx;
  const int mtile = t1 % gy;
  const int bz = t1 / gy;

  const unsigned short* B = B0;
  if (EMAP) {
    int e = tmap[mtile];
    if (e < 0) return;
    B += (size_t)e * (size_t)estride;
  }
  const int n0 = bx * 128;
  const int m0 = mtile * 128;
  if (EPI == 0) C += (size_t)bz * (size_t)zstride;
  __shared__ unsigned short sA[128 * 64];
  __shared__ unsigned short sB[128 * 64];
  const int tid  = threadIdx.x;
  const int w    = tid >> 6;
  const int lane = tid & 63;
  const int quad = lane >> 4;
  const int r16  = lane & 15;
  const int wr   = w >> 1;
  const int wc   = w & 1;
  const int rl   = lane >> 3;
  const int csl  = lane & 7;
  const int cg   = csl ^ rl;
  float4v acc[4][4];
#pragma unroll
  for (int i = 0; i < 4; ++i)
#pragma unroll
    for (int j = 0; j < 4; ++j) acc[i][j] = float4v{0.f, 0.f, 0.f, 0.f};

  const unsigned short* Ab = A + (size_t)m0 * K + cg * 8;
  const unsigned short* Bb = B + (size_t)n0 * K + cg * 8;

  const int kbeg = bz * kslice;
  const int kend = kbeg + kslice;
  for (int k0 = kbeg; k0 < kend; k0 += 64) {
    __syncthreads();
#pragma unroll
    for (int i = 0; i < 4; ++i) {
      const int j = w * 4 + i;
      gl_lds16(Ab + (size_t)(j * 8 + rl) * K + k0, (char*)sA + j * 1024);
      gl_lds16(Bb + (size_t)(j * 8 + rl) * K + k0, (char*)sB + j * 1024);
    }
    __syncthreads();
#pragma unroll
    for (int kc = 0; kc < 8; kc += 4) {
      short8 af[4], bq[4];
#pragma unroll
      for (int mt = 0; mt < 4; ++mt) {
        int r = wr * 64 + mt * 16 + r16;
        af[mt] = *(const short8*)(sA + ((r * 8 + ((kc + quad) ^ (r & 7))) * 8));
      }
#pragma unroll
      for (int nt = 0; nt < 4; ++nt) {
        int r = wc * 64 + nt * 16 + r16;
        bq[nt] = *(const short8*)(sB + ((r * 8 + ((kc + quad) ^ (r & 7))) * 8));
      }
#pragma unroll
      for (int mt = 0; mt < 4; ++mt)
#pragma unroll
        for (int nt = 0; nt < 4; ++nt)
          acc[mt][nt] = __builtin_amdgcn_mfma_f32_16x16x32_bf16(af[mt], bq[nt], acc[mt][nt], 0, 0, 0);
    }
  }
#pragma unroll
  for (int mt = 0; mt < 4; ++mt) {
#pragma unroll
    for (int nt = 0; nt < 4; ++nt) {
#pragma unroll
      for (int rg = 0; rg < 4; ++rg) {
        const int m = m0 + wr * 64 + mt * 16 + quad * 4 + rg;
        const int n = n0 + wc * 64 + nt * 16 + r16;
        const size_t idx = (size_t)m * N + n;
        const float v = acc[mt][nt][rg];
        if (EPI == 0) C[idx] = v;
        else {
          // tanh-form gelu: x*sigmoid(1.5958(x+0.044715x^3)); |err| ~1e-4,
          // far below hid's bf16 quantization. Replaces ~25-op erff.
          const float u = v + 0.044715f * v * v * v;
          const float ge = v / (1.0f + __expf(-1.5957691216f * u));
          Cbf[idx] = f2bf(ge);
        }
      }
    }
  }
}

// ------- split-bf16 GEMM: C = (Ah+Al)x(Bh+Bl)^T, 3 terms, split-K slabs -----
__launch_bounds__(256, 2)
__global__ void gemm_split(const unsigned short* __restrict__ Ah,
                           const unsigned short* __restrict__ Al,
                           const unsigned short* __restrict__ Bh,
                           const unsigned short* __restrict__ Bl,
                           float* __restrict__ C,
                           const int N, const int K,
                           const int kslice, const long zstride) {
  const int gx = gridDim.x, gy = gridDim.y;
  const int nwg = gx * gy * gridDim.z;
  const int lid = xcd_swz(blockIdx.x + gx * (blockIdx.y + gy * blockIdx.z), nwg);
  const int bx = lid % gx;
  const int t1 = lid / gx;
  const int by = t1 % gy;
  const int bz = t1 / gy;

  const int n0 = bx * 128;
  const int m0 = by * 128;
  C += (size_t)bz * (size_t)zstride;
  __shared__ unsigned short sAh[128 * 64];
  __shared__ unsigned short sAl[128 * 64];
  __shared__ unsigned short sBh[128 * 64];
  __shared__ unsigned short sBl[128 * 64];
  const int tid  = threadIdx.x;
  const int w    = tid >> 6;
  const int lane = tid & 63;
  const int quad = lane >> 4;
  const int r16  = lane & 15;
  const int wr   = w >> 1;
  const int wc   = w & 1;
  const int rl   = lane >> 3;
  const int csl  = lane & 7;
  const int cg   = csl ^ rl;
  float4v acc[4][4];
#pragma unroll
  for (int i = 0; i < 4; ++i)
#pragma unroll
    for (int j = 0; j < 4; ++j) acc[i][j] = float4v{0.f, 0.f, 0.f, 0.f};

  const size_t aoff = (size_t)m0 * K + cg * 8;
  const size_t boff = (size_t)n0 * K + cg * 8;

  const int kbeg = bz * kslice;
  const int kend = kbeg + kslice;
  for (int k0 = kbeg; k0 < kend; k0 += 64) {
    __syncthreads();
#pragma unroll
    for (int i = 0; i < 4; ++i) {
      const int j = w * 4 + i;
      const size_t ro = (size_t)(j * 8 + rl) * K + k0;
      gl_lds16(Ah + aoff + ro, (char*)sAh + j * 1024);
      gl_lds16(Al + aoff + ro, (char*)sAl + j * 1024);
      gl_lds16(Bh + boff + ro, (char*)sBh + j * 1024);
      gl_lds16(Bl + boff + ro, (char*)sBl + j * 1024);
    }
    __syncthreads();
#pragma unroll
    for (int kc = 0; kc < 8; kc += 4) {
      short8 afh[4], afl[4], bqh[4], bql[4];
#pragma unroll
      for (int mt = 0; mt < 4; ++mt) {
        int r = wr * 64 + mt * 16 + r16;
        int o = (r * 8 + ((kc + quad) ^ (r & 7))) * 8;
        afh[mt] = *(const short8*)(sAh + o);
        afl[mt] = *(const short8*)(sAl + o);
      }
#pragma unroll
      for (int nt = 0; nt < 4; ++nt) {
        int r = wc * 64 + nt * 16 + r16;
        int o = (r * 8 + ((kc + quad) ^ (r & 7))) * 8;
        bqh[nt] = *(const short8*)(sBh + o);
        bql[nt] = *(const short8*)(sBl + o);
      }
#pragma unroll
      for (int mt = 0; mt < 4; ++mt)
#pragma unroll
        for (int nt = 0; nt < 4; ++nt) {
          acc[mt][nt] = __builtin_amdgcn_mfma_f32_16x16x32_bf16(afh[mt], bqh[nt], acc[mt][nt], 0, 0, 0);
          acc[mt][nt] = __builtin_amdgcn_mfma_f32_16x16x32_bf16(afh[mt], bql[nt], acc[mt][nt], 0, 0, 0);
          acc[mt][nt] = __builtin_amdgcn_mfma_f32_16x16x32_bf16(afl[mt], bqh[nt], acc[mt][nt], 0, 0, 0);
        }
    }
  }
#pragma unroll
  for (int mt = 0; mt < 4; ++mt) {
#pragma unroll
    for (int nt = 0; nt < 4; ++nt) {
#pragma unroll
      for (int rg = 0; rg < 4; ++rg) {
        const int m = m0 + wr * 64 + mt * 16 + quad * 4 + rg;
        const int n = n0 + wc * 64 + nt * 16 + r16;
        C[(size_t)m * N + n] = acc[mt][nt][rg];
      }
    }
  }
}

// ------ fp32 [K,N] -> bf16 [N,K] (hi, optional lo), 64x64, vectorized -------
template<int WLO>
__global__ void transpose_w(const float* __restrict__ in, unsigned short* __restrict__ oh,
                            unsigned short* __restrict__ ol, const int K, const int N,
                            const long istride, const long ostride) {
  const int bz = blockIdx.z;
  in += (size_t)bz * istride;
  oh += (size_t)bz * ostride;
  if (WLO) ol += (size_t)bz * ostride;
  __shared__ float t[64][65];
  const int n0 = blockIdx.x * 64;
  const int k0 = blockIdx.y * 64;
  const int tid = threadIdx.x;
  const int rr = tid >> 4;        // 0..15
  const int c4 = (tid & 15) * 4;  // 0..60
#pragma unroll
  for (int p = 0; p < 4; ++p) {
    const int row = p * 16 + rr;
    const float4 v = *(const float4*)(in + (size_t)(k0 + row) * N + n0 + c4);
    t[row][c4] = v.x; t[row][c4 + 1] = v.y; t[row][c4 + 2] = v.z; t[row][c4 + 3] = v.w;
  }
  __syncthreads();
#pragma unroll
  for (int p = 0; p < 4; ++p) {
    const int n = p * 16 + rr;
    float vs[4];
#pragma unroll
    for (int i = 0; i < 4; ++i) vs[i] = t[c4 + i][n];
    ushort4 h;
    h.x = f2bf(vs[0]); h.y = f2bf(vs[1]); h.z = f2bf(vs[2]); h.w = f2bf(vs[3]);
    const size_t o = (size_t)(n0 + n) * K + k0 + c4;
    *(ushort4*)(oh + o) = h;
    if (WLO) {
      ushort4 lo4;
      lo4.x = f2bf(vs[0] - bf2f(h.x));
      lo4.y = f2bf(vs[1] - bf2f(h.y));
      lo4.z = f2bf(vs[2] - bf2f(h.z));
      lo4.w = f2bf(vs[3] - bf2f(h.w));
      *(ushort4*)(ol + o) = lo4;
    }
  }
}

// ---------------- LayerNorm over D=1024 -------------------------------------
__global__ void ln_kernel(const float* __restrict__ x, const float* __restrict__ g,
                          const float* __restrict__ b, unsigned short* __restrict__ hi,
                          unsigned short* __restrict__ lo, float* __restrict__ f32o) {
  const int row = blockIdx.x;
  const int tid = threadIdx.x;
  const int w = tid >> 6, lane = tid & 63;
  const float4 v = *(const float4*)(x + (size_t)row * DMODEL + tid * 4);
  float s = v.x + v.y + v.z + v.w;
  float q = v.x * v.x + v.y * v.y + v.z * v.z + v.w * v.w;
#pragma unroll
  for (int o = 32; o; o >>= 1) { s += __shfl_xor(s, o); q += __shfl_xor(q, o); }
  __shared__ float red[8];
  if (lane == 0) { red[w] = s; red[4 + w] = q; }
  __syncthreads();
  s = red[0] + red[1] + red[2] + red[3];
  q = red[4] + red[5] + red[6] + red[7];
  const float mean = s * (1.0f / DMODEL);
  const float var = q * (1.0f / DMODEL) - mean * mean;
  const float rs = rsqrtf(var + 1e-5f);
  const float4 gg = *(const float4*)(g + tid * 4);
  const float4 bb = *(const float4*)(b + tid * 4);
  float y[4];
  y[0] = (v.x - mean) * rs * gg.x + bb.x;
  y[1] = (v.y - mean) * rs * gg.y + bb.y;
  y[2] = (v.z - mean) * rs * gg.z + bb.z;
  y[3] = (v.w - mean) * rs * gg.w + bb.w;
  const size_t base = (size_t)row * DMODEL + tid * 4;
#pragma unroll
  for (int i = 0; i < 4; ++i) {
    unsigned short h = f2bf(y[i]);
    hi[base + i] = h;
    if (lo) lo[base + i] = f2bf(y[i] - bf2f(h));
    if (f32o) f32o[base + i] = y[i];
  }
}

// -------- RoPE -> split-bf16 Q [bh][L][64], K [bkvh][L][64] -----------------
// qkv arrives as 2 split-K slabs; fold the sum here (sole consumer of q/k part)
__global__ void rope_split(const float* __restrict__ qkv, const float* __restrict__ qkv2,
                           unsigned short* __restrict__ q_hi, unsigned short* __restrict__ q_lo,
                           unsigned short* __restrict__ k_hi, unsigned short* __restrict__ k_lo) {
  const int rowtok = blockIdx.x;
  const int b = rowtok >> 10;
  const int l = rowtok & 1023;
  const int tid = threadIdx.x;
  __shared__ float cb[32], sb[32];
  if (tid < 32) {
    float inv = powf(10000.0f, -(float)tid * (1.0f / 32.0f));
    float ang = (float)l * inv;
    cb[tid] = cosf(ang);
    sb[tid] = sinf(ang);
  }
  __syncthreads();
  const float* src  = qkv  + (size_t)rowtok * 1536;
  const float* src2 = qkv2 + (size_t)rowtok * 1536;
#pragma unroll
  for (int it = 0; it < 5; ++it) {
    const int e = tid + it * 256;
    const int hh = e >> 6;
    const int d = e & 63;
    const int dm = d & 31;
    float val = src[e] + src2[e];
    float partner = (d < 32) ? -(src[e + 32] + src2[e + 32]) : (src[e - 32] + src2[e - 32]);
    float ov = val * cb[dm] + partner * sb[dm];
    unsigned short hv = f2bf(ov);
    unsigned short lv = f2bf(ov - bf2f(hv));
    if (hh < 16) {
      size_t idx = ((size_t)(b * 16 + hh) * 1024 + l) * 64 + d;
      q_hi[idx] = hv; q_lo[idx] = lv;
    } else {
      size_t idx = ((size_t)(b * 4 + (hh - 16)) * 1024 + l) * 64 + d;
      k_hi[idx] = hv; k_lo[idx] = lv;
    }
  }
}

// -------- V transpose: qkv v-part [L][64] -> bf16 hi/lo [bkvh][64][L] -------
__global__ void vt_split(const float* __restrict__ qkv, const float* __restrict__ qkv2,
                         unsigned short* __restrict__ vt_hi, unsigned short* __restrict__ vt_lo) {
  const int bkvh = blockIdx.z;
  const int b = bkvh >> 2;
  const int kvh = bkvh & 3;
  const size_t sbase = (size_t)b * 1024 * 1536 + 1280 + kvh * 64;
  const float* src  = qkv  + sbase;
  const float* src2 = qkv2 + sbase;
  __shared__ float t[32][33];
  const int l0 = blockIdx.y * 32;
  const int d0 = blockIdx.x * 32;
  const int tx = threadIdx.x;
  const int ty = threadIdx.y;
#pragma unroll
  for (int i = 0; i < 4; ++i) {
    const size_t o = (size_t)(l0 + ty + i * 8) * 1536 + d0 + tx;
    t[ty + i * 8][tx] = src[o] + src2[o];
  }
  __syncthreads();
#pragma unroll
  for (int i = 0; i < 4; ++i) {
    float v = t[tx][ty + i * 8];
    size_t o = (size_t)bkvh * 65536 + (size_t)(d0 + ty + i * 8) * 1024 + l0 + tx;
    unsigned short h = f2bf(v);
    vt_hi[o] = h;
    vt_lo[o] = f2bf(v - bf2f(h));
  }
}

// ---------------- flash attention, split-bf16 MFMA, fp32 softmax ------------
__launch_bounds__(256, 2)
__global__ void attn_mfma(const unsigned short* __restrict__ q_hi, const unsigned short* __restrict__ q_lo,
                          const unsigned short* __restrict__ k_hi, const unsigned short* __restrict__ k_lo,
                          const unsigned short* __restrict__ vt_hi, const unsigned short* __restrict__ vt_lo,
                          unsigned short* __restrict__ ohi, unsigned short* __restrict__ olo) {
  const int blk = blockIdx.x;
  const int bh = blk & 31;               // (b,h)
  const int qt = 15 - (blk >> 5);        // long tiles dispatch first
  const int b = bh >> 4;
  const int h = bh & 15;
  const int kvbh = b * 4 + (h >> 2);
  const int q0 = qt * 64;
  const int tid = threadIdx.x;
  const int w = tid >> 6;
  const int lane = tid & 63;
  const int quad = lane >> 4;
  const int r16 = lane & 15;
  const int rl = lane >> 3;
  const int csl = lane & 7;
  const int cg = csl ^ rl;

  __shared__ unsigned short sK[2][64 * 64];
  __shared__ unsigned short sV[2][64 * 64];
  __shared__ unsigned short sP[2][64 * 64];

  short8 qfh[2], qfl[2];
  {
    const size_t qrow = ((size_t)bh * 1024 + q0 + w * 16 + r16) * 64 + quad * 8;
    qfh[0] = *(const short8*)(q_hi + qrow);
    qfh[1] = *(const short8*)(q_hi + qrow + 32);
    qfl[0] = *(const short8*)(q_lo + qrow);
    qfl[1] = *(const short8*)(q_lo + qrow + 32);
  }
  float4v O[4];
#pragma unroll
  for (int nt = 0; nt < 4; ++nt) O[nt] = float4v{0.f, 0.f, 0.f, 0.f};
  float m[4], l[4];
#pragma unroll
  for (int rg = 0; rg < 4; ++rg) { m[rg] = -__builtin_inff(); l[rg] = 0.f; }

  const unsigned short* khb = k_hi + (size_t)kvbh * 65536 + cg * 8;
  const unsigned short* klb = k_lo + (size_t)kvbh * 65536 + cg * 8;
  const unsigned short* vhb = vt_hi + (size_t)kvbh * 65536 + cg * 8;
  const unsigned short* vlb = vt_lo + (size_t)kvbh * 65536 + cg * 8;

  for (int c = 0; c <= qt; ++c) {
    __syncthreads();
#pragma unroll
    for (int j = 0; j < 2; ++j) {
      const int i = w * 2 + j;
      const int row = i * 8 + rl;
      gl_lds16(khb + (size_t)(c * 64 + row) * 64, (char*)sK[0] + i * 1024);
      gl_lds16(klb + (size_t)(c * 64 + row) * 64, (char*)sK[1] + i * 1024);
      gl_lds16(vhb + (size_t)row * 1024 + c * 64, (char*)sV[0] + i * 1024);
      gl_lds16(vlb + (size_t)row * 1024 + c * 64, (char*)sV[1] + i * 1024);
    }
    __syncthreads();

    float4v S[4];
#pragma unroll
    for (int nt = 0; nt < 4; ++nt) S[nt] = float4v{0.f, 0.f, 0.f, 0.f};
#pragma unroll
    for (int ks = 0; ks < 2; ++ks) {
#pragma unroll
      for (int nt = 0; nt < 4; ++nt) {
        const int r = nt * 16 + r16;
        const int o = (r * 8 + ((ks * 4 + quad) ^ (r & 7))) * 8;
        const short8 kh = *(const short8*)(sK[0] + o);
        const short8 kl = *(const short8*)(sK[1] + o);
        S[nt] = __builtin_amdgcn_mfma_f32_16x16x32_bf16(qfh[ks], kh, S[nt], 0, 0, 0);
        S[nt] = __builtin_amdgcn_mfma_f32_16x16x32_bf16(qfh[ks], kl, S[nt], 0, 0, 0);
        S[nt] = __builtin_amdgcn_mfma_f32_16x16x32_bf16(qfl[ks], kh, S[nt], 0, 0, 0);
      }
    }
    const float NEGINF = -__builtin_inff();
#pragma unroll
    for (int nt = 0; nt < 4; ++nt)
#pragma unroll
      for (int rg = 0; rg < 4; ++rg) S[nt][rg] *= 0.125f;
    if (c == qt) {
#pragma unroll
      for (int nt = 0; nt < 4; ++nt) {
        const int col = nt * 16 + r16;
#pragma unroll
        for (int rg = 0; rg < 4; ++rg) {
          const int row = w * 16 + quad * 4 + rg;
          if (col > row) S[nt][rg] = NEGINF;
        }
      }
    }
    float alpha[4], lsum[4];
#pragma unroll
    for (int rg = 0; rg < 4; ++rg) {
      float mx = fmaxf(fmaxf(S[0][rg], S[1][rg]), fmaxf(S[2][rg], S[3][rg]));
      mx = fmaxf(mx, __shfl_xor(mx, 1));
      mx = fmaxf(mx, __shfl_xor(mx, 2));
      mx = fmaxf(mx, __shfl_xor(mx, 4));
      mx = fmaxf(mx, __shfl_xor(mx, 8));
      const float mn = fmaxf(m[rg], mx);
      alpha[rg] = __expf(m[rg] - mn);
      m[rg] = mn;
      lsum[rg] = 0.f;
    }
#pragma unroll
    for (int nt = 0; nt < 4; ++nt)
#pragma unroll
      for (int rg = 0; rg < 4; ++rg) {
        const float e = __expf(S[nt][rg] - m[rg]);
        S[nt][rg] = e;
        lsum[rg] += e;
      }
#pragma unroll
    for (int rg = 0; rg < 4; ++rg) {
      float ls = lsum[rg];
      ls += __shfl_xor(ls, 1);
      ls += __shfl_xor(ls, 2);
      ls += __shfl_xor(ls, 4);
      ls += __shfl_xor(ls, 8);
      l[rg] = l[rg] * alpha[rg] + ls;
    }
#pragma unroll
    for (int nt = 0; nt < 4; ++nt) {
      const int key = nt * 16 + r16;
      const int chunk = key >> 3;
#pragma unroll
      for (int rg = 0; rg < 4; ++rg) {
        const int r = w * 16 + quad * 4 + rg;
        const int addr = r * 64 + ((chunk ^ (r & 7)) * 8) + (key & 7);
        const float e = S[nt][rg];
        const unsigned short hv = f2bf(e);
        sP[0][addr] = hv;
        sP[1][addr] = f2bf(e - bf2f(hv));
      }
    }
#pragma unroll
    for (int nt = 0; nt < 4; ++nt)
#pragma unroll
      for (int rg = 0; rg < 4; ++rg) O[nt][rg] *= alpha[rg];
#pragma unroll
    for (int ks = 0; ks < 2; ++ks) {
      const int rA = w * 16 + r16;
      const int oA = (rA * 8 + ((ks * 4 + quad) ^ (rA & 7))) * 8;
      const short8 ph = *(const short8*)(sP[0] + oA);
      const short8 pl = *(const short8*)(sP[1] + oA);
#pragma unroll
      for (int nt = 0; nt < 4; ++nt) {
        const int rv = nt * 16 + r16;
        const int ov = (rv * 8 + ((ks * 4 + quad) ^ (rv & 7))) * 8;
        const short8 vh = *(const short8*)(sV[0] + ov);
        const short8 vl = *(const short8*)(sV[1] + ov);
        O[nt] = __builtin_amdgcn_mfma_f32_16x16x32_bf16(ph, vh, O[nt], 0, 0, 0);
        O[nt] = __builtin_amdgcn_mfma_f32_16x16x32_bf16(ph, vl, O[nt], 0, 0, 0);
        O[nt] = __builtin_amdgcn_mfma_f32_16x16x32_bf16(pl, vh, O[nt], 0, 0, 0);
      }
    }
  }
#pragma unroll
  for (int nt = 0; nt < 4; ++nt) {
    const int col = h * 64 + nt * 16 + r16;
#pragma unroll
    for (int rg = 0; rg < 4; ++rg) {
      const int row = q0 + w * 16 + quad * 4 + rg;
      const float ovv = O[nt][rg] / l[rg];
      const size_t idx = ((size_t)b * 1024 + row) * DMODEL + col;
      const unsigned short hv = f2bf(ovv);
      ohi[idx] = hv;
      olo[idx] = f2bf(ovv - bf2f(hv));
    }
  }
}

// ----- x1 = x + sum of 4 wo-GEMM split-K partial slabs ----------------------
__global__ void merge_x1(const float* __restrict__ x, const float* __restrict__ parts,
                         float* __restrict__ x1) {
  const size_t i = ((size_t)blockIdx.x * 256 + threadIdx.x) * 4;
  float4 r = *(const float4*)(x + i);
#pragma unroll
  for (int z = 0; z < 4; ++z) {
    const float4 p = *(const float4*)(parts + (size_t)z * NTOK * DMODEL + i);
    r.x += p.x; r.y += p.y; r.z += p.z; r.w += p.w;
  }
  *(float4*)(x1 + i) = r;
}

// ---------------- router: fp32 logits, top-2, gates, counts -----------------
#define RED6SUM(X) { X += __shfl_xor(X,32); X += __shfl_xor(X,16); X += __shfl_xor(X,8); X += __shfl_xor(X,4); X += __shfl_xor(X,2); X += __shfl_xor(X,1); }

__global__ void router_kernel(const float* __restrict__ h2f, const float* __restrict__ wg,
                              int* __restrict__ tok_e, float* __restrict__ tok_g,
                              int* __restrict__ counts) {
  const int t = blockIdx.x;
  const int lane = threadIdx.x;
  float acc[8] = {0,0,0,0,0,0,0,0};
  const float* hr = h2f + (size_t)t * DMODEL;
  for (int d = lane; d < DMODEL; d += 64) {
    const float hv = hr[d];
    const float4 w0 = *(const float4*)(wg + d * 8);
    const float4 w1_ = *(const float4*)(wg + d * 8 + 4);
    acc[0] += hv * w0.x; acc[1] += hv * w0.y; acc[2] += hv * w0.z; acc[3] += hv * w0.w;
    acc[4] += hv * w1_.x; acc[5] += hv * w1_.y; acc[6] += hv * w1_.z; acc[7] += hv * w1_.w;
  }
#pragma unroll
  for (int e = 0; e < 8; ++e) { RED6SUM(acc[e]); }
  if (lane == 0) {
    int i0 = 0; float v0 = acc[0];
#pragma unroll
    for (int e = 1; e < 8; ++e) if (acc[e] > v0) { v0 = acc[e]; i0 = e; }
    int i1 = -1; float v1 = -__builtin_inff();
#pragma unroll
    for (int e = 0; e < 8; ++e) if (e != i0 && acc[e] > v1) { v1 = acc[e]; i1 = e; }
    const float ex = __expf(v1 - v0);
    const float den = 1.0f + ex;
    tok_e[t * 2] = i0; tok_e[t * 2 + 1] = i1;
    tok_g[t * 2] = 1.0f / den; tok_g[t * 2 + 1] = ex / den;
    atomicAdd(counts + i0, 1);
    atomicAdd(counts + i1, 1);
  }
}

__global__ void finalize_kernel(const int* __restrict__ counts, int* __restrict__ off_pad,
                                int* __restrict__ tile_map, float* __restrict__ lb_out) {
  if (threadIdx.x == 0 && blockIdx.x == 0) {
    int tile = 0, rowoff = 0;
    for (int e = 0; e < NEXP; ++e) {
      off_pad[e] = rowoff;
      const int c = counts[e];
      const int nt = (c + 127) >> 7;
      for (int i = 0; i < nt; ++i) tile_map[tile++] = e;
      rowoff += nt * 128;
    }
    for (; tile < MAXTILES; ++tile) tile_map[tile] = -1;
    float sacc = 0.f;
    for (int e = 0; e < NEXP; ++e) {
      const float cn = (float)counts[e] * (1.0f / 4096.0f);
      const float d = cn - 0.125f;
      sacc += d * d;
    }
    lb_out[0] = sacc * (1.0f / 8.0f);
  }
}

__global__ void scatter_kernel(const int* __restrict__ tok_e, const int* __restrict__ off_pad,
                               int* __restrict__ fill, int* __restrict__ tok_pos,
                               const unsigned short* __restrict__ h2bf, unsigned short* __restrict__ Xg) {
  const int slot = blockIdx.x;
  const int t = slot >> 1;
  __shared__ int sp;
  if (threadIdx.x == 0) {
    const int e = tok_e[slot];
    const int r = atomicAdd(fill + e, 1);
    const int ppos = off_pad[e] + r;
    tok_pos[slot] = ppos;
    sp = ppos;
  }
  __syncthreads();
  const int pos = sp;
  *(uint2*)(Xg + (size_t)pos * DMODEL + threadIdx.x * 4) =
      *(const uint2*)(h2bf + (size_t)t * DMODEL + threadIdx.x * 4);
}

// ----- combine: out = x1 + g0*sum_z eout_z[p0] + g1*sum_z eout_z[p1] --------
__global__ void combine_kernel(const float* __restrict__ x1, const float* __restrict__ eout,
                               const int* __restrict__ tok_pos, const float* __restrict__ tok_g,
                               float* __restrict__ out) {
  const int t = blockIdx.x;
  const int tid = threadIdx.x;
  const int p0 = tok_pos[t * 2], p1 = tok_pos[t * 2 + 1];
  const float g0 = tok_g[t * 2], g1 = tok_g[t * 2 + 1];
  const size_t o = (size_t)t * DMODEL + tid * 4;
  const float4 a = *(const float4*)(x1 + o);
  float s0x = 0.f, s0y = 0.f, s0z = 0.f, s0w = 0.f;
  float s1x = 0.f, s1y = 0.f, s1z = 0.f, s1w = 0.f;
#pragma unroll
  for (int z = 0; z < 4; ++z) {
    const size_t zb = (size_t)z * MAXROWS * DMODEL;
    const float4 e0 = *(const float4*)(eout + zb + (size_t)p0 * DMODEL + tid * 4);
    const float4 e1 = *(const float4*)(eout + zb + (size_t)p1 * DMODEL + tid * 4);
    s0x += e0.x; s0y += e0.y; s0z += e0.z; s0w += e0.w;
    s1x += e1.x; s1y += e1.y; s1z += e1.z; s1w += e1.w;
  }
  float4 r;
  r.x = a.x + g0 * s0x + g1 * s1x;
  r.y = a.y + g0 * s0y + g1 * s1y;
  r.z = a.z + g0 * s0z + g1 * s1z;
  r.w = a.w + g0 * s0w + g1 * s1w;
  *(float4*)(out + o) = r;
}

__global__ void init_kernel(int* counts, int* fill) {
  const int t = threadIdx.x;
  if (t < 8) { counts[t] = 0; fill[t] = 0; }
}

extern "C" void kernel_launch(void* const* d_in, const int* in_sizes, int n_in,
                              void* d_out, int out_size, void* d_ws, size_t ws_size,
                              hipStream_t stream) {
  (void)in_sizes; (void)n_in; (void)out_size; (void)ws_size;
  const float* x    = (const float*)d_in[0];
  const float* wq   = (const float*)d_in[1];
  const float* wk   = (const float*)d_in[2];
  const float* wv   = (const float*)d_in[3];
  const float* wo   = (const float*)d_in[4];
  const float* wg   = (const float*)d_in[5];
  const float* w1   = (const float*)d_in[6];
  const float* w2   = (const float*)d_in[7];
  const float* ln1g = (const float*)d_in[8];
  const float* ln1b = (const float*)d_in[9];
  const float* ln2g = (const float*)d_in[10];
  const float* ln2b = (const float*)d_in[11];
  float* out = (float*)d_out;

  char* p = (char*)d_ws;
  auto take = [&](size_t n) { void* r = (void*)p; p += (n + 255) & ~(size_t)255; return r; };
  unsigned short* h1_hi   = (unsigned short*)take((size_t)NTOK * DMODEL * 2);
  unsigned short* h1_lo   = (unsigned short*)take((size_t)NTOK * DMODEL * 2);
  unsigned short* wqkv_hi = (unsigned short*)take((size_t)1536 * 1024 * 2);
  unsigned short* wqkv_lo = (unsigned short*)take((size_t)1536 * 1024 * 2);
  unsigned short* woT_hi  = (unsigned short*)take((size_t)1024 * 1024 * 2);
  unsigned short* woT_lo  = (unsigned short*)take((size_t)1024 * 1024 * 2);
  unsigned short* w1t     = (unsigned short*)take((size_t)NEXP * DFF * DMODEL * 2);
  unsigned short* w2t     = (unsigned short*)take((size_t)NEXP * DMODEL * DFF * 2);
  float* qkv   = (float*)take((size_t)2 * NTOK * 1536 * 4);          // 2 split-K slabs
  unsigned short* q_hi  = (unsigned short*)take((size_t)2 * 16 * 1024 * 64 * 2);
  unsigned short* q_lo  = (unsigned short*)take((size_t)2 * 16 * 1024 * 64 * 2);
  unsigned short* k_hi  = (unsigned short*)take((size_t)2 * 4 * 1024 * 64 * 2);
  unsigned short* k_lo  = (unsigned short*)take((size_t)2 * 4 * 1024 * 64 * 2);
  unsigned short* vt_hi = (unsigned short*)take((size_t)2 * 4 * 1024 * 64 * 2);
  unsigned short* vt_lo = (unsigned short*)take((size_t)2 * 4 * 1024 * 64 * 2);
  unsigned short* attn_hi = (unsigned short*)take((size_t)NTOK * DMODEL * 2);
  unsigned short* attn_lo = (unsigned short*)take((size_t)NTOK * DMODEL * 2);
  float* x1p   = (float*)take((size_t)4 * NTOK * DMODEL * 4);        // 4 split-K slabs
  float* x1    = (float*)take((size_t)NTOK * DMODEL * 4);
  float* h2f   = (float*)take((size_t)NTOK * DMODEL * 4);
  unsigned short* h2bf = (unsigned short*)take((size_t)NTOK * DMODEL * 2);
  unsigned short* Xg   = (unsigned short*)take((size_t)MAXROWS * DMODEL * 2);
  unsigned short* hid  = (unsigned short*)take((size_t)MAXROWS * DFF * 2);
  float* eout  = (float*)take((size_t)4 * MAXROWS * DMODEL * 4);     // 4 split-K slabs
  int*   tok_e   = (int*)take(4096 * 4);
  float* tok_g   = (float*)take(4096 * 4);
  int*   tok_pos = (int*)take(4096 * 4);
  int*   counts  = (int*)take(64);
  int*   fill    = (int*)take(64);
  int*   off_pad = (int*)take(64);
  int*   tile_map = (int*)take(256);

  init_kernel<<<1, 64, 0, stream>>>(counts, fill);
  ln_kernel<<<NTOK, 256, 0, stream>>>(x, ln1g, ln1b, h1_hi, h1_lo, nullptr);
  transpose_w<1><<<dim3(16, 16, 1), 256, 0, stream>>>(wq, wqkv_hi, wqkv_lo, 1024, 1024, 0, 0);
  transpose_w<1><<<dim3(4, 16, 1), 256, 0, stream>>>(wk, wqkv_hi + (size_t)1024 * 1024, wqkv_lo + (size_t)1024 * 1024, 1024, 256, 0, 0);
  transpose_w<1><<<dim3(4, 16, 1), 256, 0, stream>>>(wv, wqkv_hi + (size_t)1280 * 1024, wqkv_lo + (size_t)1280 * 1024, 1024, 256, 0, 0);
  transpose_w<1><<<dim3(16, 16, 1), 256, 0, stream>>>(wo, woT_hi, woT_lo, 1024, 1024, 0, 0);
  transpose_w<0><<<dim3(64, 16, 8), 256, 0, stream>>>(w1, w1t, nullptr, 1024, 4096, (long)1024 * 4096, (long)4096 * 1024);
  transpose_w<0><<<dim3(16, 64, 8), 256, 0, stream>>>(w2, w2t, nullptr, 4096, 1024, (long)4096 * 1024, (long)1024 * 4096);
  // qkv = h1 @ [wq|wk|wv], split-K x2 (384 blocks), XCD-swizzled
  gemm_split<<<dim3(12, 16, 2), 256, 0, stream>>>(h1_hi, h1_lo, wqkv_hi, wqkv_lo, qkv, 1536, 1024, 512, (long)NTOK * 1536);
  rope_split<<<NTOK, 256, 0, stream>>>(qkv, qkv + (size_t)NTOK * 1536, q_hi, q_lo, k_hi, k_lo);
  vt_split<<<dim3(2, 32, 8), dim3(32, 8), 0, stream>>>(qkv, qkv + (size_t)NTOK * 1536, vt_hi, vt_lo);
  attn_mfma<<<512, 256, 0, stream>>>(q_hi, q_lo, k_hi, k_lo, vt_hi, vt_lo, attn_hi, attn_lo);
  // wo projection: split-K x4 (512 blocks); residual folded in merge_x1
  gemm_split<<<dim3(8, 16, 4), 256, 0, stream>>>(attn_hi, attn_lo, woT_hi, woT_lo, x1p, 1024, 1024, 256, (long)NTOK * DMODEL);
  merge_x1<<<2048, 256, 0, stream>>>(x, x1p, x1);
  ln_kernel<<<NTOK, 256, 0, stream>>>(x1, ln2g, ln2b, h2bf, nullptr, h2f);
  router_kernel<<<NTOK, 64, 0, stream>>>(h2f, wg, tok_e, tok_g, counts);
  finalize_kernel<<<1, 64, 0, stream>>>(counts, off_pad, tile_map, out + (size_t)NTOK * DMODEL);
  scatter_kernel<<<4096, 256, 0, stream>>>(tok_e, off_pad, fill, tok_pos, h2bf, Xg);
  // w1 GEMM: gelu epilogue tanh-form (cheap), XCD-swizzled
  gemm_bt<3,1><<<dim3(32, MAXTILES), 256, 0, stream>>>(Xg, w1t, nullptr, hid, DFF, DMODEL, DMODEL, 0, tile_map, (long)DFF * DMODEL);
  // expert down-proj: split-K x4 (1280 blocks), XCD-swizzled
  gemm_bt<0,1><<<dim3(8, MAXTILES, 4), 256, 0, stream>>>(hid, w2t, eout, nullptr, DMODEL, DFF, 1024, (long)MAXROWS * DMODEL, tile_map, (long)DMODEL * DFF);
  combine_kernel<<<NTOK, 256, 0, stream>>>(x1, eout, tok_pos, tok_g, out);
}

// Round 6
// 674.628 us; speedup vs baseline: 1.5262x; 1.0471x over previous
//
#include <hip/hip_runtime.h>
#include <hip/hip_bf16.h>

#define NTOK   2048      // B*L
#define DMODEL 1024
#define NEXP   8
#define DFF    4096
#define MAXROWS 5120
#define MAXTILES 40

typedef __attribute__((ext_vector_type(8))) short short8;
typedef __attribute__((ext_vector_type(4))) float float4v;

__device__ __forceinline__ unsigned short f2bf(float f) {
  union { float f; unsigned u; } v; v.f = f;
  unsigned r = v.u + 0x7fffu + ((v.u >> 16) & 1u);
  return (unsigned short)(r >> 16);
}
__device__ __forceinline__ float bf2f(unsigned short h) {
  union { unsigned u; float f; } v; v.u = ((unsigned)h) << 16; return v.f;
}
__device__ __forceinline__ void gl_lds16(const void* g, void* l) {
  __builtin_amdgcn_global_load_lds((const __attribute__((address_space(1))) void*)g,
                                   (__attribute__((address_space(3))) void*)l, 16, 0, 0);
}

// bijective XCD swizzle: consecutive HW bids round-robin over 8 XCDs; give each
// XCD a contiguous chunk of logical tile space (requires nwg % 8 == 0).
__device__ __forceinline__ int xcd_swz(int bid, int nwg) {
  if (nwg & 7) return bid;
  const int chunk = nwg >> 3;
  return (bid & 7) * chunk + (bid >> 3);
}

// ---------------- GEMM: C[M,N] = A[M,K](bf16) x B[N,K]^T(bf16), fp32 acc ---
// EPI: 0 C=acc ; 3 Cbf=bf16(gelu(acc))
// split-K: z covers k in [z*kslice, (z+1)*kslice), partial C slab at z*zstride
// launch_bounds(256,4): 4 waves/EU -> 128-reg budget; kernel needs ~60 VGPR +
// 64 AGPR acc. (256,5) caps at ~102 regs and SPILLS the accumulator to
// scratch: R3 measured WRITE_SIZE 38->303 MB, 78->253us. Do not raise.
template<int EPI, int EMAP>
__launch_bounds__(256, 4)
__global__ void gemm_bt(const unsigned short* __restrict__ A,
                        const unsigned short* __restrict__ B0,
                        float* __restrict__ C,
                        unsigned short* __restrict__ Cbf,
                        const int N, const int K,
                        const int kslice, const long zstride,
                        const int* __restrict__ tmap, const long estride) {
  // ---- XCD-swizzled logical tile id ----
  const int gx = gridDim.x, gy = gridDim.y;
  const int nwg = gx * gy * gridDim.z;
  const int lid = xcd_swz(blockIdx.x + gx * (blockIdx.y + gy * blockIdx.z), nwg);
  const int bx = lid % gx;
  const int t1 = lid / gx;
  const int mtile = t1 % gy;
  const int bz = t1 / gy;

  const unsigned short* B = B0;
  if (EMAP) {
    int e = tmap[mtile];
    if (e < 0) return;
    B += (size_t)e * (size_t)estride;
  }
  const int n0 = bx * 128;
  const int m0 = mtile * 128;
  if (EPI == 0) C += (size_t)bz * (size_t)zstride;
  __shared__ unsigned short sA[128 * 64];
  __shared__ unsigned short sB[128 * 64];
  const int tid  = threadIdx.x;
  const int w    = tid >> 6;
  const int lane = tid & 63;
  const int quad = lane >> 4;
  const int r16  = lane & 15;
  const int wr   = w >> 1;
  const int wc   = w & 1;
  const int rl   = lane >> 3;
  const int csl  = lane & 7;
  const int cg   = csl ^ rl;
  float4v acc[4][4];
#pragma unroll
  for (int i = 0; i < 4; ++i)
#pragma unroll
    for (int j = 0; j < 4; ++j) acc[i][j] = float4v{0.f, 0.f, 0.f, 0.f};

  const unsigned short* Ab = A + (size_t)m0 * K + cg * 8;
  const unsigned short* Bb = B + (size_t)n0 * K + cg * 8;

  const int kbeg = bz * kslice;
  const int kend = kbeg + kslice;
  for (int k0 = kbeg; k0 < kend; k0 += 64) {
    __syncthreads();
#pragma unroll
    for (int i = 0; i < 4; ++i) {
      const int j = w * 4 + i;
      gl_lds16(Ab + (size_t)(j * 8 + rl) * K + k0, (char*)sA + j * 1024);
      gl_lds16(Bb + (size_t)(j * 8 + rl) * K + k0, (char*)sB + j * 1024);
    }
    __syncthreads();
#pragma unroll
    for (int kc = 0; kc < 8; kc += 4) {
      short8 af[4], bq[4];
#pragma unroll
      for (int mt = 0; mt < 4; ++mt) {
        int r = wr * 64 + mt * 16 + r16;
        af[mt] = *(const short8*)(sA + ((r * 8 + ((kc + quad) ^ (r & 7))) * 8));
      }
#pragma unroll
      for (int nt = 0; nt < 4; ++nt) {
        int r = wc * 64 + nt * 16 + r16;
        bq[nt] = *(const short8*)(sB + ((r * 8 + ((kc + quad) ^ (r & 7))) * 8));
      }
#pragma unroll
      for (int mt = 0; mt < 4; ++mt)
#pragma unroll
        for (int nt = 0; nt < 4; ++nt)
          acc[mt][nt] = __builtin_amdgcn_mfma_f32_16x16x32_bf16(af[mt], bq[nt], acc[mt][nt], 0, 0, 0);
    }
  }
#pragma unroll
  for (int mt = 0; mt < 4; ++mt) {
#pragma unroll
    for (int nt = 0; nt < 4; ++nt) {
#pragma unroll
      for (int rg = 0; rg < 4; ++rg) {
        const int m = m0 + wr * 64 + mt * 16 + quad * 4 + rg;
        const int n = n0 + wc * 64 + nt * 16 + r16;
        const size_t idx = (size_t)m * N + n;
        const float v = acc[mt][nt][rg];
        if (EPI == 0) C[idx] = v;
        else {
          // tanh-form gelu: x*sigmoid(1.5958(x+0.044715x^3)); |err| ~1e-4,
          // far below hid's bf16 quantization. Replaces ~25-op erff.
          const float u = v + 0.044715f * v * v * v;
          const float ge = v / (1.0f + __expf(-1.5957691216f * u));
          Cbf[idx] = f2bf(ge);
        }
      }
    }
  }
}

// ------- split-bf16 GEMM: C = (Ah+Al)x(Bh+Bl)^T, 3 terms, split-K slabs -----
__launch_bounds__(256, 2)
__global__ void gemm_split(const unsigned short* __restrict__ Ah,
                           const unsigned short* __restrict__ Al,
                           const unsigned short* __restrict__ Bh,
                           const unsigned short* __restrict__ Bl,
                           float* __restrict__ C,
                           const int N, const int K,
                           const int kslice, const long zstride) {
  const int gx = gridDim.x, gy = gridDim.y;
  const int nwg = gx * gy * gridDim.z;
  const int lid = xcd_swz(blockIdx.x + gx * (blockIdx.y + gy * blockIdx.z), nwg);
  const int bx = lid % gx;
  const int t1 = lid / gx;
  const int by = t1 % gy;
  const int bz = t1 / gy;

  const int n0 = bx * 128;
  const int m0 = by * 128;
  C += (size_t)bz * (size_t)zstride;
  __shared__ unsigned short sAh[128 * 64];
  __shared__ unsigned short sAl[128 * 64];
  __shared__ unsigned short sBh[128 * 64];
  __shared__ unsigned short sBl[128 * 64];
  const int tid  = threadIdx.x;
  const int w    = tid >> 6;
  const int lane = tid & 63;
  const int quad = lane >> 4;
  const int r16  = lane & 15;
  const int wr   = w >> 1;
  const int wc   = w & 1;
  const int rl   = lane >> 3;
  const int csl  = lane & 7;
  const int cg   = csl ^ rl;
  float4v acc[4][4];
#pragma unroll
  for (int i = 0; i < 4; ++i)
#pragma unroll
    for (int j = 0; j < 4; ++j) acc[i][j] = float4v{0.f, 0.f, 0.f, 0.f};

  const size_t aoff = (size_t)m0 * K + cg * 8;
  const size_t boff = (size_t)n0 * K + cg * 8;

  const int kbeg = bz * kslice;
  const int kend = kbeg + kslice;
  for (int k0 = kbeg; k0 < kend; k0 += 64) {
    __syncthreads();
#pragma unroll
    for (int i = 0; i < 4; ++i) {
      const int j = w * 4 + i;
      const size_t ro = (size_t)(j * 8 + rl) * K + k0;
      gl_lds16(Ah + aoff + ro, (char*)sAh + j * 1024);
      gl_lds16(Al + aoff + ro, (char*)sAl + j * 1024);
      gl_lds16(Bh + boff + ro, (char*)sBh + j * 1024);
      gl_lds16(Bl + boff + ro, (char*)sBl + j * 1024);
    }
    __syncthreads();
#pragma unroll
    for (int kc = 0; kc < 8; kc += 4) {
      short8 afh[4], afl[4], bqh[4], bql[4];
#pragma unroll
      for (int mt = 0; mt < 4; ++mt) {
        int r = wr * 64 + mt * 16 + r16;
        int o = (r * 8 + ((kc + quad) ^ (r & 7))) * 8;
        afh[mt] = *(const short8*)(sAh + o);
        afl[mt] = *(const short8*)(sAl + o);
      }
#pragma unroll
      for (int nt = 0; nt < 4; ++nt) {
        int r = wc * 64 + nt * 16 + r16;
        int o = (r * 8 + ((kc + quad) ^ (r & 7))) * 8;
        bqh[nt] = *(const short8*)(sBh + o);
        bql[nt] = *(const short8*)(sBl + o);
      }
#pragma unroll
      for (int mt = 0; mt < 4; ++mt)
#pragma unroll
        for (int nt = 0; nt < 4; ++nt) {
          acc[mt][nt] = __builtin_amdgcn_mfma_f32_16x16x32_bf16(afh[mt], bqh[nt], acc[mt][nt], 0, 0, 0);
          acc[mt][nt] = __builtin_amdgcn_mfma_f32_16x16x32_bf16(afh[mt], bql[nt], acc[mt][nt], 0, 0, 0);
          acc[mt][nt] = __builtin_amdgcn_mfma_f32_16x16x32_bf16(afl[mt], bqh[nt], acc[mt][nt], 0, 0, 0);
        }
    }
  }
#pragma unroll
  for (int mt = 0; mt < 4; ++mt) {
#pragma unroll
    for (int nt = 0; nt < 4; ++nt) {
#pragma unroll
      for (int rg = 0; rg < 4; ++rg) {
        const int m = m0 + wr * 64 + mt * 16 + quad * 4 + rg;
        const int n = n0 + wc * 64 + nt * 16 + r16;
        C[(size_t)m * N + n] = acc[mt][nt][rg];
      }
    }
  }
}

// ------ fp32 [K,N] -> bf16 [N,K] (hi, optional lo), 64x64, vectorized -------
template<int WLO>
__global__ void transpose_w(const float* __restrict__ in, unsigned short* __restrict__ oh,
                            unsigned short* __restrict__ ol, const int K, const int N,
                            const long istride, const long ostride) {
  const int bz = blockIdx.z;
  in += (size_t)bz * istride;
  oh += (size_t)bz * ostride;
  if (WLO) ol += (size_t)bz * ostride;
  __shared__ float t[64][65];
  const int n0 = blockIdx.x * 64;
  const int k0 = blockIdx.y * 64;
  const int tid = threadIdx.x;
  const int rr = tid >> 4;        // 0..15
  const int c4 = (tid & 15) * 4;  // 0..60
#pragma unroll
  for (int p = 0; p < 4; ++p) {
    const int row = p * 16 + rr;
    const float4 v = *(const float4*)(in + (size_t)(k0 + row) * N + n0 + c4);
    t[row][c4] = v.x; t[row][c4 + 1] = v.y; t[row][c4 + 2] = v.z; t[row][c4 + 3] = v.w;
  }
  __syncthreads();
#pragma unroll
  for (int p = 0; p < 4; ++p) {
    const int n = p * 16 + rr;
    float vs[4];
#pragma unroll
    for (int i = 0; i < 4; ++i) vs[i] = t[c4 + i][n];
    ushort4 h;
    h.x = f2bf(vs[0]); h.y = f2bf(vs[1]); h.z = f2bf(vs[2]); h.w = f2bf(vs[3]);
    const size_t o = (size_t)(n0 + n) * K + k0 + c4;
    *(ushort4*)(oh + o) = h;
    if (WLO) {
      ushort4 lo4;
      lo4.x = f2bf(vs[0] - bf2f(h.x));
      lo4.y = f2bf(vs[1] - bf2f(h.y));
      lo4.z = f2bf(vs[2] - bf2f(h.z));
      lo4.w = f2bf(vs[3] - bf2f(h.w));
      *(ushort4*)(ol + o) = lo4;
    }
  }
}

// --- fused wq/wk/wv/wo transpose (hi+lo) + counts/fill init, one launch -----
// z=0: wq -> wqkv[0:1024); z=1: wk -> wqkv[1024:1280); z=2: wv -> [1280:1536);
// z=3: wo -> woT. All K=1024. Saves 3 launches + init launch vs separate calls.
__global__ void transpose_qkvo(const float* __restrict__ wq, const float* __restrict__ wk,
                               const float* __restrict__ wv, const float* __restrict__ wo,
                               unsigned short* __restrict__ wqkv_hi, unsigned short* __restrict__ wqkv_lo,
                               unsigned short* __restrict__ woT_hi, unsigned short* __restrict__ woT_lo,
                               int* __restrict__ counts, int* __restrict__ fill) {
  if (blockIdx.x == 0 && blockIdx.y == 0 && blockIdx.z == 0 && threadIdx.x < 16) {
    if (threadIdx.x < 8) counts[threadIdx.x] = 0;
    else fill[threadIdx.x - 8] = 0;
  }
  const int z = blockIdx.z;
  const float* in;
  unsigned short *oh, *ol;
  int N, xmax;
  if (z == 0)      { in = wq; oh = wqkv_hi;                         ol = wqkv_lo;                         N = 1024; xmax = 16; }
  else if (z == 1) { in = wk; oh = wqkv_hi + (size_t)1024 * 1024;   ol = wqkv_lo + (size_t)1024 * 1024;   N = 256;  xmax = 4; }
  else if (z == 2) { in = wv; oh = wqkv_hi + (size_t)1280 * 1024;   ol = wqkv_lo + (size_t)1280 * 1024;   N = 256;  xmax = 4; }
  else             { in = wo; oh = woT_hi;                          ol = woT_lo;                          N = 1024; xmax = 16; }
  if (blockIdx.x >= xmax) return;
  const int K = 1024;
  __shared__ float t[64][65];
  const int n0 = blockIdx.x * 64;
  const int k0 = blockIdx.y * 64;
  const int tid = threadIdx.x;
  const int rr = tid >> 4;
  const int c4 = (tid & 15) * 4;
#pragma unroll
  for (int p = 0; p < 4; ++p) {
    const int row = p * 16 + rr;
    const float4 v = *(const float4*)(in + (size_t)(k0 + row) * N + n0 + c4);
    t[row][c4] = v.x; t[row][c4 + 1] = v.y; t[row][c4 + 2] = v.z; t[row][c4 + 3] = v.w;
  }
  __syncthreads();
#pragma unroll
  for (int p = 0; p < 4; ++p) {
    const int n = p * 16 + rr;
    float vs[4];
#pragma unroll
    for (int i = 0; i < 4; ++i) vs[i] = t[c4 + i][n];
    ushort4 h;
    h.x = f2bf(vs[0]); h.y = f2bf(vs[1]); h.z = f2bf(vs[2]); h.w = f2bf(vs[3]);
    const size_t o = (size_t)(n0 + n) * K + k0 + c4;
    *(ushort4*)(oh + o) = h;
    ushort4 lo4;
    lo4.x = f2bf(vs[0] - bf2f(h.x));
    lo4.y = f2bf(vs[1] - bf2f(h.y));
    lo4.z = f2bf(vs[2] - bf2f(h.z));
    lo4.w = f2bf(vs[3] - bf2f(h.w));
    *(ushort4*)(ol + o) = lo4;
  }
}

// ---------------- LayerNorm over D=1024 (ln1: hi+lo) ------------------------
__global__ void ln_kernel(const float* __restrict__ x, const float* __restrict__ g,
                          const float* __restrict__ b, unsigned short* __restrict__ hi,
                          unsigned short* __restrict__ lo) {
  const int row = blockIdx.x;
  const int tid = threadIdx.x;
  const int w = tid >> 6, lane = tid & 63;
  const float4 v = *(const float4*)(x + (size_t)row * DMODEL + tid * 4);
  float s = v.x + v.y + v.z + v.w;
  float q = v.x * v.x + v.y * v.y + v.z * v.z + v.w * v.w;
#pragma unroll
  for (int o = 32; o; o >>= 1) { s += __shfl_xor(s, o); q += __shfl_xor(q, o); }
  __shared__ float red[8];
  if (lane == 0) { red[w] = s; red[4 + w] = q; }
  __syncthreads();
  s = red[0] + red[1] + red[2] + red[3];
  q = red[4] + red[5] + red[6] + red[7];
  const float mean = s * (1.0f / DMODEL);
  const float var = q * (1.0f / DMODEL) - mean * mean;
  const float rs = rsqrtf(var + 1e-5f);
  const float4 gg = *(const float4*)(g + tid * 4);
  const float4 bb = *(const float4*)(b + tid * 4);
  float y[4];
  y[0] = (v.x - mean) * rs * gg.x + bb.x;
  y[1] = (v.y - mean) * rs * gg.y + bb.y;
  y[2] = (v.z - mean) * rs * gg.z + bb.z;
  y[3] = (v.w - mean) * rs * gg.w + bb.w;
  const size_t base = (size_t)row * DMODEL + tid * 4;
  ushort4 h4, l4;
  h4.x = f2bf(y[0]); h4.y = f2bf(y[1]); h4.z = f2bf(y[2]); h4.w = f2bf(y[3]);
  l4.x = f2bf(y[0] - bf2f(h4.x));
  l4.y = f2bf(y[1] - bf2f(h4.y));
  l4.z = f2bf(y[2] - bf2f(h4.z));
  l4.w = f2bf(y[3] - bf2f(h4.w));
  *(ushort4*)(hi + base) = h4;
  *(ushort4*)(lo + base) = l4;
}

#define RED6SUM(X) { X += __shfl_xor(X,32); X += __shfl_xor(X,16); X += __shfl_xor(X,8); X += __shfl_xor(X,4); X += __shfl_xor(X,2); X += __shfl_xor(X,1); }

// --- fused: x1 = x + sum(4 wo slabs); ln2; h2bf; router top-2 + counts ------
// Replaces merge_x1 + ln_kernel(ln2) + router_kernel: saves 2 launches and the
// x1-reread + h2f write/read (~24 MB round trips).
__global__ void fused_ln2_router(const float* __restrict__ x, const float* __restrict__ x1p,
                                 const float* __restrict__ g, const float* __restrict__ b,
                                 float* __restrict__ x1, unsigned short* __restrict__ h2bf,
                                 const float* __restrict__ wg,
                                 int* __restrict__ tok_e, float* __restrict__ tok_g,
                                 int* __restrict__ counts) {
  const int row = blockIdx.x;
  const int tid = threadIdx.x;
  const int w = tid >> 6, lane = tid & 63;
  const size_t base = (size_t)row * DMODEL + tid * 4;
  float4 v = *(const float4*)(x + base);
#pragma unroll
  for (int z = 0; z < 4; ++z) {
    const float4 p = *(const float4*)(x1p + (size_t)z * NTOK * DMODEL + base);
    v.x += p.x; v.y += p.y; v.z += p.z; v.w += p.w;
  }
  *(float4*)(x1 + base) = v;
  float s = v.x + v.y + v.z + v.w;
  float q = v.x * v.x + v.y * v.y + v.z * v.z + v.w * v.w;
#pragma unroll
  for (int o = 32; o; o >>= 1) { s += __shfl_xor(s, o); q += __shfl_xor(q, o); }
  __shared__ float red[8];
  if (lane == 0) { red[w] = s; red[4 + w] = q; }
  __syncthreads();
  s = red[0] + red[1] + red[2] + red[3];
  q = red[4] + red[5] + red[6] + red[7];
  const float mean = s * (1.0f / DMODEL);
  const float var = q * (1.0f / DMODEL) - mean * mean;
  const float rs = rsqrtf(var + 1e-5f);
  const float4 gg = *(const float4*)(g + tid * 4);
  const float4 bb = *(const float4*)(b + tid * 4);
  float y[4];
  y[0] = (v.x - mean) * rs * gg.x + bb.x;
  y[1] = (v.y - mean) * rs * gg.y + bb.y;
  y[2] = (v.z - mean) * rs * gg.z + bb.z;
  y[3] = (v.w - mean) * rs * gg.w + bb.w;
  ushort4 h4;
  h4.x = f2bf(y[0]); h4.y = f2bf(y[1]); h4.z = f2bf(y[2]); h4.w = f2bf(y[3]);
  *(ushort4*)(h2bf + base) = h4;
  // router partials: y (fp32, exact LN output) dot wg[D][8]
  float acc[8] = {0, 0, 0, 0, 0, 0, 0, 0};
#pragma unroll
  for (int i = 0; i < 4; ++i) {
    const int d = tid * 4 + i;
    const float4 w0 = *(const float4*)(wg + d * 8);
    const float4 w1v = *(const float4*)(wg + d * 8 + 4);
    acc[0] += y[i] * w0.x;  acc[1] += y[i] * w0.y;  acc[2] += y[i] * w0.z;  acc[3] += y[i] * w0.w;
    acc[4] += y[i] * w1v.x; acc[5] += y[i] * w1v.y; acc[6] += y[i] * w1v.z; acc[7] += y[i] * w1v.w;
  }
#pragma unroll
  for (int e = 0; e < 8; ++e) { RED6SUM(acc[e]); }
  __shared__ float racc[4][8];
  if (lane == 0) {
#pragma unroll
    for (int e = 0; e < 8; ++e) racc[w][e] = acc[e];
  }
  __syncthreads();
  if (tid == 0) {
    float tot[8];
#pragma unroll
    for (int e = 0; e < 8; ++e) tot[e] = racc[0][e] + racc[1][e] + racc[2][e] + racc[3][e];
    int i0 = 0; float v0 = tot[0];
#pragma unroll
    for (int e = 1; e < 8; ++e) if (tot[e] > v0) { v0 = tot[e]; i0 = e; }
    int i1 = -1; float v1 = -__builtin_inff();
#pragma unroll
    for (int e = 0; e < 8; ++e) if (e != i0 && tot[e] > v1) { v1 = tot[e]; i1 = e; }
    const float ex = __expf(v1 - v0);
    const float den = 1.0f + ex;
    tok_e[row * 2] = i0; tok_e[row * 2 + 1] = i1;
    tok_g[row * 2] = 1.0f / den; tok_g[row * 2 + 1] = ex / den;
    atomicAdd(counts + i0, 1);
    atomicAdd(counts + i1, 1);
  }
}

// -------- RoPE -> split-bf16 Q [bh][L][64], K [bkvh][L][64] -----------------
// qkv arrives as 2 split-K slabs; fold the sum here (sole consumer of q/k part)
__global__ void rope_split(const float* __restrict__ qkv, const float* __restrict__ qkv2,
                           unsigned short* __restrict__ q_hi, unsigned short* __restrict__ q_lo,
                           unsigned short* __restrict__ k_hi, unsigned short* __restrict__ k_lo) {
  const int rowtok = blockIdx.x;
  const int b = rowtok >> 10;
  const int l = rowtok & 1023;
  const int tid = threadIdx.x;
  __shared__ float cb[32], sb[32];
  if (tid < 32) {
    float inv = powf(10000.0f, -(float)tid * (1.0f / 32.0f));
    float ang = (float)l * inv;
    cb[tid] = cosf(ang);
    sb[tid] = sinf(ang);
  }
  __syncthreads();
  const float* src  = qkv  + (size_t)rowtok * 1536;
  const float* src2 = qkv2 + (size_t)rowtok * 1536;
#pragma unroll
  for (int it = 0; it < 5; ++it) {
    const int e = tid + it * 256;
    const int hh = e >> 6;
    const int d = e & 63;
    const int dm = d & 31;
    float val = src[e] + src2[e];
    float partner = (d < 32) ? -(src[e + 32] + src2[e + 32]) : (src[e - 32] + src2[e - 32]);
    float ov = val * cb[dm] + partner * sb[dm];
    unsigned short hv = f2bf(ov);
    unsigned short lv = f2bf(ov - bf2f(hv));
    if (hh < 16) {
      size_t idx = ((size_t)(b * 16 + hh) * 1024 + l) * 64 + d;
      q_hi[idx] = hv; q_lo[idx] = lv;
    } else {
      size_t idx = ((size_t)(b * 4 + (hh - 16)) * 1024 + l) * 64 + d;
      k_hi[idx] = hv; k_lo[idx] = lv;
    }
  }
}

// -------- V transpose: qkv v-part [L][64] -> bf16 hi/lo [bkvh][64][L] -------
__global__ void vt_split(const float* __restrict__ qkv, const float* __restrict__ qkv2,
                         unsigned short* __restrict__ vt_hi, unsigned short* __restrict__ vt_lo) {
  const int bkvh = blockIdx.z;
  const int b = bkvh >> 2;
  const int kvh = bkvh & 3;
  const size_t sbase = (size_t)b * 1024 * 1536 + 1280 + kvh * 64;
  const float* src  = qkv  + sbase;
  const float* src2 = qkv2 + sbase;
  __shared__ float t[32][33];
  const int l0 = blockIdx.y * 32;
  const int d0 = blockIdx.x * 32;
  const int tx = threadIdx.x;
  const int ty = threadIdx.y;
#pragma unroll
  for (int i = 0; i < 4; ++i) {
    const size_t o = (size_t)(l0 + ty + i * 8) * 1536 + d0 + tx;
    t[ty + i * 8][tx] = src[o] + src2[o];
  }
  __syncthreads();
#pragma unroll
  for (int i = 0; i < 4; ++i) {
    float v = t[tx][ty + i * 8];
    size_t o = (size_t)bkvh * 65536 + (size_t)(d0 + ty + i * 8) * 1024 + l0 + tx;
    unsigned short h = f2bf(v);
    vt_hi[o] = h;
    vt_lo[o] = f2bf(v - bf2f(h));
  }
}

// ---------------- flash attention, split-bf16 MFMA, fp32 softmax ------------
__launch_bounds__(256, 2)
__global__ void attn_mfma(const unsigned short* __restrict__ q_hi, const unsigned short* __restrict__ q_lo,
                          const unsigned short* __restrict__ k_hi, const unsigned short* __restrict__ k_lo,
                          const unsigned short* __restrict__ vt_hi, const unsigned short* __restrict__ vt_lo,
                          unsigned short* __restrict__ ohi, unsigned short* __restrict__ olo) {
  const int blk = blockIdx.x;
  const int bh = blk & 31;               // (b,h)
  const int qt = 15 - (blk >> 5);        // long tiles dispatch first
  const int b = bh >> 4;
  const int h = bh & 15;
  const int kvbh = b * 4 + (h >> 2);
  const int q0 = qt * 64;
  const int tid = threadIdx.x;
  const int w = tid >> 6;
  const int lane = tid & 63;
  const int quad = lane >> 4;
  const int r16 = lane & 15;
  const int rl = lane >> 3;
  const int csl = lane & 7;
  const int cg = csl ^ rl;

  __shared__ unsigned short sK[2][64 * 64];
  __shared__ unsigned short sV[2][64 * 64];
  __shared__ unsigned short sP[2][64 * 64];

  short8 qfh[2], qfl[2];
  {
    const size_t qrow = ((size_t)bh * 1024 + q0 + w * 16 + r16) * 64 + quad * 8;
    qfh[0] = *(const short8*)(q_hi + qrow);
    qfh[1] = *(const short8*)(q_hi + qrow + 32);
    qfl[0] = *(const short8*)(q_lo + qrow);
    qfl[1] = *(const short8*)(q_lo + qrow + 32);
  }
  float4v O[4];
#pragma unroll
  for (int nt = 0; nt < 4; ++nt) O[nt] = float4v{0.f, 0.f, 0.f, 0.f};
  float m[4], l[4];
#pragma unroll
  for (int rg = 0; rg < 4; ++rg) { m[rg] = -__builtin_inff(); l[rg] = 0.f; }

  const unsigned short* khb = k_hi + (size_t)kvbh * 65536 + cg * 8;
  const unsigned short* klb = k_lo + (size_t)kvbh * 65536 + cg * 8;
  const unsigned short* vhb = vt_hi + (size_t)kvbh * 65536 + cg * 8;
  const unsigned short* vlb = vt_lo + (size_t)kvbh * 65536 + cg * 8;

  for (int c = 0; c <= qt; ++c) {
    __syncthreads();
#pragma unroll
    for (int j = 0; j < 2; ++j) {
      const int i = w * 2 + j;
      const int row = i * 8 + rl;
      gl_lds16(khb + (size_t)(c * 64 + row) * 64, (char*)sK[0] + i * 1024);
      gl_lds16(klb + (size_t)(c * 64 + row) * 64, (char*)sK[1] + i * 1024);
      gl_lds16(vhb + (size_t)row * 1024 + c * 64, (char*)sV[0] + i * 1024);
      gl_lds16(vlb + (size_t)row * 1024 + c * 64, (char*)sV[1] + i * 1024);
    }
    __syncthreads();

    float4v S[4];
#pragma unroll
    for (int nt = 0; nt < 4; ++nt) S[nt] = float4v{0.f, 0.f, 0.f, 0.f};
#pragma unroll
    for (int ks = 0; ks < 2; ++ks) {
#pragma unroll
      for (int nt = 0; nt < 4; ++nt) {
        const int r = nt * 16 + r16;
        const int o = (r * 8 + ((ks * 4 + quad) ^ (r & 7))) * 8;
        const short8 kh = *(const short8*)(sK[0] + o);
        const short8 kl = *(const short8*)(sK[1] + o);
        S[nt] = __builtin_amdgcn_mfma_f32_16x16x32_bf16(qfh[ks], kh, S[nt], 0, 0, 0);
        S[nt] = __builtin_amdgcn_mfma_f32_16x16x32_bf16(qfh[ks], kl, S[nt], 0, 0, 0);
        S[nt] = __builtin_amdgcn_mfma_f32_16x16x32_bf16(qfl[ks], kh, S[nt], 0, 0, 0);
      }
    }
    const float NEGINF = -__builtin_inff();
#pragma unroll
    for (int nt = 0; nt < 4; ++nt)
#pragma unroll
      for (int rg = 0; rg < 4; ++rg) S[nt][rg] *= 0.125f;
    if (c == qt) {
#pragma unroll
      for (int nt = 0; nt < 4; ++nt) {
        const int col = nt * 16 + r16;
#pragma unroll
        for (int rg = 0; rg < 4; ++rg) {
          const int row = w * 16 + quad * 4 + rg;
          if (col > row) S[nt][rg] = NEGINF;
        }
      }
    }
    float alpha[4], lsum[4];
#pragma unroll
    for (int rg = 0; rg < 4; ++rg) {
      float mx = fmaxf(fmaxf(S[0][rg], S[1][rg]), fmaxf(S[2][rg], S[3][rg]));
      mx = fmaxf(mx, __shfl_xor(mx, 1));
      mx = fmaxf(mx, __shfl_xor(mx, 2));
      mx = fmaxf(mx, __shfl_xor(mx, 4));
      mx = fmaxf(mx, __shfl_xor(mx, 8));
      const float mn = fmaxf(m[rg], mx);
      alpha[rg] = __expf(m[rg] - mn);
      m[rg] = mn;
      lsum[rg] = 0.f;
    }
#pragma unroll
    for (int nt = 0; nt < 4; ++nt)
#pragma unroll
      for (int rg = 0; rg < 4; ++rg) {
        const float e = __expf(S[nt][rg] - m[rg]);
        S[nt][rg] = e;
        lsum[rg] += e;
      }
#pragma unroll
    for (int rg = 0; rg < 4; ++rg) {
      float ls = lsum[rg];
      ls += __shfl_xor(ls, 1);
      ls += __shfl_xor(ls, 2);
      ls += __shfl_xor(ls, 4);
      ls += __shfl_xor(ls, 8);
      l[rg] = l[rg] * alpha[rg] + ls;
    }
#pragma unroll
    for (int nt = 0; nt < 4; ++nt) {
      const int key = nt * 16 + r16;
      const int chunk = key >> 3;
#pragma unroll
      for (int rg = 0; rg < 4; ++rg) {
        const int r = w * 16 + quad * 4 + rg;
        const int addr = r * 64 + ((chunk ^ (r & 7)) * 8) + (key & 7);
        const float e = S[nt][rg];
        const unsigned short hv = f2bf(e);
        sP[0][addr] = hv;
        sP[1][addr] = f2bf(e - bf2f(hv));
      }
    }
#pragma unroll
    for (int nt = 0; nt < 4; ++nt)
#pragma unroll
      for (int rg = 0; rg < 4; ++rg) O[nt][rg] *= alpha[rg];
#pragma unroll
    for (int ks = 0; ks < 2; ++ks) {
      const int rA = w * 16 + r16;
      const int oA = (rA * 8 + ((ks * 4 + quad) ^ (rA & 7))) * 8;
      const short8 ph = *(const short8*)(sP[0] + oA);
      const short8 pl = *(const short8*)(sP[1] + oA);
#pragma unroll
      for (int nt = 0; nt < 4; ++nt) {
        const int rv = nt * 16 + r16;
        const int ov = (rv * 8 + ((ks * 4 + quad) ^ (rv & 7))) * 8;
        const short8 vh = *(const short8*)(sV[0] + ov);
        const short8 vl = *(const short8*)(sV[1] + ov);
        O[nt] = __builtin_amdgcn_mfma_f32_16x16x32_bf16(ph, vh, O[nt], 0, 0, 0);
        O[nt] = __builtin_amdgcn_mfma_f32_16x16x32_bf16(ph, vl, O[nt], 0, 0, 0);
        O[nt] = __builtin_amdgcn_mfma_f32_16x16x32_bf16(pl, vh, O[nt], 0, 0, 0);
      }
    }
  }
#pragma unroll
  for (int nt = 0; nt < 4; ++nt) {
    const int col = h * 64 + nt * 16 + r16;
#pragma unroll
    for (int rg = 0; rg < 4; ++rg) {
      const int row = q0 + w * 16 + quad * 4 + rg;
      const float ovv = O[nt][rg] / l[rg];
      const size_t idx = ((size_t)b * 1024 + row) * DMODEL + col;
      const unsigned short hv = f2bf(ovv);
      ohi[idx] = hv;
      olo[idx] = f2bf(ovv - bf2f(hv));
    }
  }
}

__global__ void finalize_kernel(const int* __restrict__ counts, int* __restrict__ off_pad,
                                int* __restrict__ tile_map, float* __restrict__ lb_out) {
  if (threadIdx.x == 0 && blockIdx.x == 0) {
    int tile = 0, rowoff = 0;
    for (int e = 0; e < NEXP; ++e) {
      off_pad[e] = rowoff;
      const int c = counts[e];
      const int nt = (c + 127) >> 7;
      for (int i = 0; i < nt; ++i) tile_map[tile++] = e;
      rowoff += nt * 128;
    }
    for (; tile < MAXTILES; ++tile) tile_map[tile] = -1;
    float sacc = 0.f;
    for (int e = 0; e < NEXP; ++e) {
      const float cn = (float)counts[e] * (1.0f / 4096.0f);
      const float d = cn - 0.125f;
      sacc += d * d;
    }
    lb_out[0] = sacc * (1.0f / 8.0f);
  }
}

__global__ void scatter_kernel(const int* __restrict__ tok_e, const int* __restrict__ off_pad,
                               int* __restrict__ fill, int* __restrict__ tok_pos,
                               const unsigned short* __restrict__ h2bf, unsigned short* __restrict__ Xg) {
  const int slot = blockIdx.x;
  const int t = slot >> 1;
  __shared__ int sp;
  if (threadIdx.x == 0) {
    const int e = tok_e[slot];
    const int r = atomicAdd(fill + e, 1);
    const int ppos = off_pad[e] + r;
    tok_pos[slot] = ppos;
    sp = ppos;
  }
  __syncthreads();
  const int pos = sp;
  *(uint2*)(Xg + (size_t)pos * DMODEL + threadIdx.x * 4) =
      *(const uint2*)(h2bf + (size_t)t * DMODEL + threadIdx.x * 4);
}

// ----- combine: out = x1 + g0*sum_z eout_z[p0] + g1*sum_z eout_z[p1] --------
__global__ void combine_kernel(const float* __restrict__ x1, const float* __restrict__ eout,
                               const int* __restrict__ tok_pos, const float* __restrict__ tok_g,
                               float* __restrict__ out) {
  const int t = blockIdx.x;
  const int tid = threadIdx.x;
  const int p0 = tok_pos[t * 2], p1 = tok_pos[t * 2 + 1];
  const float g0 = tok_g[t * 2], g1 = tok_g[t * 2 + 1];
  const size_t o = (size_t)t * DMODEL + tid * 4;
  const float4 a = *(const float4*)(x1 + o);
  float s0x = 0.f, s0y = 0.f, s0z = 0.f, s0w = 0.f;
  float s1x = 0.f, s1y = 0.f, s1z = 0.f, s1w = 0.f;
#pragma unroll
  for (int z = 0; z < 4; ++z) {
    const size_t zb = (size_t)z * MAXROWS * DMODEL;
    const float4 e0 = *(const float4*)(eout + zb + (size_t)p0 * DMODEL + tid * 4);
    const float4 e1 = *(const float4*)(eout + zb + (size_t)p1 * DMODEL + tid * 4);
    s0x += e0.x; s0y += e0.y; s0z += e0.z; s0w += e0.w;
    s1x += e1.x; s1y += e1.y; s1z += e1.z; s1w += e1.w;
  }
  float4 r;
  r.x = a.x + g0 * s0x + g1 * s1x;
  r.y = a.y + g0 * s0y + g1 * s1y;
  r.z = a.z + g0 * s0z + g1 * s1z;
  r.w = a.w + g0 * s0w + g1 * s1w;
  *(float4*)(out + o) = r;
}

extern "C" void kernel_launch(void* const* d_in, const int* in_sizes, int n_in,
                              void* d_out, int out_size, void* d_ws, size_t ws_size,
                              hipStream_t stream) {
  (void)in_sizes; (void)n_in; (void)out_size; (void)ws_size;
  const float* x    = (const float*)d_in[0];
  const float* wq   = (const float*)d_in[1];
  const float* wk   = (const float*)d_in[2];
  const float* wv   = (const float*)d_in[3];
  const float* wo   = (const float*)d_in[4];
  const float* wg   = (const float*)d_in[5];
  const float* w1   = (const float*)d_in[6];
  const float* w2   = (const float*)d_in[7];
  const float* ln1g = (const float*)d_in[8];
  const float* ln1b = (const float*)d_in[9];
  const float* ln2g = (const float*)d_in[10];
  const float* ln2b = (const float*)d_in[11];
  float* out = (float*)d_out;

  char* p = (char*)d_ws;
  auto take = [&](size_t n) { void* r = (void*)p; p += (n + 255) & ~(size_t)255; return r; };
  unsigned short* h1_hi   = (unsigned short*)take((size_t)NTOK * DMODEL * 2);
  unsigned short* h1_lo   = (unsigned short*)take((size_t)NTOK * DMODEL * 2);
  unsigned short* wqkv_hi = (unsigned short*)take((size_t)1536 * 1024 * 2);
  unsigned short* wqkv_lo = (unsigned short*)take((size_t)1536 * 1024 * 2);
  unsigned short* woT_hi  = (unsigned short*)take((size_t)1024 * 1024 * 2);
  unsigned short* woT_lo  = (unsigned short*)take((size_t)1024 * 1024 * 2);
  unsigned short* w1t     = (unsigned short*)take((size_t)NEXP * DFF * DMODEL * 2);
  unsigned short* w2t     = (unsigned short*)take((size_t)NEXP * DMODEL * DFF * 2);
  float* qkv   = (float*)take((size_t)2 * NTOK * 1536 * 4);          // 2 split-K slabs
  unsigned short* q_hi  = (unsigned short*)take((size_t)2 * 16 * 1024 * 64 * 2);
  unsigned short* q_lo  = (unsigned short*)take((size_t)2 * 16 * 1024 * 64 * 2);
  unsigned short* k_hi  = (unsigned short*)take((size_t)2 * 4 * 1024 * 64 * 2);
  unsigned short* k_lo  = (unsigned short*)take((size_t)2 * 4 * 1024 * 64 * 2);
  unsigned short* vt_hi = (unsigned short*)take((size_t)2 * 4 * 1024 * 64 * 2);
  unsigned short* vt_lo = (unsigned short*)take((size_t)2 * 4 * 1024 * 64 * 2);
  unsigned short* attn_hi = (unsigned short*)take((size_t)NTOK * DMODEL * 2);
  unsigned short* attn_lo = (unsigned short*)take((size_t)NTOK * DMODEL * 2);
  float* x1p   = (float*)take((size_t)4 * NTOK * DMODEL * 4);        // 4 split-K slabs
  float* x1    = (float*)take((size_t)NTOK * DMODEL * 4);
  unsigned short* h2bf = (unsigned short*)take((size_t)NTOK * DMODEL * 2);
  unsigned short* Xg   = (unsigned short*)take((size_t)MAXROWS * DMODEL * 2);
  unsigned short* hid  = (unsigned short*)take((size_t)MAXROWS * DFF * 2);
  float* eout  = (float*)take((size_t)4 * MAXROWS * DMODEL * 4);     // 4 split-K slabs
  int*   tok_e   = (int*)take(4096 * 4);
  float* tok_g   = (float*)take(4096 * 4);
  int*   tok_pos = (int*)take(4096 * 4);
  int*   counts  = (int*)take(64);
  int*   fill    = (int*)take(64);
  int*   off_pad = (int*)take(64);
  int*   tile_map = (int*)take(256);

  // fused wq/wk/wv/wo transpose + counts/fill init (replaces 4 launches + init)
  transpose_qkvo<<<dim3(16, 16, 4), 256, 0, stream>>>(wq, wk, wv, wo, wqkv_hi, wqkv_lo,
                                                      woT_hi, woT_lo, counts, fill);
  ln_kernel<<<NTOK, 256, 0, stream>>>(x, ln1g, ln1b, h1_hi, h1_lo);
  transpose_w<0><<<dim3(64, 16, 8), 256, 0, stream>>>(w1, w1t, nullptr, 1024, 4096, (long)1024 * 4096, (long)4096 * 1024);
  transpose_w<0><<<dim3(16, 64, 8), 256, 0, stream>>>(w2, w2t, nullptr, 4096, 1024, (long)4096 * 1024, (long)1024 * 4096);
  // qkv = h1 @ [wq|wk|wv], split-K x2 (384 blocks), XCD-swizzled
  gemm_split<<<dim3(12, 16, 2), 256, 0, stream>>>(h1_hi, h1_lo, wqkv_hi, wqkv_lo, qkv, 1536, 1024, 512, (long)NTOK * 1536);
  rope_split<<<NTOK, 256, 0, stream>>>(qkv, qkv + (size_t)NTOK * 1536, q_hi, q_lo, k_hi, k_lo);
  vt_split<<<dim3(2, 32, 8), dim3(32, 8), 0, stream>>>(qkv, qkv + (size_t)NTOK * 1536, vt_hi, vt_lo);
  attn_mfma<<<512, 256, 0, stream>>>(q_hi, q_lo, k_hi, k_lo, vt_hi, vt_lo, attn_hi, attn_lo);
  // wo projection: split-K x4 (512 blocks); residual + ln2 + router fused next
  gemm_split<<<dim3(8, 16, 4), 256, 0, stream>>>(attn_hi, attn_lo, woT_hi, woT_lo, x1p, 1024, 1024, 256, (long)NTOK * DMODEL);
  // fused: x1 = x + sum(slabs); ln2; h2bf; router (replaces 3 launches)
  fused_ln2_router<<<NTOK, 256, 0, stream>>>(x, x1p, ln2g, ln2b, x1, h2bf, wg, tok_e, tok_g, counts);
  finalize_kernel<<<1, 64, 0, stream>>>(counts, off_pad, tile_map, out + (size_t)NTOK * DMODEL);
  scatter_kernel<<<4096, 256, 0, stream>>>(tok_e, off_pad, fill, tok_pos, h2bf, Xg);
  // w1 GEMM: gelu epilogue tanh-form (cheap), XCD-swizzled
  gemm_bt<3,1><<<dim3(32, MAXTILES), 256, 0, stream>>>(Xg, w1t, nullptr, hid, DFF, DMODEL, DMODEL, 0, tile_map, (long)DFF * DMODEL);
  // expert down-proj: split-K x4 (1280 blocks), XCD-swizzled
  gemm_bt<0,1><<<dim3(8, MAXTILES, 4), 256, 0, stream>>>(hid, w2t, eout, nullptr, DMODEL, DFF, 1024, (long)MAXROWS * DMODEL, tile_map, (long)DMODEL * DFF);
  combine_kernel<<<NTOK, 256, 0, stream>>>(x1, eout, tok_pos, tok_g, out);
}

// Round 7
// 672.194 us; speedup vs baseline: 1.5317x; 1.0036x over previous
//
#include <hip/hip_runtime.h>
#include <hip/hip_bf16.h>

#define NTOK   2048      // B*L
#define DMODEL 1024
#define NEXP   8
#define DFF    4096
#define MAXROWS 5120
#define MAXTILES 40

typedef __attribute__((ext_vector_type(8))) short short8;
typedef __attribute__((ext_vector_type(4))) float float4v;

__device__ __forceinline__ unsigned short f2bf(float f) {
  union { float f; unsigned u; } v; v.f = f;
  unsigned r = v.u + 0x7fffu + ((v.u >> 16) & 1u);
  return (unsigned short)(r >> 16);
}
__device__ __forceinline__ float bf2f(unsigned short h) {
  union { unsigned u; float f; } v; v.u = ((unsigned)h) << 16; return v.f;
}
__device__ __forceinline__ void gl_lds16(const void* g, void* l) {
  __builtin_amdgcn_global_load_lds((const __attribute__((address_space(1))) void*)g,
                                   (__attribute__((address_space(3))) void*)l, 16, 0, 0);
}

// bijective XCD swizzle: consecutive HW bids round-robin over 8 XCDs; give each
// XCD a contiguous chunk of logical tile space (requires nwg % 8 == 0).
__device__ __forceinline__ int xcd_swz(int bid, int nwg) {
  if (nwg & 7) return bid;
  const int chunk = nwg >> 3;
  return (bid & 7) * chunk + (bid >> 3);
}

// ---------------- GEMM: C[M,N] = A[M,K](bf16) x B[N,K]^T(bf16), fp32 acc ---
// EPI: 0 C=acc ; 3 Cbf=bf16(gelu(acc))
// split-K: z covers k in [z*kslice, (z+1)*kslice), partial C slab at z*zstride
// launch_bounds(256,4): 4 waves/EU -> 128-reg budget; kernel needs ~60 VGPR +
// 64 AGPR acc. (256,5) caps at ~102 regs and SPILLS the accumulator to
// scratch: R3 measured WRITE_SIZE 38->303 MB, 78->253us. Do not raise.
template<int EPI, int EMAP>
__launch_bounds__(256, 4)
__global__ void gemm_bt(const unsigned short* __restrict__ A,
                        const unsigned short* __restrict__ B0,
                        float* __restrict__ C,
                        unsigned short* __restrict__ Cbf,
                        const int N, const int K,
                        const int kslice, const long zstride,
                        const int* __restrict__ tmap, const long estride) {
  // ---- XCD-swizzled logical tile id ----
  const int gx = gridDim.x, gy = gridDim.y;
  const int nwg = gx * gy * gridDim.z;
  const int lid = xcd_swz(blockIdx.x + gx * (blockIdx.y + gy * blockIdx.z), nwg);
  const int bx = lid % gx;
  const int t1 = lid / gx;
  const int mtile = t1 % gy;
  const int bz = t1 / gy;

  const unsigned short* B = B0;
  if (EMAP) {
    int e = tmap[mtile];
    if (e < 0) return;
    B += (size_t)e * (size_t)estride;
  }
  const int n0 = bx * 128;
  const int m0 = mtile * 128;
  if (EPI == 0) C += (size_t)bz * (size_t)zstride;
  __shared__ unsigned short sA[128 * 64];
  __shared__ unsigned short sB[128 * 64];
  const int tid  = threadIdx.x;
  const int w    = tid >> 6;
  const int lane = tid & 63;
  const int quad = lane >> 4;
  const int r16  = lane & 15;
  const int wr   = w >> 1;
  const int wc   = w & 1;
  const int rl   = lane >> 3;
  const int csl  = lane & 7;
  const int cg   = csl ^ rl;
  float4v acc[4][4];
#pragma unroll
  for (int i = 0; i < 4; ++i)
#pragma unroll
    for (int j = 0; j < 4; ++j) acc[i][j] = float4v{0.f, 0.f, 0.f, 0.f};

  const unsigned short* Ab = A + (size_t)m0 * K + cg * 8;
  const unsigned short* Bb = B + (size_t)n0 * K + cg * 8;

  const int kbeg = bz * kslice;
  const int kend = kbeg + kslice;
  for (int k0 = kbeg; k0 < kend; k0 += 64) {
    __syncthreads();
#pragma unroll
    for (int i = 0; i < 4; ++i) {
      const int j = w * 4 + i;
      gl_lds16(Ab + (size_t)(j * 8 + rl) * K + k0, (char*)sA + j * 1024);
      gl_lds16(Bb + (size_t)(j * 8 + rl) * K + k0, (char*)sB + j * 1024);
    }
    __syncthreads();
#pragma unroll
    for (int kc = 0; kc < 8; kc += 4) {
      short8 af[4], bq[4];
#pragma unroll
      for (int mt = 0; mt < 4; ++mt) {
        int r = wr * 64 + mt * 16 + r16;
        af[mt] = *(const short8*)(sA + ((r * 8 + ((kc + quad) ^ (r & 7))) * 8));
      }
#pragma unroll
      for (int nt = 0; nt < 4; ++nt) {
        int r = wc * 64 + nt * 16 + r16;
        bq[nt] = *(const short8*)(sB + ((r * 8 + ((kc + quad) ^ (r & 7))) * 8));
      }
#pragma unroll
      for (int mt = 0; mt < 4; ++mt)
#pragma unroll
        for (int nt = 0; nt < 4; ++nt)
          acc[mt][nt] = __builtin_amdgcn_mfma_f32_16x16x32_bf16(af[mt], bq[nt], acc[mt][nt], 0, 0, 0);
    }
  }
#pragma unroll
  for (int mt = 0; mt < 4; ++mt) {
#pragma unroll
    for (int nt = 0; nt < 4; ++nt) {
#pragma unroll
      for (int rg = 0; rg < 4; ++rg) {
        const int m = m0 + wr * 64 + mt * 16 + quad * 4 + rg;
        const int n = n0 + wc * 64 + nt * 16 + r16;
        const size_t idx = (size_t)m * N + n;
        const float v = acc[mt][nt][rg];
        if (EPI == 0) C[idx] = v;
        else {
          // tanh-form gelu: x*sigmoid(1.5958(x+0.044715x^3)); |err| ~1e-4,
          // far below hid's bf16 quantization. Replaces ~25-op erff.
          const float u = v + 0.044715f * v * v * v;
          const float ge = v / (1.0f + __expf(-1.5957691216f * u));
          Cbf[idx] = f2bf(ge);
        }
      }
    }
  }
}

// ------- split-bf16 GEMM: C = (Ah+Al)x(Bh+Bl)^T, 3 terms, split-K slabs -----
// 64KB LDS -> hard cap of 2 blocks/CU; do not raise launch_bounds.
__launch_bounds__(256, 2)
__global__ void gemm_split(const unsigned short* __restrict__ Ah,
                           const unsigned short* __restrict__ Al,
                           const unsigned short* __restrict__ Bh,
                           const unsigned short* __restrict__ Bl,
                           float* __restrict__ C,
                           const int N, const int K,
                           const int kslice, const long zstride) {
  const int gx = gridDim.x, gy = gridDim.y;
  const int nwg = gx * gy * gridDim.z;
  const int lid = xcd_swz(blockIdx.x + gx * (blockIdx.y + gy * blockIdx.z), nwg);
  const int bx = lid % gx;
  const int t1 = lid / gx;
  const int by = t1 % gy;
  const int bz = t1 / gy;

  const int n0 = bx * 128;
  const int m0 = by * 128;
  C += (size_t)bz * (size_t)zstride;
  __shared__ unsigned short sAh[128 * 64];
  __shared__ unsigned short sAl[128 * 64];
  __shared__ unsigned short sBh[128 * 64];
  __shared__ unsigned short sBl[128 * 64];
  const int tid  = threadIdx.x;
  const int w    = tid >> 6;
  const int lane = tid & 63;
  const int quad = lane >> 4;
  const int r16  = lane & 15;
  const int wr   = w >> 1;
  const int wc   = w & 1;
  const int rl   = lane >> 3;
  const int csl  = lane & 7;
  const int cg   = csl ^ rl;
  float4v acc[4][4];
#pragma unroll
  for (int i = 0; i < 4; ++i)
#pragma unroll
    for (int j = 0; j < 4; ++j) acc[i][j] = float4v{0.f, 0.f, 0.f, 0.f};

  const size_t aoff = (size_t)m0 * K + cg * 8;
  const size_t boff = (size_t)n0 * K + cg * 8;

  const int kbeg = bz * kslice;
  const int kend = kbeg + kslice;
  for (int k0 = kbeg; k0 < kend; k0 += 64) {
    __syncthreads();
#pragma unroll
    for (int i = 0; i < 4; ++i) {
      const int j = w * 4 + i;
      const size_t ro = (size_t)(j * 8 + rl) * K + k0;
      gl_lds16(Ah + aoff + ro, (char*)sAh + j * 1024);
      gl_lds16(Al + aoff + ro, (char*)sAl + j * 1024);
      gl_lds16(Bh + boff + ro, (char*)sBh + j * 1024);
      gl_lds16(Bl + boff + ro, (char*)sBl + j * 1024);
    }
    __syncthreads();
#pragma unroll
    for (int kc = 0; kc < 8; kc += 4) {
      short8 afh[4], afl[4], bqh[4], bql[4];
#pragma unroll
      for (int mt = 0; mt < 4; ++mt) {
        int r = wr * 64 + mt * 16 + r16;
        int o = (r * 8 + ((kc + quad) ^ (r & 7))) * 8;
        afh[mt] = *(const short8*)(sAh + o);
        afl[mt] = *(const short8*)(sAl + o);
      }
#pragma unroll
      for (int nt = 0; nt < 4; ++nt) {
        int r = wc * 64 + nt * 16 + r16;
        int o = (r * 8 + ((kc + quad) ^ (r & 7))) * 8;
        bqh[nt] = *(const short8*)(sBh + o);
        bql[nt] = *(const short8*)(sBl + o);
      }
#pragma unroll
      for (int mt = 0; mt < 4; ++mt)
#pragma unroll
        for (int nt = 0; nt < 4; ++nt) {
          acc[mt][nt] = __builtin_amdgcn_mfma_f32_16x16x32_bf16(afh[mt], bqh[nt], acc[mt][nt], 0, 0, 0);
          acc[mt][nt] = __builtin_amdgcn_mfma_f32_16x16x32_bf16(afh[mt], bql[nt], acc[mt][nt], 0, 0, 0);
          acc[mt][nt] = __builtin_amdgcn_mfma_f32_16x16x32_bf16(afl[mt], bqh[nt], acc[mt][nt], 0, 0, 0);
        }
    }
  }
#pragma unroll
  for (int mt = 0; mt < 4; ++mt) {
#pragma unroll
    for (int nt = 0; nt < 4; ++nt) {
#pragma unroll
      for (int rg = 0; rg < 4; ++rg) {
        const int m = m0 + wr * 64 + mt * 16 + quad * 4 + rg;
        const int n = n0 + wc * 64 + nt * 16 + r16;
        C[(size_t)m * N + n] = acc[mt][nt][rg];
      }
    }
  }
}

// --- fused w1+w2 transpose: fp32 [K,N] -> bf16 [N,K], 1D grid, one launch ---
// blocks 0..8191: w1 (8 experts x 64x16 tiles of 64x64, K=1024,N=4096)
// blocks 8192..16383: w2 (8 experts x 16x64 tiles, K=4096,N=1024)
__global__ void transpose_w12(const float* __restrict__ w1, const float* __restrict__ w2,
                              unsigned short* __restrict__ w1t, unsigned short* __restrict__ w2t) {
  const int t = blockIdx.x;
  const float* in;
  unsigned short* oh;
  int K, N, n0, k0;
  if (t < 8192) {
    const int bz = t >> 10, rem = t & 1023;
    K = 1024; N = 4096;
    in = w1 + (size_t)bz * 1024 * 4096;
    oh = w1t + (size_t)bz * 4096 * 1024;
    n0 = (rem & 63) * 64; k0 = (rem >> 6) * 64;
  } else {
    const int u = t - 8192;
    const int bz = u >> 10, rem = u & 1023;
    K = 4096; N = 1024;
    in = w2 + (size_t)bz * 4096 * 1024;
    oh = w2t + (size_t)bz * 1024 * 4096;
    n0 = (rem & 15) * 64; k0 = (rem >> 4) * 64;
  }
  __shared__ float tl[64][65];
  const int tid = threadIdx.x;
  const int rr = tid >> 4;
  const int c4 = (tid & 15) * 4;
#pragma unroll
  for (int p = 0; p < 4; ++p) {
    const int row = p * 16 + rr;
    const float4 v = *(const float4*)(in + (size_t)(k0 + row) * N + n0 + c4);
    tl[row][c4] = v.x; tl[row][c4 + 1] = v.y; tl[row][c4 + 2] = v.z; tl[row][c4 + 3] = v.w;
  }
  __syncthreads();
#pragma unroll
  for (int p = 0; p < 4; ++p) {
    const int n = p * 16 + rr;
    ushort4 h;
    h.x = f2bf(tl[c4][n]); h.y = f2bf(tl[c4 + 1][n]);
    h.z = f2bf(tl[c4 + 2][n]); h.w = f2bf(tl[c4 + 3][n]);
    *(ushort4*)(oh + (size_t)(n0 + n) * K + k0 + c4) = h;
  }
}

// --- fused wq/wk/wv/wo transpose (hi+lo) + counts/fill init, one launch -----
__global__ void transpose_qkvo(const float* __restrict__ wq, const float* __restrict__ wk,
                               const float* __restrict__ wv, const float* __restrict__ wo,
                               unsigned short* __restrict__ wqkv_hi, unsigned short* __restrict__ wqkv_lo,
                               unsigned short* __restrict__ woT_hi, unsigned short* __restrict__ woT_lo,
                               int* __restrict__ counts, int* __restrict__ fill) {
  if (blockIdx.x == 0 && blockIdx.y == 0 && blockIdx.z == 0 && threadIdx.x < 16) {
    if (threadIdx.x < 8) counts[threadIdx.x] = 0;
    else fill[threadIdx.x - 8] = 0;
  }
  const int z = blockIdx.z;
  const float* in;
  unsigned short *oh, *ol;
  int N, xmax;
  if (z == 0)      { in = wq; oh = wqkv_hi;                         ol = wqkv_lo;                         N = 1024; xmax = 16; }
  else if (z == 1) { in = wk; oh = wqkv_hi + (size_t)1024 * 1024;   ol = wqkv_lo + (size_t)1024 * 1024;   N = 256;  xmax = 4; }
  else if (z == 2) { in = wv; oh = wqkv_hi + (size_t)1280 * 1024;   ol = wqkv_lo + (size_t)1280 * 1024;   N = 256;  xmax = 4; }
  else             { in = wo; oh = woT_hi;                          ol = woT_lo;                          N = 1024; xmax = 16; }
  if (blockIdx.x >= xmax) return;
  const int K = 1024;
  __shared__ float t[64][65];
  const int n0 = blockIdx.x * 64;
  const int k0 = blockIdx.y * 64;
  const int tid = threadIdx.x;
  const int rr = tid >> 4;
  const int c4 = (tid & 15) * 4;
#pragma unroll
  for (int p = 0; p < 4; ++p) {
    const int row = p * 16 + rr;
    const float4 v = *(const float4*)(in + (size_t)(k0 + row) * N + n0 + c4);
    t[row][c4] = v.x; t[row][c4 + 1] = v.y; t[row][c4 + 2] = v.z; t[row][c4 + 3] = v.w;
  }
  __syncthreads();
#pragma unroll
  for (int p = 0; p < 4; ++p) {
    const int n = p * 16 + rr;
    float vs[4];
#pragma unroll
    for (int i = 0; i < 4; ++i) vs[i] = t[c4 + i][n];
    ushort4 h;
    h.x = f2bf(vs[0]); h.y = f2bf(vs[1]); h.z = f2bf(vs[2]); h.w = f2bf(vs[3]);
    const size_t o = (size_t)(n0 + n) * K + k0 + c4;
    *(ushort4*)(oh + o) = h;
    ushort4 lo4;
    lo4.x = f2bf(vs[0] - bf2f(h.x));
    lo4.y = f2bf(vs[1] - bf2f(h.y));
    lo4.z = f2bf(vs[2] - bf2f(h.z));
    lo4.w = f2bf(vs[3] - bf2f(h.w));
    *(ushort4*)(ol + o) = lo4;
  }
}

// ---------------- LayerNorm over D=1024 (ln1: hi+lo) ------------------------
__global__ void ln_kernel(const float* __restrict__ x, const float* __restrict__ g,
                          const float* __restrict__ b, unsigned short* __restrict__ hi,
                          unsigned short* __restrict__ lo) {
  const int row = blockIdx.x;
  const int tid = threadIdx.x;
  const int w = tid >> 6, lane = tid & 63;
  const float4 v = *(const float4*)(x + (size_t)row * DMODEL + tid * 4);
  float s = v.x + v.y + v.z + v.w;
  float q = v.x * v.x + v.y * v.y + v.z * v.z + v.w * v.w;
#pragma unroll
  for (int o = 32; o; o >>= 1) { s += __shfl_xor(s, o); q += __shfl_xor(q, o); }
  __shared__ float red[8];
  if (lane == 0) { red[w] = s; red[4 + w] = q; }
  __syncthreads();
  s = red[0] + red[1] + red[2] + red[3];
  q = red[4] + red[5] + red[6] + red[7];
  const float mean = s * (1.0f / DMODEL);
  const float var = q * (1.0f / DMODEL) - mean * mean;
  const float rs = rsqrtf(var + 1e-5f);
  const float4 gg = *(const float4*)(g + tid * 4);
  const float4 bb = *(const float4*)(b + tid * 4);
  float y[4];
  y[0] = (v.x - mean) * rs * gg.x + bb.x;
  y[1] = (v.y - mean) * rs * gg.y + bb.y;
  y[2] = (v.z - mean) * rs * gg.z + bb.z;
  y[3] = (v.w - mean) * rs * gg.w + bb.w;
  const size_t base = (size_t)row * DMODEL + tid * 4;
  ushort4 h4, l4;
  h4.x = f2bf(y[0]); h4.y = f2bf(y[1]); h4.z = f2bf(y[2]); h4.w = f2bf(y[3]);
  l4.x = f2bf(y[0] - bf2f(h4.x));
  l4.y = f2bf(y[1] - bf2f(h4.y));
  l4.z = f2bf(y[2] - bf2f(h4.z));
  l4.w = f2bf(y[3] - bf2f(h4.w));
  *(ushort4*)(hi + base) = h4;
  *(ushort4*)(lo + base) = l4;
}

#define RED6SUM(X) { X += __shfl_xor(X,32); X += __shfl_xor(X,16); X += __shfl_xor(X,8); X += __shfl_xor(X,4); X += __shfl_xor(X,2); X += __shfl_xor(X,1); }

// --- fused: x1 = x + sum(4 wo slabs); ln2; h2bf; router top-2 + counts ------
__global__ void fused_ln2_router(const float* __restrict__ x, const float* __restrict__ x1p,
                                 const float* __restrict__ g, const float* __restrict__ b,
                                 float* __restrict__ x1, unsigned short* __restrict__ h2bf,
                                 const float* __restrict__ wg,
                                 int* __restrict__ tok_e, float* __restrict__ tok_g,
                                 int* __restrict__ counts) {
  const int row = blockIdx.x;
  const int tid = threadIdx.x;
  const int w = tid >> 6, lane = tid & 63;
  const size_t base = (size_t)row * DMODEL + tid * 4;
  float4 v = *(const float4*)(x + base);
#pragma unroll
  for (int z = 0; z < 4; ++z) {
    const float4 p = *(const float4*)(x1p + (size_t)z * NTOK * DMODEL + base);
    v.x += p.x; v.y += p.y; v.z += p.z; v.w += p.w;
  }
  *(float4*)(x1 + base) = v;
  float s = v.x + v.y + v.z + v.w;
  float q = v.x * v.x + v.y * v.y + v.z * v.z + v.w * v.w;
#pragma unroll
  for (int o = 32; o; o >>= 1) { s += __shfl_xor(s, o); q += __shfl_xor(q, o); }
  __shared__ float red[8];
  if (lane == 0) { red[w] = s; red[4 + w] = q; }
  __syncthreads();
  s = red[0] + red[1] + red[2] + red[3];
  q = red[4] + red[5] + red[6] + red[7];
  const float mean = s * (1.0f / DMODEL);
  const float var = q * (1.0f / DMODEL) - mean * mean;
  const float rs = rsqrtf(var + 1e-5f);
  const float4 gg = *(const float4*)(g + tid * 4);
  const float4 bb = *(const float4*)(b + tid * 4);
  float y[4];
  y[0] = (v.x - mean) * rs * gg.x + bb.x;
  y[1] = (v.y - mean) * rs * gg.y + bb.y;
  y[2] = (v.z - mean) * rs * gg.z + bb.z;
  y[3] = (v.w - mean) * rs * gg.w + bb.w;
  ushort4 h4;
  h4.x = f2bf(y[0]); h4.y = f2bf(y[1]); h4.z = f2bf(y[2]); h4.w = f2bf(y[3]);
  *(ushort4*)(h2bf + base) = h4;
  float acc[8] = {0, 0, 0, 0, 0, 0, 0, 0};
#pragma unroll
  for (int i = 0; i < 4; ++i) {
    const int d = tid * 4 + i;
    const float4 w0 = *(const float4*)(wg + d * 8);
    const float4 w1v = *(const float4*)(wg + d * 8 + 4);
    acc[0] += y[i] * w0.x;  acc[1] += y[i] * w0.y;  acc[2] += y[i] * w0.z;  acc[3] += y[i] * w0.w;
    acc[4] += y[i] * w1v.x; acc[5] += y[i] * w1v.y; acc[6] += y[i] * w1v.z; acc[7] += y[i] * w1v.w;
  }
#pragma unroll
  for (int e = 0; e < 8; ++e) { RED6SUM(acc[e]); }
  __shared__ float racc[4][8];
  if (lane == 0) {
#pragma unroll
    for (int e = 0; e < 8; ++e) racc[w][e] = acc[e];
  }
  __syncthreads();
  if (tid == 0) {
    float tot[8];
#pragma unroll
    for (int e = 0; e < 8; ++e) tot[e] = racc[0][e] + racc[1][e] + racc[2][e] + racc[3][e];
    int i0 = 0; float v0 = tot[0];
#pragma unroll
    for (int e = 1; e < 8; ++e) if (tot[e] > v0) { v0 = tot[e]; i0 = e; }
    int i1 = -1; float v1 = -__builtin_inff();
#pragma unroll
    for (int e = 0; e < 8; ++e) if (e != i0 && tot[e] > v1) { v1 = tot[e]; i1 = e; }
    const float ex = __expf(v1 - v0);
    const float den = 1.0f + ex;
    tok_e[row * 2] = i0; tok_e[row * 2 + 1] = i1;
    tok_g[row * 2] = 1.0f / den; tok_g[row * 2 + 1] = ex / den;
    atomicAdd(counts + i0, 1);
    atomicAdd(counts + i1, 1);
  }
}

// --- fused RoPE + V-transpose, one launch (both consume the qkv slabs) ------
// blocks 0..2047: rope for token blk; blocks 2048..2559: vt tile.
__global__ void rope_vt(const float* __restrict__ qkv, const float* __restrict__ qkv2,
                        unsigned short* __restrict__ q_hi, unsigned short* __restrict__ q_lo,
                        unsigned short* __restrict__ k_hi, unsigned short* __restrict__ k_lo,
                        unsigned short* __restrict__ vt_hi, unsigned short* __restrict__ vt_lo) {
  const int blk = blockIdx.x;
  const int tid = threadIdx.x;
  if (blk < 2048) {
    const int rowtok = blk;
    const int b = rowtok >> 10;
    const int l = rowtok & 1023;
    __shared__ float cb[32], sb[32];
    if (tid < 32) {
      float inv = powf(10000.0f, -(float)tid * (1.0f / 32.0f));
      float ang = (float)l * inv;
      cb[tid] = cosf(ang);
      sb[tid] = sinf(ang);
    }
    __syncthreads();
    const float* src  = qkv  + (size_t)rowtok * 1536;
    const float* src2 = qkv2 + (size_t)rowtok * 1536;
#pragma unroll
    for (int it = 0; it < 5; ++it) {
      const int e = tid + it * 256;
      const int hh = e >> 6;
      const int d = e & 63;
      const int dm = d & 31;
      float val = src[e] + src2[e];
      float partner = (d < 32) ? -(src[e + 32] + src2[e + 32]) : (src[e - 32] + src2[e - 32]);
      float ov = val * cb[dm] + partner * sb[dm];
      unsigned short hv = f2bf(ov);
      unsigned short lv = f2bf(ov - bf2f(hv));
      if (hh < 16) {
        size_t idx = ((size_t)(b * 16 + hh) * 1024 + l) * 64 + d;
        q_hi[idx] = hv; q_lo[idx] = lv;
      } else {
        size_t idx = ((size_t)(b * 4 + (hh - 16)) * 1024 + l) * 64 + d;
        k_hi[idx] = hv; k_lo[idx] = lv;
      }
    }
  } else {
    const int v5 = blk - 2048;               // 0..511 = (d0:2, l0:32, bkvh:8)
    const int d0 = (v5 & 1) * 32;
    const int l0 = ((v5 >> 1) & 31) * 32;
    const int bkvh = v5 >> 6;
    const int b = bkvh >> 2;
    const int kvh = bkvh & 3;
    const size_t sbase = (size_t)b * 1024 * 1536 + 1280 + kvh * 64;
    const float* src  = qkv  + sbase;
    const float* src2 = qkv2 + sbase;
    __shared__ float t[32][33];
    const int tx = tid & 31;
    const int ty = tid >> 5;                 // 0..7
#pragma unroll
    for (int i = 0; i < 4; ++i) {
      const size_t o = (size_t)(l0 + ty + i * 8) * 1536 + d0 + tx;
      t[ty + i * 8][tx] = src[o] + src2[o];
    }
    __syncthreads();
#pragma unroll
    for (int i = 0; i < 4; ++i) {
      float v = t[tx][ty + i * 8];
      size_t o = (size_t)bkvh * 65536 + (size_t)(d0 + ty + i * 8) * 1024 + l0 + tx;
      unsigned short h = f2bf(v);
      vt_hi[o] = h;
      vt_lo[o] = f2bf(v - bf2f(h));
    }
  }
}

// ---------------- flash attention, split-bf16 MFMA, fp32 softmax ------------
// LDS = 48KB -> 3 blocks/CU fit (144 <= 160KB). (256,3) = 3 waves/EU ->
// ~170-reg budget; kernel needs ~120 (16 qf + 16 acc + 16 S + temps) -> no
// spill expected. Watch WRITE_SIZE if attn shows up in top-5.
__launch_bounds__(256, 3)
__global__ void attn_mfma(const unsigned short* __restrict__ q_hi, const unsigned short* __restrict__ q_lo,
                          const unsigned short* __restrict__ k_hi, const unsigned short* __restrict__ k_lo,
                          const unsigned short* __restrict__ vt_hi, const unsigned short* __restrict__ vt_lo,
                          unsigned short* __restrict__ ohi, unsigned short* __restrict__ olo) {
  const int blk = blockIdx.x;
  const int bh = blk & 31;               // (b,h)
  const int qt = 15 - (blk >> 5);        // long tiles dispatch first
  const int b = bh >> 4;
  const int h = bh & 15;
  const int kvbh = b * 4 + (h >> 2);
  const int q0 = qt * 64;
  const int tid = threadIdx.x;
  const int w = tid >> 6;
  const int lane = tid & 63;
  const int quad = lane >> 4;
  const int r16 = lane & 15;
  const int rl = lane >> 3;
  const int csl = lane & 7;
  const int cg = csl ^ rl;

  __shared__ unsigned short sK[2][64 * 64];
  __shared__ unsigned short sV[2][64 * 64];
  __shared__ unsigned short sP[2][64 * 64];

  short8 qfh[2], qfl[2];
  {
    const size_t qrow = ((size_t)bh * 1024 + q0 + w * 16 + r16) * 64 + quad * 8;
    qfh[0] = *(const short8*)(q_hi + qrow);
    qfh[1] = *(const short8*)(q_hi + qrow + 32);
    qfl[0] = *(const short8*)(q_lo + qrow);
    qfl[1] = *(const short8*)(q_lo + qrow + 32);
  }
  float4v O[4];
#pragma unroll
  for (int nt = 0; nt < 4; ++nt) O[nt] = float4v{0.f, 0.f, 0.f, 0.f};
  float m[4], l[4];
#pragma unroll
  for (int rg = 0; rg < 4; ++rg) { m[rg] = -__builtin_inff(); l[rg] = 0.f; }

  const unsigned short* khb = k_hi + (size_t)kvbh * 65536 + cg * 8;
  const unsigned short* klb = k_lo + (size_t)kvbh * 65536 + cg * 8;
  const unsigned short* vhb = vt_hi + (size_t)kvbh * 65536 + cg * 8;
  const unsigned short* vlb = vt_lo + (size_t)kvbh * 65536 + cg * 8;

  for (int c = 0; c <= qt; ++c) {
    __syncthreads();
#pragma unroll
    for (int j = 0; j < 2; ++j) {
      const int i = w * 2 + j;
      const int row = i * 8 + rl;
      gl_lds16(khb + (size_t)(c * 64 + row) * 64, (char*)sK[0] + i * 1024);
      gl_lds16(klb + (size_t)(c * 64 + row) * 64, (char*)sK[1] + i * 1024);
      gl_lds16(vhb + (size_t)row * 1024 + c * 64, (char*)sV[0] + i * 1024);
      gl_lds16(vlb + (size_t)row * 1024 + c * 64, (char*)sV[1] + i * 1024);
    }
    __syncthreads();

    float4v S[4];
#pragma unroll
    for (int nt = 0; nt < 4; ++nt) S[nt] = float4v{0.f, 0.f, 0.f, 0.f};
#pragma unroll
    for (int ks = 0; ks < 2; ++ks) {
#pragma unroll
      for (int nt = 0; nt < 4; ++nt) {
        const int r = nt * 16 + r16;
        const int o = (r * 8 + ((ks * 4 + quad) ^ (r & 7))) * 8;
        const short8 kh = *(const short8*)(sK[0] + o);
        const short8 kl = *(const short8*)(sK[1] + o);
        S[nt] = __builtin_amdgcn_mfma_f32_16x16x32_bf16(qfh[ks], kh, S[nt], 0, 0, 0);
        S[nt] = __builtin_amdgcn_mfma_f32_16x16x32_bf16(qfh[ks], kl, S[nt], 0, 0, 0);
        S[nt] = __builtin_amdgcn_mfma_f32_16x16x32_bf16(qfl[ks], kh, S[nt], 0, 0, 0);
      }
    }
    const float NEGINF = -__builtin_inff();
#pragma unroll
    for (int nt = 0; nt < 4; ++nt)
#pragma unroll
      for (int rg = 0; rg < 4; ++rg) S[nt][rg] *= 0.125f;
    if (c == qt) {
#pragma unroll
      for (int nt = 0; nt < 4; ++nt) {
        const int col = nt * 16 + r16;
#pragma unroll
        for (int rg = 0; rg < 4; ++rg) {
          const int row = w * 16 + quad * 4 + rg;
          if (col > row) S[nt][rg] = NEGINF;
        }
      }
    }
    float alpha[4], lsum[4];
#pragma unroll
    for (int rg = 0; rg < 4; ++rg) {
      float mx = fmaxf(fmaxf(S[0][rg], S[1][rg]), fmaxf(S[2][rg], S[3][rg]));
      mx = fmaxf(mx, __shfl_xor(mx, 1));
      mx = fmaxf(mx, __shfl_xor(mx, 2));
      mx = fmaxf(mx, __shfl_xor(mx, 4));
      mx = fmaxf(mx, __shfl_xor(mx, 8));
      const float mn = fmaxf(m[rg], mx);
      alpha[rg] = __expf(m[rg] - mn);
      m[rg] = mn;
      lsum[rg] = 0.f;
    }
#pragma unroll
    for (int nt = 0; nt < 4; ++nt)
#pragma unroll
      for (int rg = 0; rg < 4; ++rg) {
        const float e = __expf(S[nt][rg] - m[rg]);
        S[nt][rg] = e;
        lsum[rg] += e;
      }
#pragma unroll
    for (int rg = 0; rg < 4; ++rg) {
      float ls = lsum[rg];
      ls += __shfl_xor(ls, 1);
      ls += __shfl_xor(ls, 2);
      ls += __shfl_xor(ls, 4);
      ls += __shfl_xor(ls, 8);
      l[rg] = l[rg] * alpha[rg] + ls;
    }
#pragma unroll
    for (int nt = 0; nt < 4; ++nt) {
      const int key = nt * 16 + r16;
      const int chunk = key >> 3;
#pragma unroll
      for (int rg = 0; rg < 4; ++rg) {
        const int r = w * 16 + quad * 4 + rg;
        const int addr = r * 64 + ((chunk ^ (r & 7)) * 8) + (key & 7);
        const float e = S[nt][rg];
        const unsigned short hv = f2bf(e);
        sP[0][addr] = hv;
        sP[1][addr] = f2bf(e - bf2f(hv));
      }
    }
#pragma unroll
    for (int nt = 0; nt < 4; ++nt)
#pragma unroll
      for (int rg = 0; rg < 4; ++rg) O[nt][rg] *= alpha[rg];
#pragma unroll
    for (int ks = 0; ks < 2; ++ks) {
      const int rA = w * 16 + r16;
      const int oA = (rA * 8 + ((ks * 4 + quad) ^ (rA & 7))) * 8;
      const short8 ph = *(const short8*)(sP[0] + oA);
      const short8 pl = *(const short8*)(sP[1] + oA);
#pragma unroll
      for (int nt = 0; nt < 4; ++nt) {
        const int rv = nt * 16 + r16;
        const int ov = (rv * 8 + ((ks * 4 + quad) ^ (rv & 7))) * 8;
        const short8 vh = *(const short8*)(sV[0] + ov);
        const short8 vl = *(const short8*)(sV[1] + ov);
        O[nt] = __builtin_amdgcn_mfma_f32_16x16x32_bf16(ph, vh, O[nt], 0, 0, 0);
        O[nt] = __builtin_amdgcn_mfma_f32_16x16x32_bf16(ph, vl, O[nt], 0, 0, 0);
        O[nt] = __builtin_amdgcn_mfma_f32_16x16x32_bf16(pl, vh, O[nt], 0, 0, 0);
      }
    }
  }
#pragma unroll
  for (int nt = 0; nt < 4; ++nt) {
    const int col = h * 64 + nt * 16 + r16;
#pragma unroll
    for (int rg = 0; rg < 4; ++rg) {
      const int row = q0 + w * 16 + quad * 4 + rg;
      const float ovv = O[nt][rg] / l[rg];
      const size_t idx = ((size_t)b * 1024 + row) * DMODEL + col;
      const unsigned short hv = f2bf(ovv);
      ohi[idx] = hv;
      olo[idx] = f2bf(ovv - bf2f(hv));
    }
  }
}

__global__ void finalize_kernel(const int* __restrict__ counts, int* __restrict__ off_pad,
                                int* __restrict__ tile_map, float* __restrict__ lb_out) {
  if (threadIdx.x == 0 && blockIdx.x == 0) {
    int tile = 0, rowoff = 0;
    for (int e = 0; e < NEXP; ++e) {
      off_pad[e] = rowoff;
      const int c = counts[e];
      const int nt = (c + 127) >> 7;
      for (int i = 0; i < nt; ++i) tile_map[tile++] = e;
      rowoff += nt * 128;
    }
    for (; tile < MAXTILES; ++tile) tile_map[tile] = -1;
    float sacc = 0.f;
    for (int e = 0; e < NEXP; ++e) {
      const float cn = (float)counts[e] * (1.0f / 4096.0f);
      const float d = cn - 0.125f;
      sacc += d * d;
    }
    lb_out[0] = sacc * (1.0f / 8.0f);
  }
}

__global__ void scatter_kernel(const int* __restrict__ tok_e, const int* __restrict__ off_pad,
                               int* __restrict__ fill, int* __restrict__ tok_pos,
                               const unsigned short* __restrict__ h2bf, unsigned short* __restrict__ Xg) {
  const int slot = blockIdx.x;
  const int t = slot >> 1;
  __shared__ int sp;
  if (threadIdx.x == 0) {
    const int e = tok_e[slot];
    const int r = atomicAdd(fill + e, 1);
    const int ppos = off_pad[e] + r;
    tok_pos[slot] = ppos;
    sp = ppos;
  }
  __syncthreads();
  const int pos = sp;
  *(uint2*)(Xg + (size_t)pos * DMODEL + threadIdx.x * 4) =
      *(const uint2*)(h2bf + (size_t)t * DMODEL + threadIdx.x * 4);
}

// ----- combine: out = x1 + g0*sum_z eout_z[p0] + g1*sum_z eout_z[p1] --------
__global__ void combine_kernel(const float* __restrict__ x1, const float* __restrict__ eout,
                               const int* __restrict__ tok_pos, const float* __restrict__ tok_g,
                               float* __restrict__ out) {
  const int t = blockIdx.x;
  const int tid = threadIdx.x;
  const int p0 = tok_pos[t * 2], p1 = tok_pos[t * 2 + 1];
  const float g0 = tok_g[t * 2], g1 = tok_g[t * 2 + 1];
  const size_t o = (size_t)t * DMODEL + tid * 4;
  const float4 a = *(const float4*)(x1 + o);
  float s0x = 0.f, s0y = 0.f, s0z = 0.f, s0w = 0.f;
  float s1x = 0.f, s1y = 0.f, s1z = 0.f, s1w = 0.f;
#pragma unroll
  for (int z = 0; z < 4; ++z) {
    const size_t zb = (size_t)z * MAXROWS * DMODEL;
    const float4 e0 = *(const float4*)(eout + zb + (size_t)p0 * DMODEL + tid * 4);
    const float4 e1 = *(const float4*)(eout + zb + (size_t)p1 * DMODEL + tid * 4);
    s0x += e0.x; s0y += e0.y; s0z += e0.z; s0w += e0.w;
    s1x += e1.x; s1y += e1.y; s1z += e1.z; s1w += e1.w;
  }
  float4 r;
  r.x = a.x + g0 * s0x + g1 * s1x;
  r.y = a.y + g0 * s0y + g1 * s1y;
  r.z = a.z + g0 * s0z + g1 * s1z;
  r.w = a.w + g0 * s0w + g1 * s1w;
  *(float4*)(out + o) = r;
}

extern "C" void kernel_launch(void* const* d_in, const int* in_sizes, int n_in,
                              void* d_out, int out_size, void* d_ws, size_t ws_size,
                              hipStream_t stream) {
  (void)in_sizes; (void)n_in; (void)out_size; (void)ws_size;
  const float* x    = (const float*)d_in[0];
  const float* wq   = (const float*)d_in[1];
  const float* wk   = (const float*)d_in[2];
  const float* wv   = (const float*)d_in[3];
  const float* wo   = (const float*)d_in[4];
  const float* wg   = (const float*)d_in[5];
  const float* w1   = (const float*)d_in[6];
  const float* w2   = (const float*)d_in[7];
  const float* ln1g = (const float*)d_in[8];
  const float* ln1b = (const float*)d_in[9];
  const float* ln2g = (const float*)d_in[10];
  const float* ln2b = (const float*)d_in[11];
  float* out = (float*)d_out;

  char* p = (char*)d_ws;
  auto take = [&](size_t n) { void* r = (void*)p; p += (n + 255) & ~(size_t)255; return r; };
  unsigned short* h1_hi   = (unsigned short*)take((size_t)NTOK * DMODEL * 2);
  unsigned short* h1_lo   = (unsigned short*)take((size_t)NTOK * DMODEL * 2);
  unsigned short* wqkv_hi = (unsigned short*)take((size_t)1536 * 1024 * 2);
  unsigned short* wqkv_lo = (unsigned short*)take((size_t)1536 * 1024 * 2);
  unsigned short* woT_hi  = (unsigned short*)take((size_t)1024 * 1024 * 2);
  unsigned short* woT_lo  = (unsigned short*)take((size_t)1024 * 1024 * 2);
  unsigned short* w1t     = (unsigned short*)take((size_t)NEXP * DFF * DMODEL * 2);
  unsigned short* w2t     = (unsigned short*)take((size_t)NEXP * DMODEL * DFF * 2);
  float* qkv   = (float*)take((size_t)2 * NTOK * 1536 * 4);          // 2 split-K slabs
  unsigned short* q_hi  = (unsigned short*)take((size_t)2 * 16 * 1024 * 64 * 2);
  unsigned short* q_lo  = (unsigned short*)take((size_t)2 * 16 * 1024 * 64 * 2);
  unsigned short* k_hi  = (unsigned short*)take((size_t)2 * 4 * 1024 * 64 * 2);
  unsigned short* k_lo  = (unsigned short*)take((size_t)2 * 4 * 1024 * 64 * 2);
  unsigned short* vt_hi = (unsigned short*)take((size_t)2 * 4 * 1024 * 64 * 2);
  unsigned short* vt_lo = (unsigned short*)take((size_t)2 * 4 * 1024 * 64 * 2);
  unsigned short* attn_hi = (unsigned short*)take((size_t)NTOK * DMODEL * 2);
  unsigned short* attn_lo = (unsigned short*)take((size_t)NTOK * DMODEL * 2);
  float* x1p   = (float*)take((size_t)4 * NTOK * DMODEL * 4);        // 4 split-K slabs
  float* x1    = (float*)take((size_t)NTOK * DMODEL * 4);
  unsigned short* h2bf = (unsigned short*)take((size_t)NTOK * DMODEL * 2);
  unsigned short* Xg   = (unsigned short*)take((size_t)MAXROWS * DMODEL * 2);
  unsigned short* hid  = (unsigned short*)take((size_t)MAXROWS * DFF * 2);
  float* eout  = (float*)take((size_t)4 * MAXROWS * DMODEL * 4);     // 4 split-K slabs
  int*   tok_e   = (int*)take(4096 * 4);
  float* tok_g   = (float*)take(4096 * 4);
  int*   tok_pos = (int*)take(4096 * 4);
  int*   counts  = (int*)take(64);
  int*   fill    = (int*)take(64);
  int*   off_pad = (int*)take(64);
  int*   tile_map = (int*)take(256);

  // fused wq/wk/wv/wo transpose + counts/fill init
  transpose_qkvo<<<dim3(16, 16, 4), 256, 0, stream>>>(wq, wk, wv, wo, wqkv_hi, wqkv_lo,
                                                      woT_hi, woT_lo, counts, fill);
  ln_kernel<<<NTOK, 256, 0, stream>>>(x, ln1g, ln1b, h1_hi, h1_lo);
  // fused w1+w2 transpose (was 2 launches)
  transpose_w12<<<16384, 256, 0, stream>>>(w1, w2, w1t, w2t);
  // qkv = h1 @ [wq|wk|wv], split-K x2 (384 blocks), XCD-swizzled
  gemm_split<<<dim3(12, 16, 2), 256, 0, stream>>>(h1_hi, h1_lo, wqkv_hi, wqkv_lo, qkv, 1536, 1024, 512, (long)NTOK * 1536);
  // fused RoPE + V-transpose (was 2 launches)
  rope_vt<<<2560, 256, 0, stream>>>(qkv, qkv + (size_t)NTOK * 1536, q_hi, q_lo, k_hi, k_lo, vt_hi, vt_lo);
  attn_mfma<<<512, 256, 0, stream>>>(q_hi, q_lo, k_hi, k_lo, vt_hi, vt_lo, attn_hi, attn_lo);
  // wo projection: split-K x4 (512 blocks)
  gemm_split<<<dim3(8, 16, 4), 256, 0, stream>>>(attn_hi, attn_lo, woT_hi, woT_lo, x1p, 1024, 1024, 256, (long)NTOK * DMODEL);
  // fused: x1 = x + sum(slabs); ln2; h2bf; router
  fused_ln2_router<<<NTOK, 256, 0, stream>>>(x, x1p, ln2g, ln2b, x1, h2bf, wg, tok_e, tok_g, counts);
  finalize_kernel<<<1, 64, 0, stream>>>(counts, off_pad, tile_map, out + (size_t)NTOK * DMODEL);
  scatter_kernel<<<4096, 256, 0, stream>>>(tok_e, off_pad, fill, tok_pos, h2bf, Xg);
  // w1 GEMM: tanh-gelu epilogue, XCD-swizzled
  gemm_bt<3,1><<<dim3(32, MAXTILES), 256, 0, stream>>>(Xg, w1t, nullptr, hid, DFF, DMODEL, DMODEL, 0, tile_map, (long)DFF * DMODEL);
  // expert down-proj: split-K x4 (1280 blocks), XCD-swizzled
  gemm_bt<0,1><<<dim3(8, MAXTILES, 4), 256, 0, stream>>>(hid, w2t, eout, nullptr, DMODEL, DFF, 1024, (long)MAXROWS * DMODEL, tile_map, (long)DMODEL * DFF);
  combine_kernel<<<NTOK, 256, 0, stream>>>(x1, eout, tok_pos, tok_g, out);
}

// Round 8
// 669.634 us; speedup vs baseline: 1.5376x; 1.0038x over previous
//
#include <hip/hip_runtime.h>
#include <hip/hip_bf16.h>

#define NTOK   2048      // B*L
#define DMODEL 1024
#define NEXP   8
#define DFF    4096
#define MAXROWS 5120
#define MAXTILES 40

typedef __attribute__((ext_vector_type(8))) short short8;
typedef __attribute__((ext_vector_type(4))) float float4v;

__device__ __forceinline__ unsigned short f2bf(float f) {
  union { float f; unsigned u; } v; v.f = f;
  unsigned r = v.u + 0x7fffu + ((v.u >> 16) & 1u);
  return (unsigned short)(r >> 16);
}
__device__ __forceinline__ float bf2f(unsigned short h) {
  union { unsigned u; float f; } v; v.u = ((unsigned)h) << 16; return v.f;
}
__device__ __forceinline__ void gl_lds16(const void* g, void* l) {
  __builtin_amdgcn_global_load_lds((const __attribute__((address_space(1))) void*)g,
                                   (__attribute__((address_space(3))) void*)l, 16, 0, 0);
}

// bijective XCD swizzle: consecutive HW bids round-robin over 8 XCDs; give each
// XCD a contiguous chunk of logical tile space (requires nwg % 8 == 0).
__device__ __forceinline__ int xcd_swz(int bid, int nwg) {
  if (nwg & 7) return bid;
  const int chunk = nwg >> 3;
  return (bid & 7) * chunk + (bid >> 3);
}

// ---------------- GEMM: C[M,N] = A[M,K](bf16) x B[N,K]^T(bf16), fp32 acc ---
// EPI: 0 C=acc ; 3 Cbf=bf16(gelu(acc))
// split-K: z covers k in [z*kslice, (z+1)*kslice), partial C slab at z*zstride
// launch_bounds(256,4): 4 waves/EU -> 128-reg budget; kernel needs ~60 VGPR +
// 64 AGPR acc. (256,5) caps at ~102 regs and SPILLS the accumulator to
// scratch: R3 measured WRITE_SIZE 38->303 MB, 78->253us. Do not raise.
template<int EPI, int EMAP>
__launch_bounds__(256, 4)
__global__ void gemm_bt(const unsigned short* __restrict__ A,
                        const unsigned short* __restrict__ B0,
                        float* __restrict__ C,
                        unsigned short* __restrict__ Cbf,
                        const int N, const int K,
                        const int kslice, const long zstride,
                        const int* __restrict__ tmap, const long estride) {
  // ---- XCD-swizzled logical tile id ----
  const int gx = gridDim.x, gy = gridDim.y;
  const int nwg = gx * gy * gridDim.z;
  const int lid = xcd_swz(blockIdx.x + gx * (blockIdx.y + gy * blockIdx.z), nwg);
  const int bx = lid % gx;
  const int t1 = lid / gx;
  const int mtile = t1 % gy;
  const int bz = t1 / gy;

  const unsigned short* B = B0;
  if (EMAP) {
    int e = tmap[mtile];
    if (e < 0) return;
    B += (size_t)e * (size_t)estride;
  }
  const int n0 = bx * 128;
  const int m0 = mtile * 128;
  if (EPI == 0) C += (size_t)bz * (size_t)zstride;
  __shared__ unsigned short sA[128 * 64];
  __shared__ unsigned short sB[128 * 64];
  const int tid  = threadIdx.x;
  const int w    = tid >> 6;
  const int lane = tid & 63;
  const int quad = lane >> 4;
  const int r16  = lane & 15;
  const int wr   = w >> 1;
  const int wc   = w & 1;
  const int rl   = lane >> 3;
  const int csl  = lane & 7;
  const int cg   = csl ^ rl;
  float4v acc[4][4];
#pragma unroll
  for (int i = 0; i < 4; ++i)
#pragma unroll
    for (int j = 0; j < 4; ++j) acc[i][j] = float4v{0.f, 0.f, 0.f, 0.f};

  const unsigned short* Ab = A + (size_t)m0 * K + cg * 8;
  const unsigned short* Bb = B + (size_t)n0 * K + cg * 8;

  const int kbeg = bz * kslice;
  const int kend = kbeg + kslice;
  for (int k0 = kbeg; k0 < kend; k0 += 64) {
    __syncthreads();
#pragma unroll
    for (int i = 0; i < 4; ++i) {
      const int j = w * 4 + i;
      gl_lds16(Ab + (size_t)(j * 8 + rl) * K + k0, (char*)sA + j * 1024);
      gl_lds16(Bb + (size_t)(j * 8 + rl) * K + k0, (char*)sB + j * 1024);
    }
    __syncthreads();
#pragma unroll
    for (int kc = 0; kc < 8; kc += 4) {
      short8 af[4], bq[4];
#pragma unroll
      for (int mt = 0; mt < 4; ++mt) {
        int r = wr * 64 + mt * 16 + r16;
        af[mt] = *(const short8*)(sA + ((r * 8 + ((kc + quad) ^ (r & 7))) * 8));
      }
#pragma unroll
      for (int nt = 0; nt < 4; ++nt) {
        int r = wc * 64 + nt * 16 + r16;
        bq[nt] = *(const short8*)(sB + ((r * 8 + ((kc + quad) ^ (r & 7))) * 8));
      }
#pragma unroll
      for (int mt = 0; mt < 4; ++mt)
#pragma unroll
        for (int nt = 0; nt < 4; ++nt)
          acc[mt][nt] = __builtin_amdgcn_mfma_f32_16x16x32_bf16(af[mt], bq[nt], acc[mt][nt], 0, 0, 0);
    }
  }
#pragma unroll
  for (int mt = 0; mt < 4; ++mt) {
#pragma unroll
    for (int nt = 0; nt < 4; ++nt) {
#pragma unroll
      for (int rg = 0; rg < 4; ++rg) {
        const int m = m0 + wr * 64 + mt * 16 + quad * 4 + rg;
        const int n = n0 + wc * 64 + nt * 16 + r16;
        const size_t idx = (size_t)m * N + n;
        const float v = acc[mt][nt][rg];
        if (EPI == 0) C[idx] = v;
        else {
          // tanh-form gelu: x*sigmoid(1.5958(x+0.044715x^3)); |err| ~1e-4,
          // far below hid's bf16 quantization. Replaces ~25-op erff.
          const float u = v + 0.044715f * v * v * v;
          const float ge = v / (1.0f + __expf(-1.5957691216f * u));
          Cbf[idx] = f2bf(ge);
        }
      }
    }
  }
}

// ------- split-bf16 GEMM: C = (Ah+Al)x(Bh+Bl)^T, 3 terms, split-K slabs -----
// 64KB LDS -> hard cap of 2 blocks/CU; do not raise launch_bounds.
__launch_bounds__(256, 2)
__global__ void gemm_split(const unsigned short* __restrict__ Ah,
                           const unsigned short* __restrict__ Al,
                           const unsigned short* __restrict__ Bh,
                           const unsigned short* __restrict__ Bl,
                           float* __restrict__ C,
                           const int N, const int K,
                           const int kslice, const long zstride) {
  const int gx = gridDim.x, gy = gridDim.y;
  const int nwg = gx * gy * gridDim.z;
  const int lid = xcd_swz(blockIdx.x + gx * (blockIdx.y + gy * blockIdx.z), nwg);
  const int bx = lid % gx;
  const int t1 = lid / gx;
  const int by = t1 % gy;
  const int bz = t1 / gy;

  const int n0 = bx * 128;
  const int m0 = by * 128;
  C += (size_t)bz * (size_t)zstride;
  __shared__ unsigned short sAh[128 * 64];
  __shared__ unsigned short sAl[128 * 64];
  __shared__ unsigned short sBh[128 * 64];
  __shared__ unsigned short sBl[128 * 64];
  const int tid  = threadIdx.x;
  const int w    = tid >> 6;
  const int lane = tid & 63;
  const int quad = lane >> 4;
  const int r16  = lane & 15;
  const int wr   = w >> 1;
  const int wc   = w & 1;
  const int rl   = lane >> 3;
  const int csl  = lane & 7;
  const int cg   = csl ^ rl;
  float4v acc[4][4];
#pragma unroll
  for (int i = 0; i < 4; ++i)
#pragma unroll
    for (int j = 0; j < 4; ++j) acc[i][j] = float4v{0.f, 0.f, 0.f, 0.f};

  const size_t aoff = (size_t)m0 * K + cg * 8;
  const size_t boff = (size_t)n0 * K + cg * 8;

  const int kbeg = bz * kslice;
  const int kend = kbeg + kslice;
  for (int k0 = kbeg; k0 < kend; k0 += 64) {
    __syncthreads();
#pragma unroll
    for (int i = 0; i < 4; ++i) {
      const int j = w * 4 + i;
      const size_t ro = (size_t)(j * 8 + rl) * K + k0;
      gl_lds16(Ah + aoff + ro, (char*)sAh + j * 1024);
      gl_lds16(Al + aoff + ro, (char*)sAl + j * 1024);
      gl_lds16(Bh + boff + ro, (char*)sBh + j * 1024);
      gl_lds16(Bl + boff + ro, (char*)sBl + j * 1024);
    }
    __syncthreads();
#pragma unroll
    for (int kc = 0; kc < 8; kc += 4) {
      short8 afh[4], afl[4], bqh[4], bql[4];
#pragma unroll
      for (int mt = 0; mt < 4; ++mt) {
        int r = wr * 64 + mt * 16 + r16;
        int o = (r * 8 + ((kc + quad) ^ (r & 7))) * 8;
        afh[mt] = *(const short8*)(sAh + o);
        afl[mt] = *(const short8*)(sAl + o);
      }
#pragma unroll
      for (int nt = 0; nt < 4; ++nt) {
        int r = wc * 64 + nt * 16 + r16;
        int o = (r * 8 + ((kc + quad) ^ (r & 7))) * 8;
        bqh[nt] = *(const short8*)(sBh + o);
        bql[nt] = *(const short8*)(sBl + o);
      }
#pragma unroll
      for (int mt = 0; mt < 4; ++mt)
#pragma unroll
        for (int nt = 0; nt < 4; ++nt) {
          acc[mt][nt] = __builtin_amdgcn_mfma_f32_16x16x32_bf16(afh[mt], bqh[nt], acc[mt][nt], 0, 0, 0);
          acc[mt][nt] = __builtin_amdgcn_mfma_f32_16x16x32_bf16(afh[mt], bql[nt], acc[mt][nt], 0, 0, 0);
          acc[mt][nt] = __builtin_amdgcn_mfma_f32_16x16x32_bf16(afl[mt], bqh[nt], acc[mt][nt], 0, 0, 0);
        }
    }
  }
#pragma unroll
  for (int mt = 0; mt < 4; ++mt) {
#pragma unroll
    for (int nt = 0; nt < 4; ++nt) {
#pragma unroll
      for (int rg = 0; rg < 4; ++rg) {
        const int m = m0 + wr * 64 + mt * 16 + quad * 4 + rg;
        const int n = n0 + wc * 64 + nt * 16 + r16;
        C[(size_t)m * N + n] = acc[mt][nt][rg];
      }
    }
  }
}

// --- fused w1+w2 transpose: fp32 [K,N] -> bf16 [N,K], 1D grid, one launch ---
// blocks 0..8191: w1 (8 experts x 64x16 tiles of 64x64, K=1024,N=4096)
// blocks 8192..16383: w2 (8 experts x 16x64 tiles, K=4096,N=1024)
// XCD-swizzled: adjacent logical blocks (n0-fastest) read the SAME 64 input
// rows; swizzle keeps them on one XCD's L2. R7 measured 110us @ 2.4TB/s
// (round-robin scattered the row-sharing across 8 non-coherent L2s).
__global__ void transpose_w12(const float* __restrict__ w1, const float* __restrict__ w2,
                              unsigned short* __restrict__ w1t, unsigned short* __restrict__ w2t) {
  const int t = xcd_swz(blockIdx.x, 16384);
  const float* in;
  unsigned short* oh;
  int K, N, n0, k0;
  if (t < 8192) {
    const int bz = t >> 10, rem = t & 1023;
    K = 1024; N = 4096;
    in = w1 + (size_t)bz * 1024 * 4096;
    oh = w1t + (size_t)bz * 4096 * 1024;
    n0 = (rem & 63) * 64; k0 = (rem >> 6) * 64;
  } else {
    const int u = t - 8192;
    const int bz = u >> 10, rem = u & 1023;
    K = 4096; N = 1024;
    in = w2 + (size_t)bz * 4096 * 1024;
    oh = w2t + (size_t)bz * 1024 * 4096;
    n0 = (rem & 15) * 64; k0 = (rem >> 4) * 64;
  }
  __shared__ float tl[64][65];
  const int tid = threadIdx.x;
  const int rr = tid >> 4;
  const int c4 = (tid & 15) * 4;
#pragma unroll
  for (int p = 0; p < 4; ++p) {
    const int row = p * 16 + rr;
    const float4 v = *(const float4*)(in + (size_t)(k0 + row) * N + n0 + c4);
    tl[row][c4] = v.x; tl[row][c4 + 1] = v.y; tl[row][c4 + 2] = v.z; tl[row][c4 + 3] = v.w;
  }
  __syncthreads();
#pragma unroll
  for (int p = 0; p < 4; ++p) {
    const int n = p * 16 + rr;
    ushort4 h;
    h.x = f2bf(tl[c4][n]); h.y = f2bf(tl[c4 + 1][n]);
    h.z = f2bf(tl[c4 + 2][n]); h.w = f2bf(tl[c4 + 3][n]);
    *(ushort4*)(oh + (size_t)(n0 + n) * K + k0 + c4) = h;
  }
}

// --- fused wq/wk/wv/wo transpose (hi+lo) + counts/fill init, one launch -----
__global__ void transpose_qkvo(const float* __restrict__ wq, const float* __restrict__ wk,
                               const float* __restrict__ wv, const float* __restrict__ wo,
                               unsigned short* __restrict__ wqkv_hi, unsigned short* __restrict__ wqkv_lo,
                               unsigned short* __restrict__ woT_hi, unsigned short* __restrict__ woT_lo,
                               int* __restrict__ counts, int* __restrict__ fill) {
  if (blockIdx.x == 0 && blockIdx.y == 0 && blockIdx.z == 0 && threadIdx.x < 16) {
    if (threadIdx.x < 8) counts[threadIdx.x] = 0;
    else fill[threadIdx.x - 8] = 0;
  }
  const int z = blockIdx.z;
  const float* in;
  unsigned short *oh, *ol;
  int N, xmax;
  if (z == 0)      { in = wq; oh = wqkv_hi;                         ol = wqkv_lo;                         N = 1024; xmax = 16; }
  else if (z == 1) { in = wk; oh = wqkv_hi + (size_t)1024 * 1024;   ol = wqkv_lo + (size_t)1024 * 1024;   N = 256;  xmax = 4; }
  else if (z == 2) { in = wv; oh = wqkv_hi + (size_t)1280 * 1024;   ol = wqkv_lo + (size_t)1280 * 1024;   N = 256;  xmax = 4; }
  else             { in = wo; oh = woT_hi;                          ol = woT_lo;                          N = 1024; xmax = 16; }
  if (blockIdx.x >= xmax) return;
  const int K = 1024;
  __shared__ float t[64][65];
  const int n0 = blockIdx.x * 64;
  const int k0 = blockIdx.y * 64;
  const int tid = threadIdx.x;
  const int rr = tid >> 4;
  const int c4 = (tid & 15) * 4;
#pragma unroll
  for (int p = 0; p < 4; ++p) {
    const int row = p * 16 + rr;
    const float4 v = *(const float4*)(in + (size_t)(k0 + row) * N + n0 + c4);
    t[row][c4] = v.x; t[row][c4 + 1] = v.y; t[row][c4 + 2] = v.z; t[row][c4 + 3] = v.w;
  }
  __syncthreads();
#pragma unroll
  for (int p = 0; p < 4; ++p) {
    const int n = p * 16 + rr;
    float vs[4];
#pragma unroll
    for (int i = 0; i < 4; ++i) vs[i] = t[c4 + i][n];
    ushort4 h;
    h.x = f2bf(vs[0]); h.y = f2bf(vs[1]); h.z = f2bf(vs[2]); h.w = f2bf(vs[3]);
    const size_t o = (size_t)(n0 + n) * K + k0 + c4;
    *(ushort4*)(oh + o) = h;
    ushort4 lo4;
    lo4.x = f2bf(vs[0] - bf2f(h.x));
    lo4.y = f2bf(vs[1] - bf2f(h.y));
    lo4.z = f2bf(vs[2] - bf2f(h.z));
    lo4.w = f2bf(vs[3] - bf2f(h.w));
    *(ushort4*)(ol + o) = lo4;
  }
}

// ---------------- LayerNorm over D=1024 (ln1: hi+lo) ------------------------
__global__ void ln_kernel(const float* __restrict__ x, const float* __restrict__ g,
                          const float* __restrict__ b, unsigned short* __restrict__ hi,
                          unsigned short* __restrict__ lo) {
  const int row = blockIdx.x;
  const int tid = threadIdx.x;
  const int w = tid >> 6, lane = tid & 63;
  const float4 v = *(const float4*)(x + (size_t)row * DMODEL + tid * 4);
  float s = v.x + v.y + v.z + v.w;
  float q = v.x * v.x + v.y * v.y + v.z * v.z + v.w * v.w;
#pragma unroll
  for (int o = 32; o; o >>= 1) { s += __shfl_xor(s, o); q += __shfl_xor(q, o); }
  __shared__ float red[8];
  if (lane == 0) { red[w] = s; red[4 + w] = q; }
  __syncthreads();
  s = red[0] + red[1] + red[2] + red[3];
  q = red[4] + red[5] + red[6] + red[7];
  const float mean = s * (1.0f / DMODEL);
  const float var = q * (1.0f / DMODEL) - mean * mean;
  const float rs = rsqrtf(var + 1e-5f);
  const float4 gg = *(const float4*)(g + tid * 4);
  const float4 bb = *(const float4*)(b + tid * 4);
  float y[4];
  y[0] = (v.x - mean) * rs * gg.x + bb.x;
  y[1] = (v.y - mean) * rs * gg.y + bb.y;
  y[2] = (v.z - mean) * rs * gg.z + bb.z;
  y[3] = (v.w - mean) * rs * gg.w + bb.w;
  const size_t base = (size_t)row * DMODEL + tid * 4;
  ushort4 h4, l4;
  h4.x = f2bf(y[0]); h4.y = f2bf(y[1]); h4.z = f2bf(y[2]); h4.w = f2bf(y[3]);
  l4.x = f2bf(y[0] - bf2f(h4.x));
  l4.y = f2bf(y[1] - bf2f(h4.y));
  l4.z = f2bf(y[2] - bf2f(h4.z));
  l4.w = f2bf(y[3] - bf2f(h4.w));
  *(ushort4*)(hi + base) = h4;
  *(ushort4*)(lo + base) = l4;
}

#define RED6SUM(X) { X += __shfl_xor(X,32); X += __shfl_xor(X,16); X += __shfl_xor(X,8); X += __shfl_xor(X,4); X += __shfl_xor(X,2); X += __shfl_xor(X,1); }

// --- fused: x1 = x + sum(4 wo slabs); ln2; h2bf; router top-2 + counts ------
__global__ void fused_ln2_router(const float* __restrict__ x, const float* __restrict__ x1p,
                                 const float* __restrict__ g, const float* __restrict__ b,
                                 float* __restrict__ x1, unsigned short* __restrict__ h2bf,
                                 const float* __restrict__ wg,
                                 int* __restrict__ tok_e, float* __restrict__ tok_g,
                                 int* __restrict__ counts) {
  const int row = blockIdx.x;
  const int tid = threadIdx.x;
  const int w = tid >> 6, lane = tid & 63;
  const size_t base = (size_t)row * DMODEL + tid * 4;
  float4 v = *(const float4*)(x + base);
#pragma unroll
  for (int z = 0; z < 4; ++z) {
    const float4 p = *(const float4*)(x1p + (size_t)z * NTOK * DMODEL + base);
    v.x += p.x; v.y += p.y; v.z += p.z; v.w += p.w;
  }
  *(float4*)(x1 + base) = v;
  float s = v.x + v.y + v.z + v.w;
  float q = v.x * v.x + v.y * v.y + v.z * v.z + v.w * v.w;
#pragma unroll
  for (int o = 32; o; o >>= 1) { s += __shfl_xor(s, o); q += __shfl_xor(q, o); }
  __shared__ float red[8];
  if (lane == 0) { red[w] = s; red[4 + w] = q; }
  __syncthreads();
  s = red[0] + red[1] + red[2] + red[3];
  q = red[4] + red[5] + red[6] + red[7];
  const float mean = s * (1.0f / DMODEL);
  const float var = q * (1.0f / DMODEL) - mean * mean;
  const float rs = rsqrtf(var + 1e-5f);
  const float4 gg = *(const float4*)(g + tid * 4);
  const float4 bb = *(const float4*)(b + tid * 4);
  float y[4];
  y[0] = (v.x - mean) * rs * gg.x + bb.x;
  y[1] = (v.y - mean) * rs * gg.y + bb.y;
  y[2] = (v.z - mean) * rs * gg.z + bb.z;
  y[3] = (v.w - mean) * rs * gg.w + bb.w;
  ushort4 h4;
  h4.x = f2bf(y[0]); h4.y = f2bf(y[1]); h4.z = f2bf(y[2]); h4.w = f2bf(y[3]);
  *(ushort4*)(h2bf + base) = h4;
  float acc[8] = {0, 0, 0, 0, 0, 0, 0, 0};
#pragma unroll
  for (int i = 0; i < 4; ++i) {
    const int d = tid * 4 + i;
    const float4 w0 = *(const float4*)(wg + d * 8);
    const float4 w1v = *(const float4*)(wg + d * 8 + 4);
    acc[0] += y[i] * w0.x;  acc[1] += y[i] * w0.y;  acc[2] += y[i] * w0.z;  acc[3] += y[i] * w0.w;
    acc[4] += y[i] * w1v.x; acc[5] += y[i] * w1v.y; acc[6] += y[i] * w1v.z; acc[7] += y[i] * w1v.w;
  }
#pragma unroll
  for (int e = 0; e < 8; ++e) { RED6SUM(acc[e]); }
  __shared__ float racc[4][8];
  if (lane == 0) {
#pragma unroll
    for (int e = 0; e < 8; ++e) racc[w][e] = acc[e];
  }
  __syncthreads();
  if (tid == 0) {
    float tot[8];
#pragma unroll
    for (int e = 0; e < 8; ++e) tot[e] = racc[0][e] + racc[1][e] + racc[2][e] + racc[3][e];
    int i0 = 0; float v0 = tot[0];
#pragma unroll
    for (int e = 1; e < 8; ++e) if (tot[e] > v0) { v0 = tot[e]; i0 = e; }
    int i1 = -1; float v1 = -__builtin_inff();
#pragma unroll
    for (int e = 0; e < 8; ++e) if (e != i0 && tot[e] > v1) { v1 = tot[e]; i1 = e; }
    const float ex = __expf(v1 - v0);
    const float den = 1.0f + ex;
    tok_e[row * 2] = i0; tok_e[row * 2 + 1] = i1;
    tok_g[row * 2] = 1.0f / den; tok_g[row * 2 + 1] = ex / den;
    atomicAdd(counts + i0, 1);
    atomicAdd(counts + i1, 1);
  }
}

// --- fused RoPE + V-transpose, one launch (both consume the qkv slabs) ------
// blocks 0..2047: rope for token blk; blocks 2048..2559: vt tile.
__global__ void rope_vt(const float* __restrict__ qkv, const float* __restrict__ qkv2,
                        unsigned short* __restrict__ q_hi, unsigned short* __restrict__ q_lo,
                        unsigned short* __restrict__ k_hi, unsigned short* __restrict__ k_lo,
                        unsigned short* __restrict__ vt_hi, unsigned short* __restrict__ vt_lo) {
  const int blk = blockIdx.x;
  const int tid = threadIdx.x;
  if (blk < 2048) {
    const int rowtok = blk;
    const int b = rowtok >> 10;
    const int l = rowtok & 1023;
    __shared__ float cb[32], sb[32];
    if (tid < 32) {
      float inv = powf(10000.0f, -(float)tid * (1.0f / 32.0f));
      float ang = (float)l * inv;
      cb[tid] = cosf(ang);
      sb[tid] = sinf(ang);
    }
    __syncthreads();
    const float* src  = qkv  + (size_t)rowtok * 1536;
    const float* src2 = qkv2 + (size_t)rowtok * 1536;
#pragma unroll
    for (int it = 0; it < 5; ++it) {
      const int e = tid + it * 256;
      const int hh = e >> 6;
      const int d = e & 63;
      const int dm = d & 31;
      float val = src[e] + src2[e];
      float partner = (d < 32) ? -(src[e + 32] + src2[e + 32]) : (src[e - 32] + src2[e - 32]);
      float ov = val * cb[dm] + partner * sb[dm];
      unsigned short hv = f2bf(ov);
      unsigned short lv = f2bf(ov - bf2f(hv));
      if (hh < 16) {
        size_t idx = ((size_t)(b * 16 + hh) * 1024 + l) * 64 + d;
        q_hi[idx] = hv; q_lo[idx] = lv;
      } else {
        size_t idx = ((size_t)(b * 4 + (hh - 16)) * 1024 + l) * 64 + d;
        k_hi[idx] = hv; k_lo[idx] = lv;
      }
    }
  } else {
    const int v5 = blk - 2048;               // 0..511 = (d0:2, l0:32, bkvh:8)
    const int d0 = (v5 & 1) * 32;
    const int l0 = ((v5 >> 1) & 31) * 32;
    const int bkvh = v5 >> 6;
    const int b = bkvh >> 2;
    const int kvh = bkvh & 3;
    const size_t sbase = (size_t)b * 1024 * 1536 + 1280 + kvh * 64;
    const float* src  = qkv  + sbase;
    const float* src2 = qkv2 + sbase;
    __shared__ float t[32][33];
    const int tx = tid & 31;
    const int ty = tid >> 5;                 // 0..7
#pragma unroll
    for (int i = 0; i < 4; ++i) {
      const size_t o = (size_t)(l0 + ty + i * 8) * 1536 + d0 + tx;
      t[ty + i * 8][tx] = src[o] + src2[o];
    }
    __syncthreads();
#pragma unroll
    for (int i = 0; i < 4; ++i) {
      float v = t[tx][ty + i * 8];
      size_t o = (size_t)bkvh * 65536 + (size_t)(d0 + ty + i * 8) * 1024 + l0 + tx;
      unsigned short h = f2bf(v);
      vt_hi[o] = h;
      vt_lo[o] = f2bf(v - bf2f(h));
    }
  }
}

// ---------------- flash attention, split-bf16 MFMA, fp32 softmax ------------
// LDS = 48KB -> 3 blocks/CU fit (144 <= 160KB). (256,3) = 3 waves/EU ->
// ~170-reg budget; kernel needs ~120 -> no spill expected.
__launch_bounds__(256, 3)
__global__ void attn_mfma(const unsigned short* __restrict__ q_hi, const unsigned short* __restrict__ q_lo,
                          const unsigned short* __restrict__ k_hi, const unsigned short* __restrict__ k_lo,
                          const unsigned short* __restrict__ vt_hi, const unsigned short* __restrict__ vt_lo,
                          unsigned short* __restrict__ ohi, unsigned short* __restrict__ olo) {
  const int blk = blockIdx.x;
  const int bh = blk & 31;               // (b,h)
  const int qt = 15 - (blk >> 5);        // long tiles dispatch first
  const int b = bh >> 4;
  const int h = bh & 15;
  const int kvbh = b * 4 + (h >> 2);
  const int q0 = qt * 64;
  const int tid = threadIdx.x;
  const int w = tid >> 6;
  const int lane = tid & 63;
  const int quad = lane >> 4;
  const int r16 = lane & 15;
  const int rl = lane >> 3;
  const int csl = lane & 7;
  const int cg = csl ^ rl;

  __shared__ unsigned short sK[2][64 * 64];
  __shared__ unsigned short sV[2][64 * 64];
  __shared__ unsigned short sP[2][64 * 64];

  short8 qfh[2], qfl[2];
  {
    const size_t qrow = ((size_t)bh * 1024 + q0 + w * 16 + r16) * 64 + quad * 8;
    qfh[0] = *(const short8*)(q_hi + qrow);
    qfh[1] = *(const short8*)(q_hi + qrow + 32);
    qfl[0] = *(const short8*)(q_lo + qrow);
    qfl[1] = *(const short8*)(q_lo + qrow + 32);
  }
  float4v O[4];
#pragma unroll
  for (int nt = 0; nt < 4; ++nt) O[nt] = float4v{0.f, 0.f, 0.f, 0.f};
  float m[4], l[4];
#pragma unroll
  for (int rg = 0; rg < 4; ++rg) { m[rg] = -__builtin_inff(); l[rg] = 0.f; }

  const unsigned short* khb = k_hi + (size_t)kvbh * 65536 + cg * 8;
  const unsigned short* klb = k_lo + (size_t)kvbh * 65536 + cg * 8;
  const unsigned short* vhb = vt_hi + (size_t)kvbh * 65536 + cg * 8;
  const unsigned short* vlb = vt_lo + (size_t)kvbh * 65536 + cg * 8;

  for (int c = 0; c <= qt; ++c) {
    __syncthreads();
#pragma unroll
    for (int j = 0; j < 2; ++j) {
      const int i = w * 2 + j;
      const int row = i * 8 + rl;
      gl_lds16(khb + (size_t)(c * 64 + row) * 64, (char*)sK[0] + i * 1024);
      gl_lds16(klb + (size_t)(c * 64 + row) * 64, (char*)sK[1] + i * 1024);
      gl_lds16(vhb + (size_t)row * 1024 + c * 64, (char*)sV[0] + i * 1024);
      gl_lds16(vlb + (size_t)row * 1024 + c * 64, (char*)sV[1] + i * 1024);
    }
    __syncthreads();

    float4v S[4];
#pragma unroll
    for (int nt = 0; nt < 4; ++nt) S[nt] = float4v{0.f, 0.f, 0.f, 0.f};
#pragma unroll
    for (int ks = 0; ks < 2; ++ks) {
#pragma unroll
      for (int nt = 0; nt < 4; ++nt) {
        const int r = nt * 16 + r16;
        const int o = (r * 8 + ((ks * 4 + quad) ^ (r & 7))) * 8;
        const short8 kh = *(const short8*)(sK[0] + o);
        const short8 kl = *(const short8*)(sK[1] + o);
        S[nt] = __builtin_amdgcn_mfma_f32_16x16x32_bf16(qfh[ks], kh, S[nt], 0, 0, 0);
        S[nt] = __builtin_amdgcn_mfma_f32_16x16x32_bf16(qfh[ks], kl, S[nt], 0, 0, 0);
        S[nt] = __builtin_amdgcn_mfma_f32_16x16x32_bf16(qfl[ks], kh, S[nt], 0, 0, 0);
      }
    }
    const float NEGINF = -__builtin_inff();
#pragma unroll
    for (int nt = 0; nt < 4; ++nt)
#pragma unroll
      for (int rg = 0; rg < 4; ++rg) S[nt][rg] *= 0.125f;
    if (c == qt) {
#pragma unroll
      for (int nt = 0; nt < 4; ++nt) {
        const int col = nt * 16 + r16;
#pragma unroll
        for (int rg = 0; rg < 4; ++rg) {
          const int row = w * 16 + quad * 4 + rg;
          if (col > row) S[nt][rg] = NEGINF;
        }
      }
    }
    float alpha[4], lsum[4];
#pragma unroll
    for (int rg = 0; rg < 4; ++rg) {
      float mx = fmaxf(fmaxf(S[0][rg], S[1][rg]), fmaxf(S[2][rg], S[3][rg]));
      mx = fmaxf(mx, __shfl_xor(mx, 1));
      mx = fmaxf(mx, __shfl_xor(mx, 2));
      mx = fmaxf(mx, __shfl_xor(mx, 4));
      mx = fmaxf(mx, __shfl_xor(mx, 8));
      const float mn = fmaxf(m[rg], mx);
      alpha[rg] = __expf(m[rg] - mn);
      m[rg] = mn;
      lsum[rg] = 0.f;
    }
#pragma unroll
    for (int nt = 0; nt < 4; ++nt)
#pragma unroll
      for (int rg = 0; rg < 4; ++rg) {
        const float e = __expf(S[nt][rg] - m[rg]);
        S[nt][rg] = e;
        lsum[rg] += e;
      }
#pragma unroll
    for (int rg = 0; rg < 4; ++rg) {
      float ls = lsum[rg];
      ls += __shfl_xor(ls, 1);
      ls += __shfl_xor(ls, 2);
      ls += __shfl_xor(ls, 4);
      ls += __shfl_xor(ls, 8);
      l[rg] = l[rg] * alpha[rg] + ls;
    }
#pragma unroll
    for (int nt = 0; nt < 4; ++nt) {
      const int key = nt * 16 + r16;
      const int chunk = key >> 3;
#pragma unroll
      for (int rg = 0; rg < 4; ++rg) {
        const int r = w * 16 + quad * 4 + rg;
        const int addr = r * 64 + ((chunk ^ (r & 7)) * 8) + (key & 7);
        const float e = S[nt][rg];
        const unsigned short hv = f2bf(e);
        sP[0][addr] = hv;
        sP[1][addr] = f2bf(e - bf2f(hv));
      }
    }
#pragma unroll
    for (int nt = 0; nt < 4; ++nt)
#pragma unroll
      for (int rg = 0; rg < 4; ++rg) O[nt][rg] *= alpha[rg];
#pragma unroll
    for (int ks = 0; ks < 2; ++ks) {
      const int rA = w * 16 + r16;
      const int oA = (rA * 8 + ((ks * 4 + quad) ^ (rA & 7))) * 8;
      const short8 ph = *(const short8*)(sP[0] + oA);
      const short8 pl = *(const short8*)(sP[1] + oA);
#pragma unroll
      for (int nt = 0; nt < 4; ++nt) {
        const int rv = nt * 16 + r16;
        const int ov = (rv * 8 + ((ks * 4 + quad) ^ (rv & 7))) * 8;
        const short8 vh = *(const short8*)(sV[0] + ov);
        const short8 vl = *(const short8*)(sV[1] + ov);
        O[nt] = __builtin_amdgcn_mfma_f32_16x16x32_bf16(ph, vh, O[nt], 0, 0, 0);
        O[nt] = __builtin_amdgcn_mfma_f32_16x16x32_bf16(ph, vl, O[nt], 0, 0, 0);
        O[nt] = __builtin_amdgcn_mfma_f32_16x16x32_bf16(pl, vh, O[nt], 0, 0, 0);
      }
    }
  }
#pragma unroll
  for (int nt = 0; nt < 4; ++nt) {
    const int col = h * 64 + nt * 16 + r16;
#pragma unroll
    for (int rg = 0; rg < 4; ++rg) {
      const int row = q0 + w * 16 + quad * 4 + rg;
      const float ovv = O[nt][rg] / l[rg];
      const size_t idx = ((size_t)b * 1024 + row) * DMODEL + col;
      const unsigned short hv = f2bf(ovv);
      ohi[idx] = hv;
      olo[idx] = f2bf(ovv - bf2f(hv));
    }
  }
}

__global__ void finalize_kernel(const int* __restrict__ counts, int* __restrict__ off_pad,
                                int* __restrict__ tile_map, float* __restrict__ lb_out) {
  if (threadIdx.x == 0 && blockIdx.x == 0) {
    int tile = 0, rowoff = 0;
    for (int e = 0; e < NEXP; ++e) {
      off_pad[e] = rowoff;
      const int c = counts[e];
      const int nt = (c + 127) >> 7;
      for (int i = 0; i < nt; ++i) tile_map[tile++] = e;
      rowoff += nt * 128;
    }
    for (; tile < MAXTILES; ++tile) tile_map[tile] = -1;
    float sacc = 0.f;
    for (int e = 0; e < NEXP; ++e) {
      const float cn = (float)counts[e] * (1.0f / 4096.0f);
      const float d = cn - 0.125f;
      sacc += d * d;
    }
    lb_out[0] = sacc * (1.0f / 8.0f);
  }
}

__global__ void scatter_kernel(const int* __restrict__ tok_e, const int* __restrict__ off_pad,
                               int* __restrict__ fill, int* __restrict__ tok_pos,
                               const unsigned short* __restrict__ h2bf, unsigned short* __restrict__ Xg) {
  const int slot = blockIdx.x;
  const int t = slot >> 1;
  __shared__ int sp;
  if (threadIdx.x == 0) {
    const int e = tok_e[slot];
    const int r = atomicAdd(fill + e, 1);
    const int ppos = off_pad[e] + r;
    tok_pos[slot] = ppos;
    sp = ppos;
  }
  __syncthreads();
  const int pos = sp;
  *(uint2*)(Xg + (size_t)pos * DMODEL + threadIdx.x * 4) =
      *(const uint2*)(h2bf + (size_t)t * DMODEL + threadIdx.x * 4);
}

// ----- combine: out = x1 + g0*sum_z eout_z[p0] + g1*sum_z eout_z[p1] --------
__global__ void combine_kernel(const float* __restrict__ x1, const float* __restrict__ eout,
                               const int* __restrict__ tok_pos, const float* __restrict__ tok_g,
                               float* __restrict__ out) {
  const int t = blockIdx.x;
  const int tid = threadIdx.x;
  const int p0 = tok_pos[t * 2], p1 = tok_pos[t * 2 + 1];
  const float g0 = tok_g[t * 2], g1 = tok_g[t * 2 + 1];
  const size_t o = (size_t)t * DMODEL + tid * 4;
  const float4 a = *(const float4*)(x1 + o);
  float s0x = 0.f, s0y = 0.f, s0z = 0.f, s0w = 0.f;
  float s1x = 0.f, s1y = 0.f, s1z = 0.f, s1w = 0.f;
#pragma unroll
  for (int z = 0; z < 4; ++z) {
    const size_t zb = (size_t)z * MAXROWS * DMODEL;
    const float4 e0 = *(const float4*)(eout + zb + (size_t)p0 * DMODEL + tid * 4);
    const float4 e1 = *(const float4*)(eout + zb + (size_t)p1 * DMODEL + tid * 4);
    s0x += e0.x; s0y += e0.y; s0z += e0.z; s0w += e0.w;
    s1x += e1.x; s1y += e1.y; s1z += e1.z; s1w += e1.w;
  }
  float4 r;
  r.x = a.x + g0 * s0x + g1 * s1x;
  r.y = a.y + g0 * s0y + g1 * s1y;
  r.z = a.z + g0 * s0z + g1 * s1z;
  r.w = a.w + g0 * s0w + g1 * s1w;
  *(float4*)(out + o) = r;
}

extern "C" void kernel_launch(void* const* d_in, const int* in_sizes, int n_in,
                              void* d_out, int out_size, void* d_ws, size_t ws_size,
                              hipStream_t stream) {
  (void)in_sizes; (void)n_in; (void)out_size; (void)ws_size;
  const float* x    = (const float*)d_in[0];
  const float* wq   = (const float*)d_in[1];
  const float* wk   = (const float*)d_in[2];
  const float* wv   = (const float*)d_in[3];
  const float* wo   = (const float*)d_in[4];
  const float* wg   = (const float*)d_in[5];
  const float* w1   = (const float*)d_in[6];
  const float* w2   = (const float*)d_in[7];
  const float* ln1g = (const float*)d_in[8];
  const float* ln1b = (const float*)d_in[9];
  const float* ln2g = (const float*)d_in[10];
  const float* ln2b = (const float*)d_in[11];
  float* out = (float*)d_out;

  char* p = (char*)d_ws;
  auto take = [&](size_t n) { void* r = (void*)p; p += (n + 255) & ~(size_t)255; return r; };
  unsigned short* h1_hi   = (unsigned short*)take((size_t)NTOK * DMODEL * 2);
  unsigned short* h1_lo   = (unsigned short*)take((size_t)NTOK * DMODEL * 2);
  unsigned short* wqkv_hi = (unsigned short*)take((size_t)1536 * 1024 * 2);
  unsigned short* wqkv_lo = (unsigned short*)take((size_t)1536 * 1024 * 2);
  unsigned short* woT_hi  = (unsigned short*)take((size_t)1024 * 1024 * 2);
  unsigned short* woT_lo  = (unsigned short*)take((size_t)1024 * 1024 * 2);
  unsigned short* w1t     = (unsigned short*)take((size_t)NEXP * DFF * DMODEL * 2);
  unsigned short* w2t     = (unsigned short*)take((size_t)NEXP * DMODEL * DFF * 2);
  float* qkv   = (float*)take((size_t)2 * NTOK * 1536 * 4);          // 2 split-K slabs
  unsigned short* q_hi  = (unsigned short*)take((size_t)2 * 16 * 1024 * 64 * 2);
  unsigned short* q_lo  = (unsigned short*)take((size_t)2 * 16 * 1024 * 64 * 2);
  unsigned short* k_hi  = (unsigned short*)take((size_t)2 * 4 * 1024 * 64 * 2);
  unsigned short* k_lo  = (unsigned short*)take((size_t)2 * 4 * 1024 * 64 * 2);
  unsigned short* vt_hi = (unsigned short*)take((size_t)2 * 4 * 1024 * 64 * 2);
  unsigned short* vt_lo = (unsigned short*)take((size_t)2 * 4 * 1024 * 64 * 2);
  unsigned short* attn_hi = (unsigned short*)take((size_t)NTOK * DMODEL * 2);
  unsigned short* attn_lo = (unsigned short*)take((size_t)NTOK * DMODEL * 2);
  float* x1p   = (float*)take((size_t)4 * NTOK * DMODEL * 4);        // 4 split-K slabs
  float* x1    = (float*)take((size_t)NTOK * DMODEL * 4);
  unsigned short* h2bf = (unsigned short*)take((size_t)NTOK * DMODEL * 2);
  unsigned short* Xg   = (unsigned short*)take((size_t)MAXROWS * DMODEL * 2);
  unsigned short* hid  = (unsigned short*)take((size_t)MAXROWS * DFF * 2);
  float* eout  = (float*)take((size_t)4 * MAXROWS * DMODEL * 4);     // 4 split-K slabs
  int*   tok_e   = (int*)take(4096 * 4);
  float* tok_g   = (float*)take(4096 * 4);
  int*   tok_pos = (int*)take(4096 * 4);
  int*   counts  = (int*)take(64);
  int*   fill    = (int*)take(64);
  int*   off_pad = (int*)take(64);
  int*   tile_map = (int*)take(256);

  // fused wq/wk/wv/wo transpose + counts/fill init
  transpose_qkvo<<<dim3(16, 16, 4), 256, 0, stream>>>(wq, wk, wv, wo, wqkv_hi, wqkv_lo,
                                                      woT_hi, woT_lo, counts, fill);
  ln_kernel<<<NTOK, 256, 0, stream>>>(x, ln1g, ln1b, h1_hi, h1_lo);
  // fused w1+w2 transpose, now XCD-swizzled (R7: 110us @ 2.4TB/s, read-share bound)
  transpose_w12<<<16384, 256, 0, stream>>>(w1, w2, w1t, w2t);
  // qkv = h1 @ [wq|wk|wv], split-K x2 (384 blocks), XCD-swizzled
  gemm_split<<<dim3(12, 16, 2), 256, 0, stream>>>(h1_hi, h1_lo, wqkv_hi, wqkv_lo, qkv, 1536, 1024, 512, (long)NTOK * 1536);
  // fused RoPE + V-transpose
  rope_vt<<<2560, 256, 0, stream>>>(qkv, qkv + (size_t)NTOK * 1536, q_hi, q_lo, k_hi, k_lo, vt_hi, vt_lo);
  attn_mfma<<<512, 256, 0, stream>>>(q_hi, q_lo, k_hi, k_lo, vt_hi, vt_lo, attn_hi, attn_lo);
  // wo projection: split-K x4 (512 blocks)
  gemm_split<<<dim3(8, 16, 4), 256, 0, stream>>>(attn_hi, attn_lo, woT_hi, woT_lo, x1p, 1024, 1024, 256, (long)NTOK * DMODEL);
  // fused: x1 = x + sum(slabs); ln2; h2bf; router
  fused_ln2_router<<<NTOK, 256, 0, stream>>>(x, x1p, ln2g, ln2b, x1, h2bf, wg, tok_e, tok_g, counts);
  finalize_kernel<<<1, 64, 0, stream>>>(counts, off_pad, tile_map, out + (size_t)NTOK * DMODEL);
  scatter_kernel<<<4096, 256, 0, stream>>>(tok_e, off_pad, fill, tok_pos, h2bf, Xg);
  // w1 GEMM: tanh-gelu epilogue, XCD-swizzled
  gemm_bt<3,1><<<dim3(32, MAXTILES), 256, 0, stream>>>(Xg, w1t, nullptr, hid, DFF, DMODEL, DMODEL, 0, tile_map, (long)DFF * DMODEL);
  // expert down-proj: split-K x4 (1280 blocks), XCD-swizzled
  gemm_bt<0,1><<<dim3(8, MAXTILES, 4), 256, 0, stream>>>(hid, w2t, eout, nullptr, DMODEL, DFF, 1024, (long)MAXROWS * DMODEL, tile_map, (long)DMODEL * DFF);
  combine_kernel<<<NTOK, 256, 0, stream>>>(x1, eout, tok_pos, tok_g, out);
}